// Round 1
// baseline (31975.140 us; speedup 1.0000x reference)
//
#include <hip/hip_runtime.h>

// ---------------- problem constants ----------------
constexpr int BB = 32, TT = 250;
constexpr int FEATD = 128, NCLS = 25, UNITS = 512, CELL = 64, HEADS = 4;
constexpr int RVD = HEADS * CELL;   // 256
constexpr int ZC = 4 * UNITS;       // 2048

// ---------------- scratch layout (floats) ----------------
constexpr size_t OFF_FEAT   = 0;
constexpr size_t OFF_WXI    = OFF_FEAT + (size_t)8000 * 128;          // 1,024,000
constexpr size_t OFF_WHI    = OFF_WXI + (size_t)409 * 2048;
constexpr size_t OFF_BLI    = OFF_WHI + (size_t)512 * 2048;
constexpr size_t OFF_ZACC   = OFF_BLI + 2048;
constexpr size_t OFF_OUTH   = OFF_ZACC + (size_t)32 * 2048;
constexpr size_t OFF_OUTPRE = OFF_OUTH + (size_t)32 * 512;
constexpr size_t OFF_HIDPRE = OFF_OUTPRE + (size_t)32 * 512;
constexpr size_t OFF_H      = OFF_HIDPRE + (size_t)32 * 320;          // zero-region start
constexpr size_t OFF_C      = OFF_H + (size_t)32 * 512;
constexpr size_t OFF_RV     = OFF_C + (size_t)32 * 512;
constexpr size_t OFF_WV     = OFF_RV + (size_t)32 * 256;
constexpr size_t OFF_RING   = OFF_WV + (size_t)32 * 64;
constexpr size_t OFF_BAR    = OFF_RING + (size_t)32 * 250 * 64;
constexpr size_t WS_FLOATS  = OFF_BAR + 1024;

__device__ __forceinline__ float sigm(float x) { return 1.f / (1.f + __expf(-x)); }

// ---------------- weight re-layout: gate-interleaved Wx/Wh/bl ----------------
// WXI[k][u*4+g] = Wx[k][g*512+u]  (same for WHI, BLI)
__global__ __launch_bounds__(256) void prep_kernel(const float* __restrict__ Wx,
                                                   const float* __restrict__ Wh,
                                                   const float* __restrict__ bl,
                                                   float* __restrict__ ws) {
  float* WXI = ws + OFF_WXI;
  float* WHI = ws + OFF_WHI;
  float* BLI = ws + OFF_BLI;
  const int total = 409 * 2048 + 512 * 2048 + 2048;
  for (int idx = blockIdx.x * blockDim.x + threadIdx.x; idx < total;
       idx += gridDim.x * blockDim.x) {
    if (idx < 409 * 2048) {
      int k = idx >> 11, cc = idx & 2047;
      WXI[idx] = Wx[(size_t)k * 2048 + (cc & 3) * 512 + (cc >> 2)];
    } else if (idx < 409 * 2048 + 512 * 2048) {
      int j = idx - 409 * 2048;
      int k = j >> 11, cc = j & 2047;
      WHI[j] = Wh[(size_t)k * 2048 + (cc & 3) * 512 + (cc >> 2)];
    } else {
      int cc = idx - (409 * 2048 + 512 * 2048);
      BLI[cc] = bl[(cc & 3) * 512 + (cc >> 2)];
    }
  }
}

// ---------------- conv stack: 3x (3x3 stride-2 VALID conv + BN + ReLU) ----------------
__global__ __launch_bounds__(128) void conv_kernel(
    const float* __restrict__ img,
    const float* __restrict__ k1, const float* __restrict__ cb1, const float* __restrict__ g1,
    const float* __restrict__ be1, const float* __restrict__ mm1, const float* __restrict__ mv1,
    const float* __restrict__ k2, const float* __restrict__ cb2, const float* __restrict__ g2,
    const float* __restrict__ be2, const float* __restrict__ mm2, const float* __restrict__ mv2,
    const float* __restrict__ k3, const float* __restrict__ cb3, const float* __restrict__ g3,
    const float* __restrict__ be3, const float* __restrict__ mm3, const float* __restrict__ mv3,
    float* __restrict__ ws) {
  __shared__ float s_in[784];
  __shared__ float s_y1[13 * 13 * 8];
  __shared__ float s_y2[6 * 6 * 16];
  __shared__ float s_k1[72], s_k2[1152], s_k3[4608];
  __shared__ float s_s1[8], s_b1[8], s_s2[16], s_b2[16], s_s3[32], s_b3[32];
  float* FEATP = ws + OFF_FEAT;
  const int n = blockIdx.x, tid = threadIdx.x;
  const float* ip = img + (size_t)n * 784;
  for (int i = tid; i < 784; i += 128) s_in[i] = ip[i];
  for (int i = tid; i < 72; i += 128) s_k1[i] = k1[i];
  for (int i = tid; i < 1152; i += 128) s_k2[i] = k2[i];
  for (int i = tid; i < 4608; i += 128) s_k3[i] = k3[i];
  if (tid < 8) {
    float s = g1[tid] * rsqrtf(mv1[tid] + 1e-3f);
    s_s1[tid] = s; s_b1[tid] = (cb1[tid] - mm1[tid]) * s + be1[tid];
  } else if (tid >= 32 && tid < 48) {
    int c = tid - 32;
    float s = g2[c] * rsqrtf(mv2[c] + 1e-3f);
    s_s2[c] = s; s_b2[c] = (cb2[c] - mm2[c]) * s + be2[c];
  } else if (tid >= 64 && tid < 96) {
    int c = tid - 64;
    float s = g3[c] * rsqrtf(mv3[c] + 1e-3f);
    s_s3[c] = s; s_b3[c] = (cb3[c] - mm3[c]) * s + be3[c];
  }
  __syncthreads();
  // conv1: 13x13x8
  for (int idx = tid; idx < 13 * 13 * 8; idx += 128) {
    int co = idx & 7, pos = idx >> 3;
    int j = pos % 13, i = pos / 13;
    float acc = 0.f;
    #pragma unroll
    for (int ky = 0; ky < 3; ++ky)
      #pragma unroll
      for (int kx = 0; kx < 3; ++kx)
        acc += s_in[(2 * i + ky) * 28 + (2 * j + kx)] * s_k1[(ky * 3 + kx) * 8 + co];
    float v = acc * s_s1[co] + s_b1[co];
    s_y1[idx] = v > 0.f ? v : 0.f;
  }
  __syncthreads();
  // conv2: 6x6x16
  for (int idx = tid; idx < 6 * 6 * 16; idx += 128) {
    int co = idx & 15, pos = idx >> 4;
    int j = pos % 6, i = pos / 6;
    float acc = 0.f;
    for (int ky = 0; ky < 3; ++ky)
      for (int kx = 0; kx < 3; ++kx) {
        int base = ((2 * i + ky) * 13 + (2 * j + kx)) * 8;
        int kb = (ky * 3 + kx) * 128 + co;
        #pragma unroll
        for (int ci = 0; ci < 8; ++ci) acc += s_y1[base + ci] * s_k2[kb + ci * 16];
      }
    float v = acc * s_s2[co] + s_b2[co];
    s_y2[idx] = v > 0.f ? v : 0.f;
  }
  __syncthreads();
  // conv3: 2x2x32 -> feat[128]
  for (int idx = tid; idx < 128; idx += 128) {
    int co = idx & 31, pos = idx >> 5;
    int j = pos & 1, i = pos >> 1;
    float acc = 0.f;
    for (int ky = 0; ky < 3; ++ky)
      for (int kx = 0; kx < 3; ++kx) {
        int base = ((2 * i + ky) * 6 + (2 * j + kx)) * 16;
        int kb = (ky * 3 + kx) * 512 + co;
        #pragma unroll
        for (int ci = 0; ci < 16; ++ci) acc += s_y2[base + ci] * s_k3[kb + ci * 32];
      }
    float v = acc * s_s3[co] + s_b3[co];
    FEATP[(size_t)n * 128 + idx] = v > 0.f ? v : 0.f;
  }
}

// ---------------- persistent LSTM scan kernel ----------------
// grid = 256 blocks x 512 threads; exactly 1 block/CU -> all co-resident.
__global__ __launch_bounds__(512) void lstm_kernel(
    const int* __restrict__ labels,
    const float* __restrict__ Wo, const float* __restrict__ bo,
    const float* __restrict__ Wp, const float* __restrict__ bp,
    const float* __restrict__ Wf, const float* __restrict__ bf,
    float* __restrict__ ws, float* __restrict__ out) {
  __shared__ float sm[9248];
  float* FEATP  = ws + OFF_FEAT;
  float* WXI    = ws + OFF_WXI;
  float* WHI    = ws + OFF_WHI;
  float* BLI    = ws + OFF_BLI;
  float* ZACC   = ws + OFF_ZACC;
  float* OUTH   = ws + OFF_OUTH;
  float* OUTPRE = ws + OFF_OUTPRE;
  float* HIDPRE = ws + OFF_HIDPRE;
  float* Hs     = ws + OFF_H;
  float* Cs     = ws + OFF_C;
  float* RVs    = ws + OFF_RV;
  float* WVs    = ws + OFF_WV;
  float* RING   = ws + OFF_RING;
  int*   BARp   = (int*)(ws + OFF_BAR);

  const int bid = blockIdx.x;
  const int tid = threadIdx.x;
  int barGen = 0;

  auto gbar = [&]() {
    __syncthreads();
    ++barGen;
    if (tid == 0) {
      __builtin_amdgcn_fence(__ATOMIC_RELEASE, "agent");
      int a = __hip_atomic_fetch_add(&BARp[(bid & 7) << 6], 1, __ATOMIC_RELAXED,
                                     __HIP_MEMORY_SCOPE_AGENT);
      if ((a & 31) == 31) {
        int r = __hip_atomic_fetch_add(&BARp[512], 1, __ATOMIC_RELAXED,
                                       __HIP_MEMORY_SCOPE_AGENT);
        if ((r & 7) == 7) {
          __hip_atomic_fetch_add(&BARp[576], 1, __ATOMIC_RELAXED,
                                 __HIP_MEMORY_SCOPE_AGENT);
        }
      }
      while (__hip_atomic_load(&BARp[576], __ATOMIC_RELAXED,
                               __HIP_MEMORY_SCOPE_AGENT) < barGen) {
        __builtin_amdgcn_s_sleep(2);
      }
      __builtin_amdgcn_fence(__ATOMIC_ACQUIRE, "agent");
    }
    __syncthreads();
  };

  // ---- PH-A: gates (h_t,c_t) + outpre_{t-1} ----
  auto phaseA = [&](int t) {
    if (bid < 32) {  // gates, t in 0..249
      if (t <= 249) {
        const int bg = bid >> 2, ug = bid & 3;
        float* rvT = sm;          // [256][4]
        float* zsb = sm + 1024;   // [512][16]
        for (int i = tid; i < 1024; i += 512)
          rvT[i] = RVs[((bg << 2) + (i & 3)) * 256 + (i >> 2)];
        __syncthreads();
        const int cl = tid & 127, ks = tid >> 7;
        const int u = ug * 128 + cl;
        float acc[16];
        #pragma unroll
        for (int q = 0; q < 16; ++q) acc[q] = 0.f;
        const float* wb = WXI + (size_t)(153 + ks * 64) * 2048 + u * 4;
        const float* rp = rvT + (ks * 64) * 4;
        for (int k = 0; k < 64; ++k) {
          float4 r4 = *(const float4*)(rp + k * 4);
          float4 w4 = *(const float4*)(wb + (size_t)k * 2048);
          acc[0]  += r4.x * w4.x; acc[1]  += r4.x * w4.y; acc[2]  += r4.x * w4.z; acc[3]  += r4.x * w4.w;
          acc[4]  += r4.y * w4.x; acc[5]  += r4.y * w4.y; acc[6]  += r4.y * w4.z; acc[7]  += r4.y * w4.w;
          acc[8]  += r4.z * w4.x; acc[9]  += r4.z * w4.y; acc[10] += r4.z * w4.z; acc[11] += r4.z * w4.w;
          acc[12] += r4.w * w4.x; acc[13] += r4.w * w4.y; acc[14] += r4.w * w4.z; acc[15] += r4.w * w4.w;
        }
        float* zrow = zsb + tid * 16;
        #pragma unroll
        for (int q = 0; q < 16; ++q) zrow[q] = acc[q];
        __syncthreads();
        const int bi = tid & 3, cl2 = tid >> 2;
        const int b = (bg << 2) + bi, u2 = ug * 128 + cl2;
        float4 za = *(const float4*)(ZACC + (size_t)b * 2048 + u2 * 4);
        float z0 = za.x, z1 = za.y, z2 = za.z, z3 = za.w;
        #pragma unroll
        for (int q = 0; q < 4; ++q) {
          const float* p = zsb + (q * 128 + cl2) * 16 + bi * 4;
          z0 += p[0]; z1 += p[1]; z2 += p[2]; z3 += p[3];
        }
        float ig = sigm(z0), fg = sigm(z1), gg = tanhf(z2), og = sigm(z3);
        float cc = fg * Cs[b * 512 + u2] + ig * gg;
        Cs[b * 512 + u2] = cc;
        Hs[b * 512 + u2] = og * tanhf(cc);
      }
    } else if (bid < 40) {  // outpre for step t-1, t in 1..250
      if (t >= 1) {
        const int bg = bid - 32;
        float* rvT = sm;
        for (int i = tid; i < 1024; i += 512)
          rvT[i] = RVs[((bg << 2) + (i & 3)) * 256 + (i >> 2)];
        __syncthreads();
        const int u = tid;
        float bov = bo[u];
        float a0 = OUTH[(bg * 4 + 0) * 512 + u] + bov;
        float a1 = OUTH[(bg * 4 + 1) * 512 + u] + bov;
        float a2 = OUTH[(bg * 4 + 2) * 512 + u] + bov;
        float a3 = OUTH[(bg * 4 + 3) * 512 + u] + bov;
        const float* wb = Wo + (size_t)512 * 512 + u;
        for (int k = 0; k < 256; ++k) {
          float4 r4 = *(const float4*)(rvT + k * 4);
          float w = wb[(size_t)k * 512];
          a0 += r4.x * w; a1 += r4.y * w; a2 += r4.z * w; a3 += r4.w * w;
        }
        OUTPRE[(bg * 4 + 0) * 512 + u] = a0;
        OUTPRE[(bg * 4 + 1) * 512 + u] = a1;
        OUTPRE[(bg * 4 + 2) * 512 + u] = a2;
        OUTPRE[(bg * 4 + 3) * 512 + u] = a3;
      }
    }
  };

  // ---- PH-B: merged column GEMM (zacc_{t+1}|outh_t|hidpre_t) + logits_{t-1} + ring insert ----
  auto phaseB = [&](int t) {
    if (bid < 92) {  // GEMM, t <= 249 (incl. prologue t=-1)
      if (t <= 249) {
        const int cgrp = bid >> 2, bg = bid & 3;
        const int tt1 = (t + 1 < 250) ? (t + 1) : 249;
        float* featT = sm;                 // [128][8]
        float* hT    = sm + 1024;          // [512][8]
        int*   labs  = (int*)(sm + 5120);  // 8 ints
        float* zsb   = sm + 5136;          // [512][8]
        for (int i = tid; i < 1024; i += 512) {
          int k = i >> 3, bi = i & 7;
          featT[i] = FEATP[((size_t)(bg * 8 + bi) * 250 + tt1) * 128 + k];
        }
        for (int i = tid; i < 4096; i += 512) {
          int k = i >> 3, bi = i & 7;
          hT[i] = Hs[(bg * 8 + bi) * 512 + k];
        }
        if (tid < 8) labs[tid] = labels[(bg * 8 + tid) * 250 + tt1];
        __syncthreads();
        const int cl = tid & 127, ks = tid >> 7;
        const int c = cgrp * 128 + cl;
        float acc[8];
        #pragma unroll
        for (int q = 0; q < 8; ++q) acc[q] = 0.f;
        if (c < 2048) {
          for (int k = ks * 32; k < ks * 32 + 32; ++k) {
            float w = WXI[(size_t)k * 2048 + c];
            float4 f0 = *(const float4*)(featT + k * 8);
            float4 f1 = *(const float4*)(featT + k * 8 + 4);
            acc[0] += f0.x * w; acc[1] += f0.y * w; acc[2] += f0.z * w; acc[3] += f0.w * w;
            acc[4] += f1.x * w; acc[5] += f1.y * w; acc[6] += f1.z * w; acc[7] += f1.w * w;
          }
          for (int k = ks * 128; k < ks * 128 + 128; ++k) {
            float w = WHI[(size_t)k * 2048 + c];
            float4 h0 = *(const float4*)(hT + k * 8);
            float4 h1 = *(const float4*)(hT + k * 8 + 4);
            acc[0] += h0.x * w; acc[1] += h0.y * w; acc[2] += h0.z * w; acc[3] += h0.w * w;
            acc[4] += h1.x * w; acc[5] += h1.y * w; acc[6] += h1.z * w; acc[7] += h1.w * w;
          }
        } else if (c < 2560) {
          const int u = c - 2048;
          for (int k = ks * 128; k < ks * 128 + 128; ++k) {
            float w = Wo[(size_t)k * 512 + u];
            float4 h0 = *(const float4*)(hT + k * 8);
            float4 h1 = *(const float4*)(hT + k * 8 + 4);
            acc[0] += h0.x * w; acc[1] += h0.y * w; acc[2] += h0.z * w; acc[3] += h0.w * w;
            acc[4] += h1.x * w; acc[5] += h1.y * w; acc[6] += h1.z * w; acc[7] += h1.w * w;
          }
        } else if (c < 2880) {
          const int j = c - 2560;
          for (int k = ks * 128; k < ks * 128 + 128; ++k) {
            float w = Wp[(size_t)k * 320 + j];
            float4 h0 = *(const float4*)(hT + k * 8);
            float4 h1 = *(const float4*)(hT + k * 8 + 4);
            acc[0] += h0.x * w; acc[1] += h0.y * w; acc[2] += h0.z * w; acc[3] += h0.w * w;
            acc[4] += h1.x * w; acc[5] += h1.y * w; acc[6] += h1.z * w; acc[7] += h1.w * w;
          }
        }
        float* zrow = zsb + tid * 8;
        #pragma unroll
        for (int q = 0; q < 8; ++q) zrow[q] = acc[q];
        __syncthreads();
        for (int oi = tid; oi < 1024; oi += 512) {
          const int cl2 = oi >> 3, bi = oi & 7;
          const int c2 = cgrp * 128 + cl2;
          if (c2 >= 2880) continue;
          float v = 0.f;
          #pragma unroll
          for (int q = 0; q < 4; ++q) v += zsb[(q * 128 + cl2) * 8 + bi];
          const int b = bg * 8 + bi;
          if (c2 < 2048) {
            v += BLI[c2] + WXI[(size_t)(128 + labs[bi]) * 2048 + c2];
            ZACC[(size_t)b * 2048 + c2] = v;
          } else if (c2 < 2560) {
            OUTH[b * 512 + (c2 - 2048)] = v;
          } else {
            HIDPRE[b * 320 + (c2 - 2560)] = v + bp[c2 - 2560];
          }
        }
      }
    } else if (bid < 124) {  // logits/softmax for t-1 + ring insert, t >= 1
      if (t >= 1) {
        const int b = bid - 92;
        if (tid < 64)
          RING[((size_t)b * 250 + ((250 - t) % 250)) * 64 + tid] = WVs[b * 64 + tid];
        float* to = sm;         // 512
        float* lp = sm + 512;   // 400
        float* lg = sm + 912;   // 27
        for (int i = tid; i < 512; i += 512) to[i] = tanhf(OUTPRE[b * 512 + i]);
        __syncthreads();
        if (tid < 400) {
          const int l = tid % 25, p = tid / 25;
          float s = 0.f;
          #pragma unroll
          for (int q = 0; q < 32; ++q) {
            int k = p * 32 + q;
            s += to[k] * Wf[k * 25 + l];
          }
          lp[p * 25 + l] = s;
        }
        __syncthreads();
        if (tid < 25) {
          float s = bf[tid];
          #pragma unroll
          for (int p = 0; p < 16; ++p) s += lp[p * 25 + tid];
          lg[tid] = s;
        }
        __syncthreads();
        if (tid == 0) {
          float mx = lg[0];
          for (int l = 1; l < 25; ++l) mx = fmaxf(mx, lg[l]);
          float sum = 0.f;
          for (int l = 0; l < 25; ++l) sum += __expf(lg[l] - mx);
          lg[25] = mx; lg[26] = 1.f / sum;
        }
        __syncthreads();
        if (tid < 25)
          out[((size_t)b * 250 + (t - 1)) * 25 + tid] = __expf(lg[tid] - lg[25]) * lg[26];
      }
    }
  };

  // ---- PH-C: attention (wv_t, rv_t), t in 0..249 ----
  auto phaseC = [&](int t) {
    if (bid < 64) {
      const int b = bid >> 1, half = bid & 1;
      float* hid = sm;         // 192
      float* kn  = sm + 192;   // 128
      float* att = sm + 320;   // 2 x 250
      float* red = sm + 820;   // 16
      float* msc = sm + 836;   // 4
      const int start = (250 - t) % 250;
      const int ncol = half ? 128 : 192;
      const int cbase = half ? 192 : 0;
      for (int i = tid; i < ncol; i += 512) {
        float v = tanhf(HIDPRE[b * 320 + cbase + i]);
        hid[i] = v;
        if (!half && i < 64) WVs[b * 64 + i] = v;
      }
      __syncthreads();
      const int kb0 = half ? 0 : 64;
      float part = 0.f;
      if (tid < 128) { float v = hid[kb0 + tid]; part = v * v; }
      for (int off = 32; off; off >>= 1) part += __shfl_down(part, off, 64);
      if ((tid & 63) == 0 && tid < 128) red[tid >> 6] = rsqrtf(fmaxf(part, 1e-12f));
      __syncthreads();
      if (tid < 128) kn[tid] = hid[kb0 + tid] * red[tid >> 6];
      __syncthreads();
      for (int m = tid; m < 250; m += 512) {
        int p = start + m; if (p >= 250) p -= 250;
        const float* cell = RING + ((size_t)b * 250 + p) * 64;
        float n2 = 0.f, d0 = 0.f, d1 = 0.f;
        #pragma unroll
        for (int s = 0; s < 64; s += 4) {
          float4 q = *(const float4*)(cell + s);
          n2 += q.x * q.x + q.y * q.y + q.z * q.z + q.w * q.w;
          d0 += kn[s] * q.x + kn[s + 1] * q.y + kn[s + 2] * q.z + kn[s + 3] * q.w;
          d1 += kn[64 + s] * q.x + kn[64 + s + 1] * q.y + kn[64 + s + 2] * q.z + kn[64 + s + 3] * q.w;
        }
        float rs = rsqrtf(fmaxf(n2, 1e-12f));
        att[m] = d0 * rs; att[250 + m] = d1 * rs;
      }
      __syncthreads();
      const int r = tid >> 8, mm = tid & 255;
      float v = (mm < 250) ? att[r * 250 + mm] : -3.4e38f;
      float wmax = v;
      for (int off = 32; off; off >>= 1) wmax = fmaxf(wmax, __shfl_down(wmax, off, 64));
      if ((tid & 63) == 0) red[tid >> 6] = wmax;
      __syncthreads();
      const int w0 = r * 4;
      float mx = fmaxf(fmaxf(red[w0], red[w0 + 1]), fmaxf(red[w0 + 2], red[w0 + 3]));
      __syncthreads();
      float e = (mm < 250) ? __expf(v - mx) : 0.f;
      if (mm < 250) att[r * 250 + mm] = e;
      float sacc = e;
      for (int off = 32; off; off >>= 1) sacc += __shfl_down(sacc, off, 64);
      if ((tid & 63) == 0) red[8 + (tid >> 6)] = sacc;
      __syncthreads();
      if (mm == 0)
        msc[r] = red[8 + w0] + red[8 + w0 + 1] + red[8 + w0 + 2] + red[8 + w0 + 3];
      __syncthreads();
      if (tid < 256) {
        const int rr = tid >> 7, s = (tid >> 1) & 63, mh = tid & 1;
        float a = 0.f;
        for (int m2 = mh * 125; m2 < mh * 125 + 125; ++m2) {
          int p = start + m2; if (p >= 250) p -= 250;
          a += att[rr * 250 + m2] * RING[((size_t)b * 250 + p) * 64 + s];
        }
        a += __shfl_down(a, 1, 64);
        if (mh == 0) RVs[b * 256 + (half * 2 + rr) * 64 + s] = a / msc[rr];
      }
    }
  };

  // ---- main sequence ----
  phaseB(-1);  // zacc_0 = feat_0 @ Wx_x + onehot + bl (h = 0)
  gbar();
  for (int t = 0; t <= 250; ++t) {
    phaseA(t);
    gbar();
    phaseB(t);
    if (t == 250) break;
    gbar();
    phaseC(t);
    gbar();
  }
}

extern "C" void kernel_launch(void* const* d_in, const int* in_sizes, int n_in,
                              void* d_out, int out_size, void* d_ws, size_t ws_size,
                              hipStream_t stream) {
  const float* images = (const float*)d_in[0];
  const int* labels = (const int*)d_in[1];
  const float* k1  = (const float*)d_in[2];
  const float* cb1 = (const float*)d_in[3];
  const float* g1  = (const float*)d_in[4];
  const float* be1 = (const float*)d_in[5];
  const float* mm1 = (const float*)d_in[6];
  const float* mv1 = (const float*)d_in[7];
  const float* k2  = (const float*)d_in[8];
  const float* cb2 = (const float*)d_in[9];
  const float* g2  = (const float*)d_in[10];
  const float* be2 = (const float*)d_in[11];
  const float* mm2 = (const float*)d_in[12];
  const float* mv2 = (const float*)d_in[13];
  const float* k3  = (const float*)d_in[14];
  const float* cb3 = (const float*)d_in[15];
  const float* g3  = (const float*)d_in[16];
  const float* be3 = (const float*)d_in[17];
  const float* mm3 = (const float*)d_in[18];
  const float* mv3 = (const float*)d_in[19];
  const float* Wx  = (const float*)d_in[20];
  const float* Wh  = (const float*)d_in[21];
  const float* bl  = (const float*)d_in[22];
  const float* Wp  = (const float*)d_in[23];
  const float* bp  = (const float*)d_in[24];
  const float* Wo  = (const float*)d_in[25];
  const float* bo  = (const float*)d_in[26];
  const float* Wf  = (const float*)d_in[27];
  const float* bf  = (const float*)d_in[28];
  float* ws = (float*)d_ws;

  // zero the state + barrier region (ws is poisoned 0xAA before each call)
  hipMemsetAsync((char*)d_ws + OFF_H * sizeof(float), 0,
                 (WS_FLOATS - OFF_H) * sizeof(float), stream);
  prep_kernel<<<1024, 256, 0, stream>>>(Wx, Wh, bl, ws);
  conv_kernel<<<8000, 128, 0, stream>>>(images,
      k1, cb1, g1, be1, mm1, mv1,
      k2, cb2, g2, be2, mm2, mv2,
      k3, cb3, g3, be3, mm3, mv3, ws);
  lstm_kernel<<<256, 512, 0, stream>>>(labels, Wo, bo, Wp, bp, Wf, bf, ws,
                                       (float*)d_out);
}

// Round 2
// 12794.422 us; speedup vs baseline: 2.4991x; 2.4991x over previous
//
#include <hip/hip_runtime.h>

// ---------------- problem constants ----------------
// B=32, T=250, FEAT=128, CLASSES=25, UNITS=512, CELL=64, HEADS=4, IN_LSTM=409

// ---------------- scratch layout (floats) ----------------
constexpr size_t OFF_FEATP  = 0;                              // [8000][128]
constexpr size_t OFF_WXI    = OFF_FEATP + (size_t)8000 * 128; // [409][2048] gate-interleaved
constexpr size_t OFF_WHI    = OFF_WXI + (size_t)409 * 2048;   // [512][2048]
constexpr size_t OFF_BLI    = OFF_WHI + (size_t)512 * 2048;   // [2048]
constexpr size_t OFF_ZP0    = OFF_BLI + 2048;                 // [32][2048] zacc partial LO (incl label+bl)
constexpr size_t OFF_ZP1    = OFF_ZP0 + (size_t)32 * 2048;    // [32][2048] zacc partial HI
constexpr size_t OFF_OH0    = OFF_ZP1 + (size_t)32 * 2048;    // [32][512] outh partial LO
constexpr size_t OFF_OH1    = OFF_OH0 + (size_t)32 * 512;     // [32][512] outh partial HI
constexpr size_t OFF_HP0    = OFF_OH1 + (size_t)32 * 512;     // [32][320] hidpre partial LO
constexpr size_t OFF_HP1    = OFF_HP0 + (size_t)32 * 320;     // [32][320] hidpre partial HI
constexpr size_t OFF_OUTPRE = OFF_HP1 + (size_t)32 * 320;     // [32][512]
constexpr size_t OFF_HT     = OFF_OUTPRE + (size_t)32 * 512;  // [512][32] h transposed
constexpr size_t OFF_RVT    = OFF_HT + (size_t)512 * 32;      // [256][32] rv transposed
constexpr size_t OFF_BAR    = OFF_RVT + (size_t)256 * 32;     // barrier ints
constexpr size_t WS_FLOATS  = OFF_BAR + 1024;

constexpr int DYN_FLOATS = 34816;                 // 136 KB dynamic LDS
constexpr int DYN_BYTES  = DYN_FLOATS * 4;

__device__ __forceinline__ float sigm(float x) { return 1.f / (1.f + __expf(-x)); }

// ---------------- weight re-layout: gate-interleaved Wx/Wh/bl ----------------
__global__ __launch_bounds__(256) void prep_kernel(const float* __restrict__ Wx,
                                                   const float* __restrict__ Wh,
                                                   const float* __restrict__ bl,
                                                   float* __restrict__ ws) {
  float* WXI = ws + OFF_WXI;
  float* WHI = ws + OFF_WHI;
  float* BLI = ws + OFF_BLI;
  const int total = 409 * 2048 + 512 * 2048 + 2048;
  for (int idx = blockIdx.x * blockDim.x + threadIdx.x; idx < total;
       idx += gridDim.x * blockDim.x) {
    if (idx < 409 * 2048) {
      int k = idx >> 11, cc = idx & 2047;
      WXI[idx] = Wx[(size_t)k * 2048 + (cc & 3) * 512 + (cc >> 2)];
    } else if (idx < 409 * 2048 + 512 * 2048) {
      int j = idx - 409 * 2048;
      int k = j >> 11, cc = j & 2047;
      WHI[j] = Wh[(size_t)k * 2048 + (cc & 3) * 512 + (cc >> 2)];
    } else {
      int cc = idx - (409 * 2048 + 512 * 2048);
      BLI[cc] = bl[(cc & 3) * 512 + (cc >> 2)];
    }
  }
}

// ---------------- conv stack (unchanged from R1, validated) ----------------
__global__ __launch_bounds__(128) void conv_kernel(
    const float* __restrict__ img,
    const float* __restrict__ k1, const float* __restrict__ cb1, const float* __restrict__ g1,
    const float* __restrict__ be1, const float* __restrict__ mm1, const float* __restrict__ mv1,
    const float* __restrict__ k2, const float* __restrict__ cb2, const float* __restrict__ g2,
    const float* __restrict__ be2, const float* __restrict__ mm2, const float* __restrict__ mv2,
    const float* __restrict__ k3, const float* __restrict__ cb3, const float* __restrict__ g3,
    const float* __restrict__ be3, const float* __restrict__ mm3, const float* __restrict__ mv3,
    float* __restrict__ ws) {
  __shared__ float s_in[784];
  __shared__ float s_y1[13 * 13 * 8];
  __shared__ float s_y2[6 * 6 * 16];
  __shared__ float s_k1[72], s_k2[1152], s_k3[4608];
  __shared__ float s_s1[8], s_b1[8], s_s2[16], s_b2[16], s_s3[32], s_b3[32];
  float* FEATP = ws + OFF_FEATP;
  const int n = blockIdx.x, tid = threadIdx.x;
  const float* ip = img + (size_t)n * 784;
  for (int i = tid; i < 784; i += 128) s_in[i] = ip[i];
  for (int i = tid; i < 72; i += 128) s_k1[i] = k1[i];
  for (int i = tid; i < 1152; i += 128) s_k2[i] = k2[i];
  for (int i = tid; i < 4608; i += 128) s_k3[i] = k3[i];
  if (tid < 8) {
    float s = g1[tid] * rsqrtf(mv1[tid] + 1e-3f);
    s_s1[tid] = s; s_b1[tid] = (cb1[tid] - mm1[tid]) * s + be1[tid];
  } else if (tid >= 32 && tid < 48) {
    int c = tid - 32;
    float s = g2[c] * rsqrtf(mv2[c] + 1e-3f);
    s_s2[c] = s; s_b2[c] = (cb2[c] - mm2[c]) * s + be2[c];
  } else if (tid >= 64 && tid < 96) {
    int c = tid - 64;
    float s = g3[c] * rsqrtf(mv3[c] + 1e-3f);
    s_s3[c] = s; s_b3[c] = (cb3[c] - mm3[c]) * s + be3[c];
  }
  __syncthreads();
  for (int idx = tid; idx < 13 * 13 * 8; idx += 128) {
    int co = idx & 7, pos = idx >> 3;
    int j = pos % 13, i = pos / 13;
    float acc = 0.f;
    #pragma unroll
    for (int ky = 0; ky < 3; ++ky)
      #pragma unroll
      for (int kx = 0; kx < 3; ++kx)
        acc += s_in[(2 * i + ky) * 28 + (2 * j + kx)] * s_k1[(ky * 3 + kx) * 8 + co];
    float v = acc * s_s1[co] + s_b1[co];
    s_y1[idx] = v > 0.f ? v : 0.f;
  }
  __syncthreads();
  for (int idx = tid; idx < 6 * 6 * 16; idx += 128) {
    int co = idx & 15, pos = idx >> 4;
    int j = pos % 6, i = pos / 6;
    float acc = 0.f;
    for (int ky = 0; ky < 3; ++ky)
      for (int kx = 0; kx < 3; ++kx) {
        int base = ((2 * i + ky) * 13 + (2 * j + kx)) * 8;
        int kb = (ky * 3 + kx) * 128 + co;
        #pragma unroll
        for (int ci = 0; ci < 8; ++ci) acc += s_y1[base + ci] * s_k2[kb + ci * 16];
      }
    float v = acc * s_s2[co] + s_b2[co];
    s_y2[idx] = v > 0.f ? v : 0.f;
  }
  __syncthreads();
  for (int idx = tid; idx < 128; idx += 128) {
    int co = idx & 31, pos = idx >> 5;
    int j = pos & 1, i = pos >> 1;
    float acc = 0.f;
    for (int ky = 0; ky < 3; ++ky)
      for (int kx = 0; kx < 3; ++kx) {
        int base = ((2 * i + ky) * 6 + (2 * j + kx)) * 16;
        int kb = (ky * 3 + kx) * 512 + co;
        #pragma unroll
        for (int ci = 0; ci < 16; ++ci) acc += s_y2[base + ci] * s_k3[kb + ci * 32];
      }
    float v = acc * s_s3[co] + s_b3[co];
    FEATP[(size_t)n * 128 + idx] = v > 0.f ? v : 0.f;
  }
}

// ---------------- persistent LSTM scan: LDS-resident weights ----------------
// 256 blocks x 512 threads, 1 block/CU. Roles:
//  0..63   AZ : z_rv gemm (32 zcols, k=256) + gate/c/h update. W in LDS 32KB.
//  64..79  AO : outpre = outh + rv@Wo_rv + bo (32 ucols, k=256). W 32KB.
//  80..143 BL : zacc LO = x@Wx + label + bl + h[0:256]@Wh (32 zcols). W 51KB.
//  144..175 BH: zacc HI = h[256:512]@Wh (64 zcols). W 64KB.
//  176..191 OL: outh LO (32 ucols, Wo rows 0..255). 192..207 OHI: HI rows 256..511.
//  208..217 PL: hidpre LO (32 jcols). 218..222 PHI: HI (64 jcols).
//  223..254 CA: per-batch attention + ring (LDS-resident) + logits/softmax/out.
//  255: idle (barrier only).
__global__ __launch_bounds__(512) void lstm_kernel(
    const int* __restrict__ labels,
    const float* __restrict__ Wo, const float* __restrict__ bo,
    const float* __restrict__ Wp, const float* __restrict__ bp,
    const float* __restrict__ Wf, const float* __restrict__ bf,
    float* __restrict__ ws, float* __restrict__ out) {
  extern __shared__ float dyn[];
  const float* FEATP = ws + OFF_FEATP;
  const float* WXI   = ws + OFF_WXI;
  const float* WHI   = ws + OFF_WHI;
  const float* BLI   = ws + OFF_BLI;
  float* ZP0    = ws + OFF_ZP0;
  float* ZP1    = ws + OFF_ZP1;
  float* OH0    = ws + OFF_OH0;
  float* OH1    = ws + OFF_OH1;
  float* HP0    = ws + OFF_HP0;
  float* HP1    = ws + OFF_HP1;
  float* OUTPRE = ws + OFF_OUTPRE;
  float* HT     = ws + OFF_HT;
  float* RVT    = ws + OFF_RVT;
  int*   BARp   = (int*)(ws + OFF_BAR);

  const int bid = blockIdx.x;
  const int tid = threadIdx.x;
  int barGen = 0;

  auto gbar = [&]() {
    __syncthreads();
    ++barGen;
    if (tid == 0) {
      __builtin_amdgcn_fence(__ATOMIC_RELEASE, "agent");
      int a = __hip_atomic_fetch_add(&BARp[(bid & 7) << 6], 1, __ATOMIC_RELAXED,
                                     __HIP_MEMORY_SCOPE_AGENT);
      if ((a & 31) == 31) {
        int r = __hip_atomic_fetch_add(&BARp[512], 1, __ATOMIC_RELAXED,
                                       __HIP_MEMORY_SCOPE_AGENT);
        if ((r & 7) == 7) {
          __hip_atomic_fetch_add(&BARp[576], 1, __ATOMIC_RELAXED,
                                 __HIP_MEMORY_SCOPE_AGENT);
        }
      }
      while (__hip_atomic_load(&BARp[576], __ATOMIC_RELAXED,
                               __HIP_MEMORY_SCOPE_AGENT) < barGen) {
        __builtin_amdgcn_s_sleep(2);
      }
      __builtin_amdgcn_fence(__ATOMIC_ACQUIRE, "agent");
    }
    __syncthreads();
  };

  // stage 8192-float [256][32] global buffer into [256][36]-padded LDS tile
  auto stage_act = [&](float* dst, const float* __restrict__ src) {
    for (int i = tid; i < 8192; i += 512) dst[(i >> 5) * 36 + (i & 31)] = src[i];
  };
  // 32-col gemm, k=256 split in 2 halves across tid>>8; result in part[512][4]
  auto gemm32 = [&](const float* W, const float* act, float* part) {
    const int c = tid & 31, bq = (tid >> 5) & 7, kh = tid >> 8;
    const float* wp = W + kh * 128 * 32 + c;
    const float* rp = act + kh * 128 * 36 + bq * 4;
    float4 a = {0.f, 0.f, 0.f, 0.f};
    #pragma unroll 4
    for (int k = 0; k < 128; ++k) {
      float w = wp[k * 32];
      float4 r = *(const float4*)(rp + k * 36);
      a.x = fmaf(w, r.x, a.x); a.y = fmaf(w, r.y, a.y);
      a.z = fmaf(w, r.z, a.z); a.w = fmaf(w, r.w, a.w);
    }
    *(float4*)(part + tid * 4) = a;
  };

  // ---------------- one-time init: weights -> LDS ----------------
  if (bid < 64) {            // AZ
    const int c0 = bid * 32;
    for (int i = tid; i < 8192; i += 512)
      dyn[i] = WXI[(size_t)(153 + (i >> 5)) * 2048 + c0 + (i & 31)];
    if (tid < 256) dyn[8192 + tid] = 0.f;  // Cst[b*8+u]
  } else if (bid < 80) {     // AO
    const int u0 = (bid - 64) * 32;
    for (int i = tid; i < 8192; i += 512)
      dyn[i] = Wo[(size_t)(512 + (i >> 5)) * 512 + u0 + (i & 31)];
    if (tid < 32) dyn[8192 + tid] = bo[u0 + tid];
  } else if (bid < 144) {    // BL
    const int c0 = (bid - 80) * 32;
    for (int i = tid; i < 4096; i += 512)
      dyn[i] = WXI[(size_t)(i >> 5) * 2048 + c0 + (i & 31)];
    for (int i = tid; i < 800; i += 512)
      dyn[4096 + i] = WXI[(size_t)(128 + (i >> 5)) * 2048 + c0 + (i & 31)];
    for (int i = tid; i < 8192; i += 512)
      dyn[4896 + i] = WHI[(size_t)(i >> 5) * 2048 + c0 + (i & 31)];
    if (tid < 32) dyn[13088 + tid] = BLI[c0 + tid];
  } else if (bid < 176) {    // BH
    const int c0 = (bid - 144) * 64;
    for (int i = tid; i < 16384; i += 512)
      dyn[i] = WHI[(size_t)(256 + (i >> 6)) * 2048 + c0 + (i & 63)];
  } else if (bid < 192) {    // OL
    const int u0 = (bid - 176) * 32;
    for (int i = tid; i < 8192; i += 512)
      dyn[i] = Wo[(size_t)(i >> 5) * 512 + u0 + (i & 31)];
  } else if (bid < 208) {    // OHI
    const int u0 = (bid - 192) * 32;
    for (int i = tid; i < 8192; i += 512)
      dyn[i] = Wo[(size_t)(256 + (i >> 5)) * 512 + u0 + (i & 31)];
  } else if (bid < 218) {    // PL
    const int j0 = (bid - 208) * 32;
    for (int i = tid; i < 8192; i += 512)
      dyn[i] = Wp[(size_t)(i >> 5) * 320 + j0 + (i & 31)];
  } else if (bid < 223) {    // PHI
    const int j0 = (bid - 218) * 64;
    for (int i = tid; i < 16384; i += 512)
      dyn[i] = Wp[(size_t)(256 + (i >> 6)) * 320 + j0 + (i & 63)];
  } else if (bid < 255) {    // CA
    for (int i = tid; i < 17000; i += 512) dyn[i] = 0.f;       // ring[250][68]
    for (int i = tid; i < 12800; i += 512) dyn[17000 + i] = Wf[i];
    for (int i = tid; i < 320; i += 512) dyn[29800 + i] = bp[i];
    if (tid < 25) dyn[30120 + tid] = bf[tid];
  }
  __syncthreads();

  // ---------------- phase bodies ----------------
  auto phaseA = [&](int t) {
    if (bid < 64) {          // AZ: gates for step t (t<250)
      if (t < 250) {
        const int c0 = bid * 32;
        float* Wz = dyn; float* Cst = dyn + 8192; float* rvT = dyn + 8448;
        float* zf = dyn + 17664; float* part = dyn + 18688;
        stage_act(rvT, RVT);
        for (int i = tid; i < 1024; i += 512) {
          int c = i & 31, b = i >> 5;
          zf[b * 32 + c] = ZP0[(size_t)b * 2048 + c0 + c] + ZP1[(size_t)b * 2048 + c0 + c];
        }
        __syncthreads();
        gemm32(Wz, rvT, part);
        __syncthreads();
        if (tid < 256) {
          float4 p0 = *(float4*)(part + tid * 4);
          float4 p1 = *(float4*)(part + (tid + 256) * 4);
          int c = tid & 31, bq = tid >> 5;
          zf[(bq * 4 + 0) * 32 + c] += p0.x + p1.x;
          zf[(bq * 4 + 1) * 32 + c] += p0.y + p1.y;
          zf[(bq * 4 + 2) * 32 + c] += p0.z + p1.z;
          zf[(bq * 4 + 3) * 32 + c] += p0.w + p1.w;
        }
        __syncthreads();
        if (tid < 256) {
          int u = tid & 7, b = tid >> 3;
          float4 z = *(float4*)(zf + b * 32 + u * 4);
          float ig = sigm(z.x), fg = sigm(z.y), gg = tanhf(z.z), og = sigm(z.w);
          float cc = fg * Cst[b * 8 + u] + ig * gg;
          Cst[b * 8 + u] = cc;
          HT[(size_t)(bid * 8 + u) * 32 + b] = og * tanhf(cc);
        }
      }
    } else if (bid < 80) {   // AO: outpre_{t-1} (t>=1)
      if (t >= 1) {
        const int u0 = (bid - 64) * 32;
        float* W = dyn; float* bo_l = dyn + 8192; float* rvT = dyn + 8224;
        float* of = dyn + 17440; float* part = dyn + 18464;
        stage_act(rvT, RVT);
        for (int i = tid; i < 1024; i += 512) {
          int u = i & 31, b = i >> 5;
          of[b * 32 + u] = OH0[b * 512 + u0 + u] + OH1[b * 512 + u0 + u];
        }
        __syncthreads();
        gemm32(W, rvT, part);
        __syncthreads();
        if (tid < 256) {
          float4 p0 = *(float4*)(part + tid * 4);
          float4 p1 = *(float4*)(part + (tid + 256) * 4);
          int u = tid & 31, bq = tid >> 5;
          float bv = bo_l[u];
          OUTPRE[(bq * 4 + 0) * 512 + u0 + u] = p0.x + p1.x + of[(bq * 4 + 0) * 32 + u] + bv;
          OUTPRE[(bq * 4 + 1) * 512 + u0 + u] = p0.y + p1.y + of[(bq * 4 + 1) * 32 + u] + bv;
          OUTPRE[(bq * 4 + 2) * 512 + u0 + u] = p0.z + p1.z + of[(bq * 4 + 2) * 32 + u] + bv;
          OUTPRE[(bq * 4 + 3) * 512 + u0 + u] = p0.w + p1.w + of[(bq * 4 + 3) * 32 + u] + bv;
        }
      }
    }
  };

  auto phaseB = [&](int tt1) {
    if (bid >= 80 && bid < 144) {        // BL
      const int c0 = (bid - 80) * 32;
      float* Wxf = dyn; float* Wlab = dyn + 4096; float* Whl = dyn + 4896;
      float* blc = dyn + 13088; int* slab = (int*)(dyn + 13120);
      float* xT = dyn + 13152; float* hTl = dyn + 17760; float* part = dyn + 26976;
      for (int i = tid; i < 4096; i += 512) {
        int b = i >> 7, k = i & 127;
        xT[k * 36 + b] = FEATP[((size_t)b * 250 + tt1) * 128 + k];
      }
      stage_act(hTl, HT);
      if (tid < 32) slab[tid] = labels[tid * 250 + tt1];
      __syncthreads();
      {
        const int c = tid & 31, bq = (tid >> 5) & 7, kh = tid >> 8;
        float4 a = {0.f, 0.f, 0.f, 0.f};
        if (kh == 0) {
          const float* wp = Wxf + c; const float* rp = xT + bq * 4;
          #pragma unroll 4
          for (int k = 0; k < 128; ++k) {
            float w = wp[k * 32]; float4 r = *(const float4*)(rp + k * 36);
            a.x = fmaf(w, r.x, a.x); a.y = fmaf(w, r.y, a.y);
            a.z = fmaf(w, r.z, a.z); a.w = fmaf(w, r.w, a.w);
          }
          wp = Whl + c; rp = hTl + bq * 4;
          #pragma unroll 4
          for (int k = 0; k < 64; ++k) {
            float w = wp[k * 32]; float4 r = *(const float4*)(rp + k * 36);
            a.x = fmaf(w, r.x, a.x); a.y = fmaf(w, r.y, a.y);
            a.z = fmaf(w, r.z, a.z); a.w = fmaf(w, r.w, a.w);
          }
        } else {
          const float* wp = Whl + 64 * 32 + c; const float* rp = hTl + 64 * 36 + bq * 4;
          #pragma unroll 4
          for (int k = 0; k < 192; ++k) {
            float w = wp[k * 32]; float4 r = *(const float4*)(rp + k * 36);
            a.x = fmaf(w, r.x, a.x); a.y = fmaf(w, r.y, a.y);
            a.z = fmaf(w, r.z, a.z); a.w = fmaf(w, r.w, a.w);
          }
        }
        *(float4*)(part + tid * 4) = a;
      }
      __syncthreads();
      if (tid < 256) {
        float4 p0 = *(float4*)(part + tid * 4);
        float4 p1 = *(float4*)(part + (tid + 256) * 4);
        int c = tid & 31, bq = tid >> 5;
        float base = blc[c];
        int b0 = bq * 4;
        ZP0[(size_t)(b0 + 0) * 2048 + c0 + c] = p0.x + p1.x + base + Wlab[slab[b0 + 0] * 32 + c];
        ZP0[(size_t)(b0 + 1) * 2048 + c0 + c] = p0.y + p1.y + base + Wlab[slab[b0 + 1] * 32 + c];
        ZP0[(size_t)(b0 + 2) * 2048 + c0 + c] = p0.z + p1.z + base + Wlab[slab[b0 + 2] * 32 + c];
        ZP0[(size_t)(b0 + 3) * 2048 + c0 + c] = p0.w + p1.w + base + Wlab[slab[b0 + 3] * 32 + c];
      }
    } else if (bid >= 144 && bid < 176) { // BH
      const int c0 = (bid - 144) * 64;
      float* W = dyn; float* hTh = dyn + 16384;
      stage_act(hTh, HT + 8192);
      __syncthreads();
      const int c = tid & 63, bq = tid >> 6;
      const float* wp = W + c; const float* rp = hTh + bq * 4;
      float4 a = {0.f, 0.f, 0.f, 0.f};
      #pragma unroll 4
      for (int k = 0; k < 256; ++k) {
        float w = wp[k * 64]; float4 r = *(const float4*)(rp + k * 36);
        a.x = fmaf(w, r.x, a.x); a.y = fmaf(w, r.y, a.y);
        a.z = fmaf(w, r.z, a.z); a.w = fmaf(w, r.w, a.w);
      }
      ZP1[(size_t)(bq * 4 + 0) * 2048 + c0 + c] = a.x;
      ZP1[(size_t)(bq * 4 + 1) * 2048 + c0 + c] = a.y;
      ZP1[(size_t)(bq * 4 + 2) * 2048 + c0 + c] = a.z;
      ZP1[(size_t)(bq * 4 + 3) * 2048 + c0 + c] = a.w;
    } else if (bid >= 176 && bid < 218) { // OL / OHI / PL
      float* W = dyn; float* hT = dyn + 8192; float* part = dyn + 17408;
      const bool isOL = bid < 192, isOHI = (bid >= 192 && bid < 208);
      stage_act(hT, isOHI ? (HT + 8192) : HT);
      __syncthreads();
      gemm32(W, hT, part);
      __syncthreads();
      if (tid < 256) {
        float4 p0 = *(float4*)(part + tid * 4);
        float4 p1 = *(float4*)(part + (tid + 256) * 4);
        int c = tid & 31, bq = tid >> 5;
        float v0 = p0.x + p1.x, v1 = p0.y + p1.y, v2 = p0.z + p1.z, v3 = p0.w + p1.w;
        if (isOL) {
          const int u0 = (bid - 176) * 32;
          OH0[(bq * 4 + 0) * 512 + u0 + c] = v0;
          OH0[(bq * 4 + 1) * 512 + u0 + c] = v1;
          OH0[(bq * 4 + 2) * 512 + u0 + c] = v2;
          OH0[(bq * 4 + 3) * 512 + u0 + c] = v3;
        } else if (isOHI) {
          const int u0 = (bid - 192) * 32;
          OH1[(bq * 4 + 0) * 512 + u0 + c] = v0;
          OH1[(bq * 4 + 1) * 512 + u0 + c] = v1;
          OH1[(bq * 4 + 2) * 512 + u0 + c] = v2;
          OH1[(bq * 4 + 3) * 512 + u0 + c] = v3;
        } else {
          const int j0 = (bid - 208) * 32;
          HP0[(bq * 4 + 0) * 320 + j0 + c] = v0;
          HP0[(bq * 4 + 1) * 320 + j0 + c] = v1;
          HP0[(bq * 4 + 2) * 320 + j0 + c] = v2;
          HP0[(bq * 4 + 3) * 320 + j0 + c] = v3;
        }
      }
    } else if (bid >= 218 && bid < 223) { // PHI
      const int j0 = (bid - 218) * 64;
      float* W = dyn; float* hTh = dyn + 16384;
      stage_act(hTh, HT + 8192);
      __syncthreads();
      const int c = tid & 63, bq = tid >> 6;
      const float* wp = W + c; const float* rp = hTh + bq * 4;
      float4 a = {0.f, 0.f, 0.f, 0.f};
      #pragma unroll 4
      for (int k = 0; k < 256; ++k) {
        float w = wp[k * 64]; float4 r = *(const float4*)(rp + k * 36);
        a.x = fmaf(w, r.x, a.x); a.y = fmaf(w, r.y, a.y);
        a.z = fmaf(w, r.z, a.z); a.w = fmaf(w, r.w, a.w);
      }
      HP1[(bq * 4 + 0) * 320 + j0 + c] = a.x;
      HP1[(bq * 4 + 1) * 320 + j0 + c] = a.y;
      HP1[(bq * 4 + 2) * 320 + j0 + c] = a.z;
      HP1[(bq * 4 + 3) * 320 + j0 + c] = a.w;
    }
  };

  auto phaseC = [&](int t) {
    if (bid < 223 || bid >= 255) return;
    float* ring = dyn;             // [250][68]
    float* WfL  = dyn + 17000;
    float* bpL  = dyn + 29800;
    float* bfL  = dyn + 30120;
    float* hid  = dyn + 30152;     // 320
    float* kn   = dyn + 30472;     // 256
    float* att4 = dyn + 30728;     // [4][256]
    float* red  = dyn + 31752;     // 32
    float* msum = dyn + 31784;     // 16
    float* rvp  = dyn + 31800;     // 512
    float* to   = dyn + 32312;     // 512
    float* lp   = dyn + 32824;     // 400
    float* lg   = dyn + 33224;     // 32
    const int b = bid - 223;

    if (t >= 1) {  // softmax output for step t-1
      for (int i = tid; i < 512; i += 512) to[i] = tanhf(OUTPRE[b * 512 + i]);
      __syncthreads();
      if (tid < 400) {
        int l = tid % 25, p = tid / 25;
        float s = 0.f;
        #pragma unroll
        for (int q = 0; q < 32; ++q) { int k = p * 32 + q; s += to[k] * WfL[k * 25 + l]; }
        lp[p * 25 + l] = s;
      }
      __syncthreads();
      if (tid < 25) {
        float s = bfL[tid];
        #pragma unroll
        for (int p = 0; p < 16; ++p) s += lp[p * 25 + tid];
        lg[tid] = s;
      }
      __syncthreads();
      if (tid == 0) {
        float mx = lg[0];
        for (int l = 1; l < 25; ++l) mx = fmaxf(mx, lg[l]);
        float ss = 0.f;
        for (int l = 0; l < 25; ++l) ss += __expf(lg[l] - mx);
        lg[25] = mx; lg[26] = 1.f / ss;
      }
      __syncthreads();
      if (tid < 25)
        out[((size_t)b * 250 + (t - 1)) * 25 + tid] = __expf(lg[tid] - lg[25]) * lg[26];
    }
    if (t < 250) {  // attention -> rv_t, ring insert wv_t
      __syncthreads();
      if (tid < 320) hid[tid] = tanhf(HP0[b * 320 + tid] + HP1[b * 320 + tid] + bpL[tid]);
      __syncthreads();
      if (tid < 256) {
        float v = hid[64 + tid]; float pq = v * v;
        for (int off = 32; off; off >>= 1) pq += __shfl_down(pq, off, 64);
        if ((tid & 63) == 0) red[tid >> 6] = rsqrtf(fmaxf(pq, 1e-12f));
      }
      __syncthreads();
      if (tid < 256) kn[tid] = hid[64 + tid] * red[tid >> 6];
      __syncthreads();
      const int start = (250 - t) % 250;
      if (tid < 500) {
        int m = tid >> 1, dh = tid & 1;
        int p = start + m; if (p >= 250) p -= 250;
        const float* cell = ring + p * 68;
        const float* k0 = kn + dh * 128;
        float n2 = 0.f, d0 = 0.f, d1 = 0.f;
        #pragma unroll
        for (int s = 0; s < 64; s += 4) {
          float4 q = *(const float4*)(cell + s);
          n2 += q.x * q.x + q.y * q.y + q.z * q.z + q.w * q.w;
          d0 += k0[s] * q.x + k0[s + 1] * q.y + k0[s + 2] * q.z + k0[s + 3] * q.w;
          d1 += k0[64 + s] * q.x + k0[64 + s + 1] * q.y + k0[64 + s + 2] * q.z + k0[64 + s + 3] * q.w;
        }
        float rs = rsqrtf(fmaxf(n2, 1e-12f));
        att4[(2 * dh) * 256 + m] = d0 * rs;
        att4[(2 * dh + 1) * 256 + m] = d1 * rs;
      }
      __syncthreads();
      {
        int h4 = tid >> 7, mm = tid & 127;
        float v0 = att4[h4 * 256 + mm];
        bool has2 = (mm + 128) < 250;
        float v1 = has2 ? att4[h4 * 256 + mm + 128] : -3.0e38f;
        float mx = fmaxf(v0, v1);
        for (int off = 32; off; off >>= 1) mx = fmaxf(mx, __shfl_down(mx, off, 64));
        if ((tid & 63) == 0) red[tid >> 6] = mx;
        __syncthreads();
        float MX = fmaxf(red[h4 * 2], red[h4 * 2 + 1]);
        float e0 = __expf(v0 - MX);
        float e1 = has2 ? __expf(v1 - MX) : 0.f;
        att4[h4 * 256 + mm] = e0;
        if (has2) att4[h4 * 256 + mm + 128] = e1;
        float sm_ = e0 + e1;
        for (int off = 32; off; off >>= 1) sm_ += __shfl_down(sm_, off, 64);
        if ((tid & 63) == 0) red[8 + (tid >> 6)] = sm_;
        __syncthreads();
        if (tid < 4) msum[tid] = red[8 + tid * 2] + red[8 + tid * 2 + 1];
        __syncthreads();
      }
      {
        int h4 = tid >> 7, s = tid & 63, mh = (tid >> 6) & 1;
        float a = 0.f;
        for (int m = mh * 125; m < mh * 125 + 125; ++m) {
          int p = start + m; if (p >= 250) p -= 250;
          a += att4[h4 * 256 + m] * ring[p * 68 + s];
        }
        rvp[tid] = a;
      }
      __syncthreads();
      if (tid < 256) {
        int h4 = tid >> 6, s = tid & 63;
        float rv = (rvp[h4 * 128 + s] + rvp[h4 * 128 + 64 + s]) / msum[h4];
        RVT[(h4 * 64 + s) * 32 + b] = rv;
      }
      __syncthreads();
      if (tid < 64) {
        int ip = start + 249; if (ip >= 250) ip -= 250;
        ring[ip * 68 + tid] = hid[tid];
      }
    }
  };

  // ---------------- main sequence ----------------
  phaseB(0);  // prologue: zacc_0 (h=0 via memset HT)
  gbar();
  for (int t = 0; t <= 250; ++t) {
    phaseA(t);
    gbar();
    if (t < 250) {
      int tt1 = (t + 1 <= 249) ? t + 1 : 249;
      phaseB(tt1);
      gbar();
    }
    phaseC(t);
    if (t < 250) gbar();
  }
}

extern "C" void kernel_launch(void* const* d_in, const int* in_sizes, int n_in,
                              void* d_out, int out_size, void* d_ws, size_t ws_size,
                              hipStream_t stream) {
  const float* images = (const float*)d_in[0];
  const int* labels = (const int*)d_in[1];
  const float* k1  = (const float*)d_in[2];
  const float* cb1 = (const float*)d_in[3];
  const float* g1  = (const float*)d_in[4];
  const float* be1 = (const float*)d_in[5];
  const float* mm1 = (const float*)d_in[6];
  const float* mv1 = (const float*)d_in[7];
  const float* k2  = (const float*)d_in[8];
  const float* cb2 = (const float*)d_in[9];
  const float* g2  = (const float*)d_in[10];
  const float* be2 = (const float*)d_in[11];
  const float* mm2 = (const float*)d_in[12];
  const float* mv2 = (const float*)d_in[13];
  const float* k3  = (const float*)d_in[14];
  const float* cb3 = (const float*)d_in[15];
  const float* g3  = (const float*)d_in[16];
  const float* be3 = (const float*)d_in[17];
  const float* mm3 = (const float*)d_in[18];
  const float* mv3 = (const float*)d_in[19];
  const float* Wx  = (const float*)d_in[20];
  const float* Wh  = (const float*)d_in[21];
  const float* bl  = (const float*)d_in[22];
  const float* Wp  = (const float*)d_in[23];
  const float* bp  = (const float*)d_in[24];
  const float* Wo  = (const float*)d_in[25];
  const float* bo  = (const float*)d_in[26];
  const float* Wf  = (const float*)d_in[27];
  const float* bf  = (const float*)d_in[28];
  float* ws = (float*)d_ws;

  hipFuncSetAttribute((const void*)lstm_kernel,
                      hipFuncAttributeMaxDynamicSharedMemorySize, DYN_BYTES);

  // zero activation/state/barrier region (ws poisoned 0xAA before each call)
  hipMemsetAsync((char*)d_ws + OFF_ZP0 * sizeof(float), 0,
                 (WS_FLOATS - OFF_ZP0) * sizeof(float), stream);
  prep_kernel<<<1024, 256, 0, stream>>>(Wx, Wh, bl, ws);
  conv_kernel<<<8000, 128, 0, stream>>>(images,
      k1, cb1, g1, be1, mm1, mv1,
      k2, cb2, g2, be2, mm2, mv2,
      k3, cb3, g3, be3, mm3, mv3, ws);
  lstm_kernel<<<256, 512, DYN_BYTES, stream>>>(labels, Wo, bo, Wp, bp, Wf, bf, ws,
                                               (float*)d_out);
}

// Round 3
// 8613.557 us; speedup vs baseline: 3.7122x; 1.4854x over previous
//
#include <hip/hip_runtime.h>

// ---------------- problem constants ----------------
// B=32, T=250, FEAT=128, CLASSES=25, UNITS=512, CELL=64, HEADS=4, IN_LSTM=409

// ---------------- scratch layout (floats) ----------------
constexpr size_t OFF_FEATP  = 0;                              // [8000][128]
constexpr size_t OFF_WXI    = OFF_FEATP + (size_t)8000 * 128; // [409][2048] gate-interleaved
constexpr size_t OFF_WHI    = OFF_WXI + (size_t)409 * 2048;   // [512][2048]
constexpr size_t OFF_BLI    = OFF_WHI + (size_t)512 * 2048;   // [2048]
constexpr size_t OFF_ZP0    = OFF_BLI + 2048;                 // [32][2048] zacc partial LO (incl label+bl)
constexpr size_t OFF_ZP1    = OFF_ZP0 + (size_t)32 * 2048;    // [32][2048] zacc partial HI
constexpr size_t OFF_OH0    = OFF_ZP1 + (size_t)32 * 2048;    // [32][512] outh partial LO
constexpr size_t OFF_OH1    = OFF_OH0 + (size_t)32 * 512;     // [32][512] outh partial HI
constexpr size_t OFF_HP0    = OFF_OH1 + (size_t)32 * 512;     // [32][320] hidpre partial LO
constexpr size_t OFF_HP1    = OFF_HP0 + (size_t)32 * 320;     // [32][320] hidpre partial HI
constexpr size_t OFF_OUTPRE = OFF_HP1 + (size_t)32 * 320;     // [32][512]
constexpr size_t OFF_HT     = OFF_OUTPRE + (size_t)32 * 512;  // [512][32] h transposed
constexpr size_t OFF_RVT    = OFF_HT + (size_t)512 * 32;      // [256][32] rv transposed
constexpr size_t OFF_BAR    = OFF_RVT + (size_t)256 * 32;     // barrier ints
constexpr size_t WS_FLOATS  = OFF_BAR + 1024;

constexpr int DYN_FLOATS = 34816;                 // 136 KB dynamic LDS
constexpr int DYN_BYTES  = DYN_FLOATS * 4;

__device__ __forceinline__ float sigm(float x) { return 1.f / (1.f + __expf(-x)); }

// LLC-coherent (sc0 sc1) accesses: read/write the device coherence point
// directly so NO cache invalidate/writeback fences are needed anywhere.
__device__ __forceinline__ float ld_sc(const float* p) {
  return __hip_atomic_load(p, __ATOMIC_RELAXED, __HIP_MEMORY_SCOPE_AGENT);
}
__device__ __forceinline__ void st_sc(float* p, float v) {
  __hip_atomic_store(p, v, __ATOMIC_RELAXED, __HIP_MEMORY_SCOPE_AGENT);
}

// ---------------- weight re-layout: gate-interleaved Wx/Wh/bl ----------------
__global__ __launch_bounds__(256) void prep_kernel(const float* __restrict__ Wx,
                                                   const float* __restrict__ Wh,
                                                   const float* __restrict__ bl,
                                                   float* __restrict__ ws) {
  float* WXI = ws + OFF_WXI;
  float* WHI = ws + OFF_WHI;
  float* BLI = ws + OFF_BLI;
  const int total = 409 * 2048 + 512 * 2048 + 2048;
  for (int idx = blockIdx.x * blockDim.x + threadIdx.x; idx < total;
       idx += gridDim.x * blockDim.x) {
    if (idx < 409 * 2048) {
      int k = idx >> 11, cc = idx & 2047;
      WXI[idx] = Wx[(size_t)k * 2048 + (cc & 3) * 512 + (cc >> 2)];
    } else if (idx < 409 * 2048 + 512 * 2048) {
      int j = idx - 409 * 2048;
      int k = j >> 11, cc = j & 2047;
      WHI[j] = Wh[(size_t)k * 2048 + (cc & 3) * 512 + (cc >> 2)];
    } else {
      int cc = idx - (409 * 2048 + 512 * 2048);
      BLI[cc] = bl[(cc & 3) * 512 + (cc >> 2)];
    }
  }
}

// ---------------- conv stack (validated) ----------------
__global__ __launch_bounds__(128) void conv_kernel(
    const float* __restrict__ img,
    const float* __restrict__ k1, const float* __restrict__ cb1, const float* __restrict__ g1,
    const float* __restrict__ be1, const float* __restrict__ mm1, const float* __restrict__ mv1,
    const float* __restrict__ k2, const float* __restrict__ cb2, const float* __restrict__ g2,
    const float* __restrict__ be2, const float* __restrict__ mm2, const float* __restrict__ mv2,
    const float* __restrict__ k3, const float* __restrict__ cb3, const float* __restrict__ g3,
    const float* __restrict__ be3, const float* __restrict__ mm3, const float* __restrict__ mv3,
    float* __restrict__ ws) {
  __shared__ float s_in[784];
  __shared__ float s_y1[13 * 13 * 8];
  __shared__ float s_y2[6 * 6 * 16];
  __shared__ float s_k1[72], s_k2[1152], s_k3[4608];
  __shared__ float s_s1[8], s_b1[8], s_s2[16], s_b2[16], s_s3[32], s_b3[32];
  float* FEATP = ws + OFF_FEATP;
  const int n = blockIdx.x, tid = threadIdx.x;
  const float* ip = img + (size_t)n * 784;
  for (int i = tid; i < 784; i += 128) s_in[i] = ip[i];
  for (int i = tid; i < 72; i += 128) s_k1[i] = k1[i];
  for (int i = tid; i < 1152; i += 128) s_k2[i] = k2[i];
  for (int i = tid; i < 4608; i += 128) s_k3[i] = k3[i];
  if (tid < 8) {
    float s = g1[tid] * rsqrtf(mv1[tid] + 1e-3f);
    s_s1[tid] = s; s_b1[tid] = (cb1[tid] - mm1[tid]) * s + be1[tid];
  } else if (tid >= 32 && tid < 48) {
    int c = tid - 32;
    float s = g2[c] * rsqrtf(mv2[c] + 1e-3f);
    s_s2[c] = s; s_b2[c] = (cb2[c] - mm2[c]) * s + be2[c];
  } else if (tid >= 64 && tid < 96) {
    int c = tid - 64;
    float s = g3[c] * rsqrtf(mv3[c] + 1e-3f);
    s_s3[c] = s; s_b3[c] = (cb3[c] - mm3[c]) * s + be3[c];
  }
  __syncthreads();
  for (int idx = tid; idx < 13 * 13 * 8; idx += 128) {
    int co = idx & 7, pos = idx >> 3;
    int j = pos % 13, i = pos / 13;
    float acc = 0.f;
    #pragma unroll
    for (int ky = 0; ky < 3; ++ky)
      #pragma unroll
      for (int kx = 0; kx < 3; ++kx)
        acc += s_in[(2 * i + ky) * 28 + (2 * j + kx)] * s_k1[(ky * 3 + kx) * 8 + co];
    float v = acc * s_s1[co] + s_b1[co];
    s_y1[idx] = v > 0.f ? v : 0.f;
  }
  __syncthreads();
  for (int idx = tid; idx < 6 * 6 * 16; idx += 128) {
    int co = idx & 15, pos = idx >> 4;
    int j = pos % 6, i = pos / 6;
    float acc = 0.f;
    for (int ky = 0; ky < 3; ++ky)
      for (int kx = 0; kx < 3; ++kx) {
        int base = ((2 * i + ky) * 13 + (2 * j + kx)) * 8;
        int kb = (ky * 3 + kx) * 128 + co;
        #pragma unroll
        for (int ci = 0; ci < 8; ++ci) acc += s_y1[base + ci] * s_k2[kb + ci * 16];
      }
    float v = acc * s_s2[co] + s_b2[co];
    s_y2[idx] = v > 0.f ? v : 0.f;
  }
  __syncthreads();
  for (int idx = tid; idx < 128; idx += 128) {
    int co = idx & 31, pos = idx >> 5;
    int j = pos & 1, i = pos >> 1;
    float acc = 0.f;
    for (int ky = 0; ky < 3; ++ky)
      for (int kx = 0; kx < 3; ++kx) {
        int base = ((2 * i + ky) * 6 + (2 * j + kx)) * 16;
        int kb = (ky * 3 + kx) * 512 + co;
        #pragma unroll
        for (int ci = 0; ci < 16; ++ci) acc += s_y2[base + ci] * s_k3[kb + ci * 32];
      }
    float v = acc * s_s3[co] + s_b3[co];
    FEATP[(size_t)n * 128 + idx] = v > 0.f ? v : 0.f;
  }
}

// ---------------- persistent LSTM scan: LDS-resident weights, fence-free ----------------
__global__ __launch_bounds__(512) void lstm_kernel(
    const int* __restrict__ labels,
    const float* __restrict__ Wo, const float* __restrict__ bo,
    const float* __restrict__ Wp, const float* __restrict__ bp,
    const float* __restrict__ Wf, const float* __restrict__ bf,
    float* __restrict__ ws, float* __restrict__ out) {
  extern __shared__ float dyn[];
  const float* FEATP = ws + OFF_FEATP;
  const float* WXI   = ws + OFF_WXI;
  const float* WHI   = ws + OFF_WHI;
  const float* BLI   = ws + OFF_BLI;
  float* ZP0    = ws + OFF_ZP0;
  float* ZP1    = ws + OFF_ZP1;
  float* OH0    = ws + OFF_OH0;
  float* OH1    = ws + OFF_OH1;
  float* HP0    = ws + OFF_HP0;
  float* HP1    = ws + OFF_HP1;
  float* OUTPRE = ws + OFF_OUTPRE;
  float* HT     = ws + OFF_HT;
  float* RVT    = ws + OFF_RVT;
  int*   BARp   = (int*)(ws + OFF_BAR);

  const int bid = blockIdx.x;
  const int tid = threadIdx.x;
  int barGen = 0;

  // Fence-free barrier: all shared data moves via sc0/sc1 (LLC) accesses, so
  // ordering only needs each wave's outstanding vmem drained before arrival.
  auto gbar = [&]() {
    asm volatile("s_waitcnt vmcnt(0) lgkmcnt(0)" ::: "memory");
    __syncthreads();
    ++barGen;
    if (tid == 0) {
      int a = __hip_atomic_fetch_add(&BARp[(bid & 7) << 6], 1, __ATOMIC_RELAXED,
                                     __HIP_MEMORY_SCOPE_AGENT);
      if ((a & 31) == 31) {
        int r = __hip_atomic_fetch_add(&BARp[512], 1, __ATOMIC_RELAXED,
                                       __HIP_MEMORY_SCOPE_AGENT);
        if ((r & 7) == 7) {
          __hip_atomic_fetch_add(&BARp[576], 1, __ATOMIC_RELAXED,
                                 __HIP_MEMORY_SCOPE_AGENT);
        }
      }
      while (__hip_atomic_load(&BARp[576], __ATOMIC_RELAXED,
                               __HIP_MEMORY_SCOPE_AGENT) < barGen) {
        __builtin_amdgcn_s_sleep(2);
      }
    }
    __syncthreads();
  };

  // stage 8192-float [256][32] global buffer into [256][36]-padded LDS tile
  auto stage_act = [&](float* dst, const float* __restrict__ src) {
    for (int i = tid; i < 8192; i += 512) dst[(i >> 5) * 36 + (i & 31)] = ld_sc(&src[i]);
  };
  // 32-col gemm, k=256 split in 2 halves across tid>>8; result in part[512][4]
  auto gemm32 = [&](const float* W, const float* act, float* part) {
    const int c = tid & 31, bq = (tid >> 5) & 7, kh = tid >> 8;
    const float* wp = W + kh * 128 * 32 + c;
    const float* rp = act + kh * 128 * 36 + bq * 4;
    float4 a = {0.f, 0.f, 0.f, 0.f};
    #pragma unroll 4
    for (int k = 0; k < 128; ++k) {
      float w = wp[k * 32];
      float4 r = *(const float4*)(rp + k * 36);
      a.x = fmaf(w, r.x, a.x); a.y = fmaf(w, r.y, a.y);
      a.z = fmaf(w, r.z, a.z); a.w = fmaf(w, r.w, a.w);
    }
    *(float4*)(part + tid * 4) = a;
  };

  // ---------------- one-time init: weights -> LDS ----------------
  if (bid < 64) {            // AZ
    const int c0 = bid * 32;
    for (int i = tid; i < 8192; i += 512)
      dyn[i] = WXI[(size_t)(153 + (i >> 5)) * 2048 + c0 + (i & 31)];
    if (tid < 256) dyn[8192 + tid] = 0.f;  // Cst[b*8+u]
  } else if (bid < 80) {     // AO
    const int u0 = (bid - 64) * 32;
    for (int i = tid; i < 8192; i += 512)
      dyn[i] = Wo[(size_t)(512 + (i >> 5)) * 512 + u0 + (i & 31)];
    if (tid < 32) dyn[8192 + tid] = bo[u0 + tid];
  } else if (bid < 144) {    // BL
    const int c0 = (bid - 80) * 32;
    for (int i = tid; i < 4096; i += 512)
      dyn[i] = WXI[(size_t)(i >> 5) * 2048 + c0 + (i & 31)];
    for (int i = tid; i < 800; i += 512)
      dyn[4096 + i] = WXI[(size_t)(128 + (i >> 5)) * 2048 + c0 + (i & 31)];
    for (int i = tid; i < 8192; i += 512)
      dyn[4896 + i] = WHI[(size_t)(i >> 5) * 2048 + c0 + (i & 31)];
    if (tid < 32) dyn[13088 + tid] = BLI[c0 + tid];
  } else if (bid < 176) {    // BH
    const int c0 = (bid - 144) * 64;
    for (int i = tid; i < 16384; i += 512)
      dyn[i] = WHI[(size_t)(256 + (i >> 6)) * 2048 + c0 + (i & 63)];
  } else if (bid < 192) {    // OL
    const int u0 = (bid - 176) * 32;
    for (int i = tid; i < 8192; i += 512)
      dyn[i] = Wo[(size_t)(i >> 5) * 512 + u0 + (i & 31)];
  } else if (bid < 208) {    // OHI
    const int u0 = (bid - 192) * 32;
    for (int i = tid; i < 8192; i += 512)
      dyn[i] = Wo[(size_t)(256 + (i >> 5)) * 512 + u0 + (i & 31)];
  } else if (bid < 218) {    // PL
    const int j0 = (bid - 208) * 32;
    for (int i = tid; i < 8192; i += 512)
      dyn[i] = Wp[(size_t)(i >> 5) * 320 + j0 + (i & 31)];
  } else if (bid < 223) {    // PHI
    const int j0 = (bid - 218) * 64;
    for (int i = tid; i < 16384; i += 512)
      dyn[i] = Wp[(size_t)(256 + (i >> 6)) * 320 + j0 + (i & 63)];
  } else if (bid < 255) {    // CA
    for (int i = tid; i < 17000; i += 512) dyn[i] = 0.f;       // ring[250][68]
    for (int i = tid; i < 12800; i += 512) dyn[17000 + i] = Wf[i];
    for (int i = tid; i < 320; i += 512) dyn[29800 + i] = bp[i];
    if (tid < 25) dyn[30120 + tid] = bf[tid];
  }
  __syncthreads();

  // ---------------- phase bodies ----------------
  auto phaseA = [&](int t) {
    if (bid < 64) {          // AZ: gates for step t (t<250)
      if (t < 250) {
        const int c0 = bid * 32;
        float* Wz = dyn; float* Cst = dyn + 8192; float* rvT = dyn + 8448;
        float* zf = dyn + 17664; float* part = dyn + 18688;
        stage_act(rvT, RVT);
        for (int i = tid; i < 1024; i += 512) {
          int c = i & 31, b = i >> 5;
          zf[b * 32 + c] = ld_sc(&ZP0[(size_t)b * 2048 + c0 + c]) +
                           ld_sc(&ZP1[(size_t)b * 2048 + c0 + c]);
        }
        __syncthreads();
        gemm32(Wz, rvT, part);
        __syncthreads();
        if (tid < 256) {
          float4 p0 = *(float4*)(part + tid * 4);
          float4 p1 = *(float4*)(part + (tid + 256) * 4);
          int c = tid & 31, bq = tid >> 5;
          zf[(bq * 4 + 0) * 32 + c] += p0.x + p1.x;
          zf[(bq * 4 + 1) * 32 + c] += p0.y + p1.y;
          zf[(bq * 4 + 2) * 32 + c] += p0.z + p1.z;
          zf[(bq * 4 + 3) * 32 + c] += p0.w + p1.w;
        }
        __syncthreads();
        if (tid < 256) {
          int u = tid & 7, b = tid >> 3;
          float4 z = *(float4*)(zf + b * 32 + u * 4);
          float ig = sigm(z.x), fg = sigm(z.y), gg = tanhf(z.z), og = sigm(z.w);
          float cc = fg * Cst[b * 8 + u] + ig * gg;
          Cst[b * 8 + u] = cc;
          st_sc(&HT[(size_t)(bid * 8 + u) * 32 + b], og * tanhf(cc));
        }
      }
    } else if (bid < 80) {   // AO: outpre_{t-1} (t>=1)
      if (t >= 1) {
        const int u0 = (bid - 64) * 32;
        float* W = dyn; float* bo_l = dyn + 8192; float* rvT = dyn + 8224;
        float* of = dyn + 17440; float* part = dyn + 18464;
        stage_act(rvT, RVT);
        for (int i = tid; i < 1024; i += 512) {
          int u = i & 31, b = i >> 5;
          of[b * 32 + u] = ld_sc(&OH0[b * 512 + u0 + u]) + ld_sc(&OH1[b * 512 + u0 + u]);
        }
        __syncthreads();
        gemm32(W, rvT, part);
        __syncthreads();
        if (tid < 256) {
          float4 p0 = *(float4*)(part + tid * 4);
          float4 p1 = *(float4*)(part + (tid + 256) * 4);
          int u = tid & 31, bq = tid >> 5;
          float bv = bo_l[u];
          st_sc(&OUTPRE[(bq * 4 + 0) * 512 + u0 + u], p0.x + p1.x + of[(bq * 4 + 0) * 32 + u] + bv);
          st_sc(&OUTPRE[(bq * 4 + 1) * 512 + u0 + u], p0.y + p1.y + of[(bq * 4 + 1) * 32 + u] + bv);
          st_sc(&OUTPRE[(bq * 4 + 2) * 512 + u0 + u], p0.z + p1.z + of[(bq * 4 + 2) * 32 + u] + bv);
          st_sc(&OUTPRE[(bq * 4 + 3) * 512 + u0 + u], p0.w + p1.w + of[(bq * 4 + 3) * 32 + u] + bv);
        }
      }
    }
  };

  auto phaseB = [&](int tt1) {
    if (bid >= 80 && bid < 144) {        // BL
      const int c0 = (bid - 80) * 32;
      float* Wxf = dyn; float* Wlab = dyn + 4096; float* Whl = dyn + 4896;
      float* blc = dyn + 13088; int* slab = (int*)(dyn + 13120);
      float* xT = dyn + 13152; float* hTl = dyn + 17760; float* part = dyn + 26976;
      for (int i = tid; i < 4096; i += 512) {
        int b = i >> 7, k = i & 127;
        xT[k * 36 + b] = FEATP[((size_t)b * 250 + tt1) * 128 + k];
      }
      stage_act(hTl, HT);
      if (tid < 32) slab[tid] = labels[tid * 250 + tt1];
      __syncthreads();
      {
        const int c = tid & 31, bq = (tid >> 5) & 7, kh = tid >> 8;
        float4 a = {0.f, 0.f, 0.f, 0.f};
        if (kh == 0) {
          const float* wp = Wxf + c; const float* rp = xT + bq * 4;
          #pragma unroll 4
          for (int k = 0; k < 128; ++k) {
            float w = wp[k * 32]; float4 r = *(const float4*)(rp + k * 36);
            a.x = fmaf(w, r.x, a.x); a.y = fmaf(w, r.y, a.y);
            a.z = fmaf(w, r.z, a.z); a.w = fmaf(w, r.w, a.w);
          }
          wp = Whl + c; rp = hTl + bq * 4;
          #pragma unroll 4
          for (int k = 0; k < 64; ++k) {
            float w = wp[k * 32]; float4 r = *(const float4*)(rp + k * 36);
            a.x = fmaf(w, r.x, a.x); a.y = fmaf(w, r.y, a.y);
            a.z = fmaf(w, r.z, a.z); a.w = fmaf(w, r.w, a.w);
          }
        } else {
          const float* wp = Whl + 64 * 32 + c; const float* rp = hTl + 64 * 36 + bq * 4;
          #pragma unroll 4
          for (int k = 0; k < 192; ++k) {
            float w = wp[k * 32]; float4 r = *(const float4*)(rp + k * 36);
            a.x = fmaf(w, r.x, a.x); a.y = fmaf(w, r.y, a.y);
            a.z = fmaf(w, r.z, a.z); a.w = fmaf(w, r.w, a.w);
          }
        }
        *(float4*)(part + tid * 4) = a;
      }
      __syncthreads();
      if (tid < 256) {
        float4 p0 = *(float4*)(part + tid * 4);
        float4 p1 = *(float4*)(part + (tid + 256) * 4);
        int c = tid & 31, bq = tid >> 5;
        float base = blc[c];
        int b0 = bq * 4;
        st_sc(&ZP0[(size_t)(b0 + 0) * 2048 + c0 + c], p0.x + p1.x + base + Wlab[slab[b0 + 0] * 32 + c]);
        st_sc(&ZP0[(size_t)(b0 + 1) * 2048 + c0 + c], p0.y + p1.y + base + Wlab[slab[b0 + 1] * 32 + c]);
        st_sc(&ZP0[(size_t)(b0 + 2) * 2048 + c0 + c], p0.z + p1.z + base + Wlab[slab[b0 + 2] * 32 + c]);
        st_sc(&ZP0[(size_t)(b0 + 3) * 2048 + c0 + c], p0.w + p1.w + base + Wlab[slab[b0 + 3] * 32 + c]);
      }
    } else if (bid >= 144 && bid < 176) { // BH
      const int c0 = (bid - 144) * 64;
      float* W = dyn; float* hTh = dyn + 16384;
      stage_act(hTh, HT + 8192);
      __syncthreads();
      const int c = tid & 63, bq = tid >> 6;
      const float* wp = W + c; const float* rp = hTh + bq * 4;
      float4 a = {0.f, 0.f, 0.f, 0.f};
      #pragma unroll 4
      for (int k = 0; k < 256; ++k) {
        float w = wp[k * 64]; float4 r = *(const float4*)(rp + k * 36);
        a.x = fmaf(w, r.x, a.x); a.y = fmaf(w, r.y, a.y);
        a.z = fmaf(w, r.z, a.z); a.w = fmaf(w, r.w, a.w);
      }
      st_sc(&ZP1[(size_t)(bq * 4 + 0) * 2048 + c0 + c], a.x);
      st_sc(&ZP1[(size_t)(bq * 4 + 1) * 2048 + c0 + c], a.y);
      st_sc(&ZP1[(size_t)(bq * 4 + 2) * 2048 + c0 + c], a.z);
      st_sc(&ZP1[(size_t)(bq * 4 + 3) * 2048 + c0 + c], a.w);
    } else if (bid >= 176 && bid < 218) { // OL / OHI / PL
      float* W = dyn; float* hT = dyn + 8192; float* part = dyn + 17408;
      const bool isOL = bid < 192, isOHI = (bid >= 192 && bid < 208);
      stage_act(hT, isOHI ? (HT + 8192) : HT);
      __syncthreads();
      gemm32(W, hT, part);
      __syncthreads();
      if (tid < 256) {
        float4 p0 = *(float4*)(part + tid * 4);
        float4 p1 = *(float4*)(part + (tid + 256) * 4);
        int c = tid & 31, bq = tid >> 5;
        float v0 = p0.x + p1.x, v1 = p0.y + p1.y, v2 = p0.z + p1.z, v3 = p0.w + p1.w;
        if (isOL) {
          const int u0 = (bid - 176) * 32;
          st_sc(&OH0[(bq * 4 + 0) * 512 + u0 + c], v0);
          st_sc(&OH0[(bq * 4 + 1) * 512 + u0 + c], v1);
          st_sc(&OH0[(bq * 4 + 2) * 512 + u0 + c], v2);
          st_sc(&OH0[(bq * 4 + 3) * 512 + u0 + c], v3);
        } else if (isOHI) {
          const int u0 = (bid - 192) * 32;
          st_sc(&OH1[(bq * 4 + 0) * 512 + u0 + c], v0);
          st_sc(&OH1[(bq * 4 + 1) * 512 + u0 + c], v1);
          st_sc(&OH1[(bq * 4 + 2) * 512 + u0 + c], v2);
          st_sc(&OH1[(bq * 4 + 3) * 512 + u0 + c], v3);
        } else {
          const int j0 = (bid - 208) * 32;
          st_sc(&HP0[(bq * 4 + 0) * 320 + j0 + c], v0);
          st_sc(&HP0[(bq * 4 + 1) * 320 + j0 + c], v1);
          st_sc(&HP0[(bq * 4 + 2) * 320 + j0 + c], v2);
          st_sc(&HP0[(bq * 4 + 3) * 320 + j0 + c], v3);
        }
      }
    } else if (bid >= 218 && bid < 223) { // PHI
      const int j0 = (bid - 218) * 64;
      float* W = dyn; float* hTh = dyn + 16384;
      stage_act(hTh, HT + 8192);
      __syncthreads();
      const int c = tid & 63, bq = tid >> 6;
      const float* wp = W + c; const float* rp = hTh + bq * 4;
      float4 a = {0.f, 0.f, 0.f, 0.f};
      #pragma unroll 4
      for (int k = 0; k < 256; ++k) {
        float w = wp[k * 64]; float4 r = *(const float4*)(rp + k * 36);
        a.x = fmaf(w, r.x, a.x); a.y = fmaf(w, r.y, a.y);
        a.z = fmaf(w, r.z, a.z); a.w = fmaf(w, r.w, a.w);
      }
      st_sc(&HP1[(bq * 4 + 0) * 320 + j0 + c], a.x);
      st_sc(&HP1[(bq * 4 + 1) * 320 + j0 + c], a.y);
      st_sc(&HP1[(bq * 4 + 2) * 320 + j0 + c], a.z);
      st_sc(&HP1[(bq * 4 + 3) * 320 + j0 + c], a.w);
    }
  };

  auto phaseC = [&](int t) {
    if (bid < 223 || bid >= 255) return;
    float* ring = dyn;             // [250][68]
    float* WfL  = dyn + 17000;
    float* bpL  = dyn + 29800;
    float* bfL  = dyn + 30120;
    float* hid  = dyn + 30152;     // 320
    float* kn   = dyn + 30472;     // 256
    float* att4 = dyn + 30728;     // [4][256]
    float* red  = dyn + 31752;     // 32
    float* msum = dyn + 31784;     // 16
    float* rvp  = dyn + 31800;     // 512
    float* to   = dyn + 32312;     // 512
    float* lp   = dyn + 32824;     // 400
    float* lg   = dyn + 33224;     // 32
    const int b = bid - 223;

    if (t >= 1) {  // softmax output for step t-1
      for (int i = tid; i < 512; i += 512) to[i] = tanhf(ld_sc(&OUTPRE[b * 512 + i]));
      __syncthreads();
      if (tid < 400) {
        int l = tid % 25, p = tid / 25;
        float s = 0.f;
        #pragma unroll
        for (int q = 0; q < 32; ++q) { int k = p * 32 + q; s += to[k] * WfL[k * 25 + l]; }
        lp[p * 25 + l] = s;
      }
      __syncthreads();
      if (tid < 25) {
        float s = bfL[tid];
        #pragma unroll
        for (int p = 0; p < 16; ++p) s += lp[p * 25 + tid];
        lg[tid] = s;
      }
      __syncthreads();
      if (tid == 0) {
        float mx = lg[0];
        for (int l = 1; l < 25; ++l) mx = fmaxf(mx, lg[l]);
        float ss = 0.f;
        for (int l = 0; l < 25; ++l) ss += __expf(lg[l] - mx);
        lg[25] = mx; lg[26] = 1.f / ss;
      }
      __syncthreads();
      if (tid < 25)
        out[((size_t)b * 250 + (t - 1)) * 25 + tid] = __expf(lg[tid] - lg[25]) * lg[26];
    }
    if (t < 250) {  // attention -> rv_t, ring insert wv_t
      __syncthreads();
      if (tid < 320) hid[tid] = tanhf(ld_sc(&HP0[b * 320 + tid]) + ld_sc(&HP1[b * 320 + tid]) + bpL[tid]);
      __syncthreads();
      if (tid < 256) {
        float v = hid[64 + tid]; float pq = v * v;
        for (int off = 32; off; off >>= 1) pq += __shfl_down(pq, off, 64);
        if ((tid & 63) == 0) red[tid >> 6] = rsqrtf(fmaxf(pq, 1e-12f));
      }
      __syncthreads();
      if (tid < 256) kn[tid] = hid[64 + tid] * red[tid >> 6];
      __syncthreads();
      const int start = (250 - t) % 250;
      if (tid < 500) {
        int m = tid >> 1, dh = tid & 1;
        int p = start + m; if (p >= 250) p -= 250;
        const float* cell = ring + p * 68;
        const float* k0 = kn + dh * 128;
        float n2 = 0.f, d0 = 0.f, d1 = 0.f;
        #pragma unroll
        for (int s = 0; s < 64; s += 4) {
          float4 q = *(const float4*)(cell + s);
          n2 += q.x * q.x + q.y * q.y + q.z * q.z + q.w * q.w;
          d0 += k0[s] * q.x + k0[s + 1] * q.y + k0[s + 2] * q.z + k0[s + 3] * q.w;
          d1 += k0[64 + s] * q.x + k0[64 + s + 1] * q.y + k0[64 + s + 2] * q.z + k0[64 + s + 3] * q.w;
        }
        float rs = rsqrtf(fmaxf(n2, 1e-12f));
        att4[(2 * dh) * 256 + m] = d0 * rs;
        att4[(2 * dh + 1) * 256 + m] = d1 * rs;
      }
      __syncthreads();
      {
        int h4 = tid >> 7, mm = tid & 127;
        float v0 = att4[h4 * 256 + mm];
        bool has2 = (mm + 128) < 250;
        float v1 = has2 ? att4[h4 * 256 + mm + 128] : -3.0e38f;
        float mx = fmaxf(v0, v1);
        for (int off = 32; off; off >>= 1) mx = fmaxf(mx, __shfl_down(mx, off, 64));
        if ((tid & 63) == 0) red[tid >> 6] = mx;
        __syncthreads();
        float MX = fmaxf(red[h4 * 2], red[h4 * 2 + 1]);
        float e0 = __expf(v0 - MX);
        float e1 = has2 ? __expf(v1 - MX) : 0.f;
        att4[h4 * 256 + mm] = e0;
        if (has2) att4[h4 * 256 + mm + 128] = e1;
        float sm_ = e0 + e1;
        for (int off = 32; off; off >>= 1) sm_ += __shfl_down(sm_, off, 64);
        if ((tid & 63) == 0) red[8 + (tid >> 6)] = sm_;
        __syncthreads();
        if (tid < 4) msum[tid] = red[8 + tid * 2] + red[8 + tid * 2 + 1];
        __syncthreads();
      }
      {
        int h4 = tid >> 7, s = tid & 63, mh = (tid >> 6) & 1;
        float a = 0.f;
        for (int m = mh * 125; m < mh * 125 + 125; ++m) {
          int p = start + m; if (p >= 250) p -= 250;
          a += att4[h4 * 256 + m] * ring[p * 68 + s];
        }
        rvp[tid] = a;
      }
      __syncthreads();
      if (tid < 256) {
        int h4 = tid >> 6, s = tid & 63;
        float rv = (rvp[h4 * 128 + s] + rvp[h4 * 128 + 64 + s]) / msum[h4];
        st_sc(&RVT[(h4 * 64 + s) * 32 + b], rv);
      }
      __syncthreads();
      if (tid < 64) {
        int ip = start + 249; if (ip >= 250) ip -= 250;
        ring[ip * 68 + tid] = hid[tid];
      }
    }
  };

  // ---------------- main sequence ----------------
  phaseB(0);  // prologue: zacc_0 (h=0 via memset HT)
  gbar();
  for (int t = 0; t <= 250; ++t) {
    phaseA(t);
    gbar();
    if (t < 250) {
      int tt1 = (t + 1 <= 249) ? t + 1 : 249;
      phaseB(tt1);
      gbar();
    }
    phaseC(t);
    if (t < 250) gbar();
  }
}

extern "C" void kernel_launch(void* const* d_in, const int* in_sizes, int n_in,
                              void* d_out, int out_size, void* d_ws, size_t ws_size,
                              hipStream_t stream) {
  const float* images = (const float*)d_in[0];
  const int* labels = (const int*)d_in[1];
  const float* k1  = (const float*)d_in[2];
  const float* cb1 = (const float*)d_in[3];
  const float* g1  = (const float*)d_in[4];
  const float* be1 = (const float*)d_in[5];
  const float* mm1 = (const float*)d_in[6];
  const float* mv1 = (const float*)d_in[7];
  const float* k2  = (const float*)d_in[8];
  const float* cb2 = (const float*)d_in[9];
  const float* g2  = (const float*)d_in[10];
  const float* be2 = (const float*)d_in[11];
  const float* mm2 = (const float*)d_in[12];
  const float* mv2 = (const float*)d_in[13];
  const float* k3  = (const float*)d_in[14];
  const float* cb3 = (const float*)d_in[15];
  const float* g3  = (const float*)d_in[16];
  const float* be3 = (const float*)d_in[17];
  const float* mm3 = (const float*)d_in[18];
  const float* mv3 = (const float*)d_in[19];
  const float* Wx  = (const float*)d_in[20];
  const float* Wh  = (const float*)d_in[21];
  const float* bl  = (const float*)d_in[22];
  const float* Wp  = (const float*)d_in[23];
  const float* bp  = (const float*)d_in[24];
  const float* Wo  = (const float*)d_in[25];
  const float* bo  = (const float*)d_in[26];
  const float* Wf  = (const float*)d_in[27];
  const float* bf  = (const float*)d_in[28];
  float* ws = (float*)d_ws;

  hipFuncSetAttribute((const void*)lstm_kernel,
                      hipFuncAttributeMaxDynamicSharedMemorySize, DYN_BYTES);

  // zero activation/state/barrier region (ws poisoned 0xAA before each call)
  hipMemsetAsync((char*)d_ws + OFF_ZP0 * sizeof(float), 0,
                 (WS_FLOATS - OFF_ZP0) * sizeof(float), stream);
  prep_kernel<<<1024, 256, 0, stream>>>(Wx, Wh, bl, ws);
  conv_kernel<<<8000, 128, 0, stream>>>(images,
      k1, cb1, g1, be1, mm1, mv1,
      k2, cb2, g2, be2, mm2, mv2,
      k3, cb3, g3, be3, mm3, mv3, ws);
  lstm_kernel<<<256, 512, DYN_BYTES, stream>>>(labels, Wo, bo, Wp, bp, Wf, bf, ws,
                                               (float*)d_out);
}

// Round 4
// 8415.603 us; speedup vs baseline: 3.7995x; 1.0235x over previous
//
#include <hip/hip_runtime.h>

// ---------------- problem constants ----------------
// B=32, T=250, FEAT=128, CLASSES=25, UNITS=512, CELL=64, HEADS=4, IN_LSTM=409

// ---------------- scratch layout (floats) ----------------
constexpr size_t OFF_FEATP  = 0;                              // [8000][128]
constexpr size_t OFF_WXI    = OFF_FEATP + (size_t)8000 * 128; // [409][2048] gate-interleaved
constexpr size_t OFF_WHI    = OFF_WXI + (size_t)409 * 2048;   // [512][2048]
constexpr size_t OFF_BLI    = OFF_WHI + (size_t)512 * 2048;   // [2048]
constexpr size_t OFF_ZP0    = OFF_BLI + 2048;                 // [32][2048] zacc partial LO
constexpr size_t OFF_ZP1    = OFF_ZP0 + (size_t)32 * 2048;    // [32][2048] zacc partial HI
constexpr size_t OFF_OH0    = OFF_ZP1 + (size_t)32 * 2048;    // [32][512] outh partial LO
constexpr size_t OFF_OH1    = OFF_OH0 + (size_t)32 * 512;     // [32][512] outh partial HI
constexpr size_t OFF_HP0    = OFF_OH1 + (size_t)32 * 512;     // [32][320] hidpre partial LO
constexpr size_t OFF_HP1    = OFF_HP0 + (size_t)32 * 320;     // [32][320] hidpre partial HI
constexpr size_t OFF_OUTPRE = OFF_HP1 + (size_t)32 * 320;     // [32][512]
constexpr size_t OFF_HT     = OFF_OUTPRE + (size_t)32 * 512;  // [512][32] h transposed
constexpr size_t OFF_RVT    = OFF_HT + (size_t)512 * 32;      // [256][32] rv transposed
constexpr size_t OFF_BAR    = OFF_RVT + (size_t)256 * 32;     // barrier ints
constexpr size_t WS_FLOATS  = OFF_BAR + 1024;

constexpr int DYN_FLOATS = 34816;                 // 136 KB dynamic LDS
constexpr int DYN_BYTES  = DYN_FLOATS * 4;

__device__ __forceinline__ float sigm(float x) { return 1.f / (1.f + __expf(-x)); }

// ---- LLC-coherent accesses (bypass L1+L2; coherence point = Infinity Cache).
// Loads are batched in single asm blocks with the waitcnt INSIDE, so the
// backend cannot serialize them into dependent round-trips.
__device__ __forceinline__ void st_sc(float* p, float v) {
  __hip_atomic_store(p, v, __ATOMIC_RELAXED, __HIP_MEMORY_SCOPE_AGENT);
}
__device__ __forceinline__ float ld_sc(const float* p) {
  return __hip_atomic_load(p, __ATOMIC_RELAXED, __HIP_MEMORY_SCOPE_AGENT);
}
__device__ __forceinline__ void ld8x2_sc(const double* b0, double* v) {
  const double *p0 = b0, *p1 = b0 + 512, *p2 = b0 + 1024, *p3 = b0 + 1536,
               *p4 = b0 + 2048, *p5 = b0 + 2560, *p6 = b0 + 3072, *p7 = b0 + 3584;
  asm volatile(
      "global_load_dwordx2 %0, %8, off sc0 sc1\n\t"
      "global_load_dwordx2 %1, %9, off sc0 sc1\n\t"
      "global_load_dwordx2 %2, %10, off sc0 sc1\n\t"
      "global_load_dwordx2 %3, %11, off sc0 sc1\n\t"
      "global_load_dwordx2 %4, %12, off sc0 sc1\n\t"
      "global_load_dwordx2 %5, %13, off sc0 sc1\n\t"
      "global_load_dwordx2 %6, %14, off sc0 sc1\n\t"
      "global_load_dwordx2 %7, %15, off sc0 sc1\n\t"
      "s_waitcnt vmcnt(0)"
      : "=&v"(v[0]), "=&v"(v[1]), "=&v"(v[2]), "=&v"(v[3]),
        "=&v"(v[4]), "=&v"(v[5]), "=&v"(v[6]), "=&v"(v[7])
      : "v"(p0), "v"(p1), "v"(p2), "v"(p3), "v"(p4), "v"(p5), "v"(p6), "v"(p7));
}
__device__ __forceinline__ void ldpair2_sc(const double* a, const double* b,
                                           double& x, double& y) {
  asm volatile(
      "global_load_dwordx2 %0, %2, off sc0 sc1\n\t"
      "global_load_dwordx2 %1, %3, off sc0 sc1\n\t"
      "s_waitcnt vmcnt(0)"
      : "=&v"(x), "=&v"(y) : "v"(a), "v"(b));
}
__device__ __forceinline__ void ldpair_sc(const float* a, const float* b,
                                          float& x, float& y) {
  asm volatile(
      "global_load_dword %0, %2, off sc0 sc1\n\t"
      "global_load_dword %1, %3, off sc0 sc1\n\t"
      "s_waitcnt vmcnt(0)"
      : "=&v"(x), "=&v"(y) : "v"(a), "v"(b));
}

// ---------------- weight re-layout: gate-interleaved Wx/Wh/bl ----------------
__global__ __launch_bounds__(256) void prep_kernel(const float* __restrict__ Wx,
                                                   const float* __restrict__ Wh,
                                                   const float* __restrict__ bl,
                                                   float* __restrict__ ws) {
  float* WXI = ws + OFF_WXI;
  float* WHI = ws + OFF_WHI;
  float* BLI = ws + OFF_BLI;
  const int total = 409 * 2048 + 512 * 2048 + 2048;
  for (int idx = blockIdx.x * blockDim.x + threadIdx.x; idx < total;
       idx += gridDim.x * blockDim.x) {
    if (idx < 409 * 2048) {
      int k = idx >> 11, cc = idx & 2047;
      WXI[idx] = Wx[(size_t)k * 2048 + (cc & 3) * 512 + (cc >> 2)];
    } else if (idx < 409 * 2048 + 512 * 2048) {
      int j = idx - 409 * 2048;
      int k = j >> 11, cc = j & 2047;
      WHI[j] = Wh[(size_t)k * 2048 + (cc & 3) * 512 + (cc >> 2)];
    } else {
      int cc = idx - (409 * 2048 + 512 * 2048);
      BLI[cc] = bl[(cc & 3) * 512 + (cc >> 2)];
    }
  }
}

// ---------------- conv stack (validated) ----------------
__global__ __launch_bounds__(128) void conv_kernel(
    const float* __restrict__ img,
    const float* __restrict__ k1, const float* __restrict__ cb1, const float* __restrict__ g1,
    const float* __restrict__ be1, const float* __restrict__ mm1, const float* __restrict__ mv1,
    const float* __restrict__ k2, const float* __restrict__ cb2, const float* __restrict__ g2,
    const float* __restrict__ be2, const float* __restrict__ mm2, const float* __restrict__ mv2,
    const float* __restrict__ k3, const float* __restrict__ cb3, const float* __restrict__ g3,
    const float* __restrict__ be3, const float* __restrict__ mm3, const float* __restrict__ mv3,
    float* __restrict__ ws) {
  __shared__ float s_in[784];
  __shared__ float s_y1[13 * 13 * 8];
  __shared__ float s_y2[6 * 6 * 16];
  __shared__ float s_k1[72], s_k2[1152], s_k3[4608];
  __shared__ float s_s1[8], s_b1[8], s_s2[16], s_b2[16], s_s3[32], s_b3[32];
  float* FEATP = ws + OFF_FEATP;
  const int n = blockIdx.x, tid = threadIdx.x;
  const float* ip = img + (size_t)n * 784;
  for (int i = tid; i < 784; i += 128) s_in[i] = ip[i];
  for (int i = tid; i < 72; i += 128) s_k1[i] = k1[i];
  for (int i = tid; i < 1152; i += 128) s_k2[i] = k2[i];
  for (int i = tid; i < 4608; i += 128) s_k3[i] = k3[i];
  if (tid < 8) {
    float s = g1[tid] * rsqrtf(mv1[tid] + 1e-3f);
    s_s1[tid] = s; s_b1[tid] = (cb1[tid] - mm1[tid]) * s + be1[tid];
  } else if (tid >= 32 && tid < 48) {
    int c = tid - 32;
    float s = g2[c] * rsqrtf(mv2[c] + 1e-3f);
    s_s2[c] = s; s_b2[c] = (cb2[c] - mm2[c]) * s + be2[c];
  } else if (tid >= 64 && tid < 96) {
    int c = tid - 64;
    float s = g3[c] * rsqrtf(mv3[c] + 1e-3f);
    s_s3[c] = s; s_b3[c] = (cb3[c] - mm3[c]) * s + be3[c];
  }
  __syncthreads();
  for (int idx = tid; idx < 13 * 13 * 8; idx += 128) {
    int co = idx & 7, pos = idx >> 3;
    int j = pos % 13, i = pos / 13;
    float acc = 0.f;
    #pragma unroll
    for (int ky = 0; ky < 3; ++ky)
      #pragma unroll
      for (int kx = 0; kx < 3; ++kx)
        acc += s_in[(2 * i + ky) * 28 + (2 * j + kx)] * s_k1[(ky * 3 + kx) * 8 + co];
    float v = acc * s_s1[co] + s_b1[co];
    s_y1[idx] = v > 0.f ? v : 0.f;
  }
  __syncthreads();
  for (int idx = tid; idx < 6 * 6 * 16; idx += 128) {
    int co = idx & 15, pos = idx >> 4;
    int j = pos % 6, i = pos / 6;
    float acc = 0.f;
    for (int ky = 0; ky < 3; ++ky)
      for (int kx = 0; kx < 3; ++kx) {
        int base = ((2 * i + ky) * 13 + (2 * j + kx)) * 8;
        int kb = (ky * 3 + kx) * 128 + co;
        #pragma unroll
        for (int ci = 0; ci < 8; ++ci) acc += s_y1[base + ci] * s_k2[kb + ci * 16];
      }
    float v = acc * s_s2[co] + s_b2[co];
    s_y2[idx] = v > 0.f ? v : 0.f;
  }
  __syncthreads();
  for (int idx = tid; idx < 128; idx += 128) {
    int co = idx & 31, pos = idx >> 5;
    int j = pos & 1, i = pos >> 1;
    float acc = 0.f;
    for (int ky = 0; ky < 3; ++ky)
      for (int kx = 0; kx < 3; ++kx) {
        int base = ((2 * i + ky) * 6 + (2 * j + kx)) * 16;
        int kb = (ky * 3 + kx) * 512 + co;
        #pragma unroll
        for (int ci = 0; ci < 16; ++ci) acc += s_y2[base + ci] * s_k3[kb + ci * 32];
      }
    float v = acc * s_s3[co] + s_b3[co];
    FEATP[(size_t)n * 128 + idx] = v > 0.f ? v : 0.f;
  }
}

// ---------------- persistent LSTM scan ----------------
__global__ __launch_bounds__(512) void lstm_kernel(
    const int* __restrict__ labels,
    const float* __restrict__ Wo, const float* __restrict__ bo,
    const float* __restrict__ Wp, const float* __restrict__ bp,
    const float* __restrict__ Wf, const float* __restrict__ bf,
    float* __restrict__ ws, float* __restrict__ out) {
  extern __shared__ float dyn[];
  const float* FEATP = ws + OFF_FEATP;
  const float* WXI   = ws + OFF_WXI;
  const float* WHI   = ws + OFF_WHI;
  const float* BLI   = ws + OFF_BLI;
  float* ZP0    = ws + OFF_ZP0;
  float* ZP1    = ws + OFF_ZP1;
  float* OH0    = ws + OFF_OH0;
  float* OH1    = ws + OFF_OH1;
  float* HP0    = ws + OFF_HP0;
  float* HP1    = ws + OFF_HP1;
  float* OUTPRE = ws + OFF_OUTPRE;
  float* HT     = ws + OFF_HT;
  float* RVT    = ws + OFF_RVT;
  int*   BARp   = (int*)(ws + OFF_BAR);

  const int bid = blockIdx.x;
  const int tid = threadIdx.x;
  int barGen = 0;

  auto gbar = [&]() {
    asm volatile("s_waitcnt vmcnt(0) lgkmcnt(0)" ::: "memory");
    __syncthreads();
    ++barGen;
    if (tid == 0) {
      int a = __hip_atomic_fetch_add(&BARp[(bid & 7) << 6], 1, __ATOMIC_RELAXED,
                                     __HIP_MEMORY_SCOPE_AGENT);
      if ((a & 31) == 31) {
        int r = __hip_atomic_fetch_add(&BARp[512], 1, __ATOMIC_RELAXED,
                                       __HIP_MEMORY_SCOPE_AGENT);
        if ((r & 7) == 7) {
          __hip_atomic_fetch_add(&BARp[576], 1, __ATOMIC_RELAXED,
                                 __HIP_MEMORY_SCOPE_AGENT);
        }
      }
      while (__hip_atomic_load(&BARp[576], __ATOMIC_RELAXED,
                               __HIP_MEMORY_SCOPE_AGENT) < barGen) {
        __builtin_amdgcn_s_sleep(1);
      }
    }
    __syncthreads();
  };

  // stage 8192-float [256][32] coherent buffer into [256][36]-padded LDS tile
  auto stage_act = [&](float* dst, const float* src) {
    double v[8];
    ld8x2_sc((const double*)src + tid, v);
    #pragma unroll
    for (int j = 0; j < 8; ++j) {
      int i = (tid + j * 512) << 1;
      *(double*)&dst[(i >> 5) * 36 + (i & 31)] = v[j];
    }
  };
  // 32-col gemm, k=256 split in 2 halves across tid>>8; result in part[512][4]
  auto gemm32 = [&](const float* W, const float* act, float* part) {
    const int c = tid & 31, bq = (tid >> 5) & 7, kh = tid >> 8;
    const float* wp = W + kh * 128 * 32 + c;
    const float* rp = act + kh * 128 * 36 + bq * 4;
    float4 a = {0.f, 0.f, 0.f, 0.f};
    #pragma unroll 4
    for (int k = 0; k < 128; ++k) {
      float w = wp[k * 32];
      float4 r = *(const float4*)(rp + k * 36);
      a.x = fmaf(w, r.x, a.x); a.y = fmaf(w, r.y, a.y);
      a.z = fmaf(w, r.z, a.z); a.w = fmaf(w, r.w, a.w);
    }
    *(float4*)(part + tid * 4) = a;
  };

  // ---------------- one-time init: weights -> LDS ----------------
  if (bid < 64) {            // AZ
    const int c0 = bid * 32;
    for (int i = tid; i < 8192; i += 512)
      dyn[i] = WXI[(size_t)(153 + (i >> 5)) * 2048 + c0 + (i & 31)];
    if (tid < 256) dyn[8192 + tid] = 0.f;  // Cst
  } else if (bid < 80) {     // AO
    const int u0 = (bid - 64) * 32;
    for (int i = tid; i < 8192; i += 512)
      dyn[i] = Wo[(size_t)(512 + (i >> 5)) * 512 + u0 + (i & 31)];
    if (tid < 32) dyn[8192 + tid] = bo[u0 + tid];
  } else if (bid < 144) {    // BL
    const int c0 = (bid - 80) * 32;
    for (int i = tid; i < 4096; i += 512)
      dyn[i] = WXI[(size_t)(i >> 5) * 2048 + c0 + (i & 31)];
    for (int i = tid; i < 800; i += 512)
      dyn[4096 + i] = WXI[(size_t)(128 + (i >> 5)) * 2048 + c0 + (i & 31)];
    for (int i = tid; i < 8192; i += 512)
      dyn[4896 + i] = WHI[(size_t)(i >> 5) * 2048 + c0 + (i & 31)];
    if (tid < 32) dyn[13088 + tid] = BLI[c0 + tid];
  } else if (bid < 176) {    // BH
    const int c0 = (bid - 144) * 64;
    for (int i = tid; i < 16384; i += 512)
      dyn[i] = WHI[(size_t)(256 + (i >> 6)) * 2048 + c0 + (i & 63)];
  } else if (bid < 192) {    // OL
    const int u0 = (bid - 176) * 32;
    for (int i = tid; i < 8192; i += 512)
      dyn[i] = Wo[(size_t)(i >> 5) * 512 + u0 + (i & 31)];
  } else if (bid < 208) {    // OHI
    const int u0 = (bid - 192) * 32;
    for (int i = tid; i < 8192; i += 512)
      dyn[i] = Wo[(size_t)(256 + (i >> 5)) * 512 + u0 + (i & 31)];
  } else if (bid < 218) {    // PL
    const int j0 = (bid - 208) * 32;
    for (int i = tid; i < 8192; i += 512)
      dyn[i] = Wp[(size_t)(i >> 5) * 320 + j0 + (i & 31)];
  } else if (bid < 223) {    // PHI
    const int j0 = (bid - 218) * 64;
    for (int i = tid; i < 16384; i += 512)
      dyn[i] = Wp[(size_t)(256 + (i >> 6)) * 320 + j0 + (i & 63)];
  } else if (bid < 255) {    // CA
    for (int i = tid; i < 17000; i += 512) dyn[i] = 0.f;       // ring[250][68]
    for (int i = tid; i < 12800; i += 512) dyn[17000 + i] = Wf[i];
    for (int i = tid; i < 320; i += 512) dyn[29800 + i] = bp[i];
    if (tid < 25) dyn[30120 + tid] = bf[tid];
  }
  __syncthreads();

  // ---------------- slot bodies ----------------
  // AZ prefetch (runs in slot3): zf = ZP0+ZP1 for next step's gates
  auto azPre = [&]() {
    const int c0 = bid * 32;
    float* zf = dyn + 17664;
    const int b = tid >> 4, c2 = tid & 15;
    double x, y;
    ldpair2_sc((const double*)(ZP0 + (size_t)b * 2048 + c0) + c2,
               (const double*)(ZP1 + (size_t)b * 2048 + c0) + c2, x, y);
    float2 fx = *(float2*)&x, fy = *(float2*)&y;
    float2 s = {fx.x + fy.x, fx.y + fy.y};
    *(double*)&zf[b * 32 + c2 * 2] = *(double*)&s;
  };
  // AO prefetch (slot3): of = OH0+OH1
  auto aoPre = [&]() {
    const int u0 = (bid - 64) * 32;
    float* of = dyn + 17440;
    const int b = tid >> 4, c2 = tid & 15;
    double x, y;
    ldpair2_sc((const double*)(OH0 + b * 512 + u0) + c2,
               (const double*)(OH1 + b * 512 + u0) + c2, x, y);
    float2 fx = *(float2*)&x, fy = *(float2*)&y;
    float2 s = {fx.x + fy.x, fx.y + fy.y};
    *(double*)&of[b * 32 + c2 * 2] = *(double*)&s;
  };
  // AZ gates (slot1): h_t, c_t from zf (pre-staged) + rv@Wxr
  auto azGates = [&]() {
    float* Wz = dyn; float* Cst = dyn + 8192; float* rvT = dyn + 8448;
    float* zf = dyn + 17664; float* part = dyn + 18688;
    stage_act(rvT, RVT);
    __syncthreads();
    gemm32(Wz, rvT, part);
    __syncthreads();
    if (tid < 256) {
      float4 p0 = *(float4*)(part + tid * 4);
      float4 p1 = *(float4*)(part + (tid + 256) * 4);
      int c = tid & 31, bq = tid >> 5;
      zf[(bq * 4 + 0) * 32 + c] += p0.x + p1.x;
      zf[(bq * 4 + 1) * 32 + c] += p0.y + p1.y;
      zf[(bq * 4 + 2) * 32 + c] += p0.z + p1.z;
      zf[(bq * 4 + 3) * 32 + c] += p0.w + p1.w;
    }
    __syncthreads();
    if (tid < 256) {
      int u = tid & 7, b = tid >> 3;
      float4 z = *(float4*)(zf + b * 32 + u * 4);
      float ig = sigm(z.x), fg = sigm(z.y), gg = tanhf(z.z), og = sigm(z.w);
      float cc = fg * Cst[b * 8 + u] + ig * gg;
      Cst[b * 8 + u] = cc;
      st_sc(&HT[(size_t)(bid * 8 + u) * 32 + b], og * tanhf(cc));
    }
  };
  // AO (slot1): outpre_{t-1} = of (pre-staged) + rv@Wor + bo
  auto aoOut = [&]() {
    const int u0 = (bid - 64) * 32;
    float* W = dyn; float* bo_l = dyn + 8192; float* rvT = dyn + 8224;
    float* of = dyn + 17440; float* part = dyn + 18464;
    stage_act(rvT, RVT);
    __syncthreads();
    gemm32(W, rvT, part);
    __syncthreads();
    if (tid < 256) {
      float4 p0 = *(float4*)(part + tid * 4);
      float4 p1 = *(float4*)(part + (tid + 256) * 4);
      int u = tid & 31, bq = tid >> 5;
      float bv = bo_l[u];
      st_sc(&OUTPRE[(bq * 4 + 0) * 512 + u0 + u], p0.x + p1.x + of[(bq * 4 + 0) * 32 + u] + bv);
      st_sc(&OUTPRE[(bq * 4 + 1) * 512 + u0 + u], p0.y + p1.y + of[(bq * 4 + 1) * 32 + u] + bv);
      st_sc(&OUTPRE[(bq * 4 + 2) * 512 + u0 + u], p0.z + p1.z + of[(bq * 4 + 2) * 32 + u] + bv);
      st_sc(&OUTPRE[(bq * 4 + 3) * 512 + u0 + u], p0.w + p1.w + of[(bq * 4 + 3) * 32 + u] + bv);
    }
  };
  // BL x-staging (slot1): feat_{tt1} + labels (read-only, cached loads)
  auto blStageX = [&](int tt1) {
    float* xT = dyn + 13152; int* slab = (int*)(dyn + 13120);
    for (int i = tid; i < 4096; i += 512) {
      int b = i >> 7, k = i & 127;
      xT[k * 36 + b] = FEATP[((size_t)b * 250 + tt1) * 128 + k];
    }
    if (tid < 32) slab[tid] = labels[tid * 250 + tt1];
  };
  // B gemms (slot2)
  auto bGemm = [&]() {
    if (bid >= 80 && bid < 144) {        // BL
      const int c0 = (bid - 80) * 32;
      float* Wxf = dyn; float* Wlab = dyn + 4096; float* Whl = dyn + 4896;
      float* blc = dyn + 13088; int* slab = (int*)(dyn + 13120);
      float* xT = dyn + 13152; float* hTl = dyn + 17760; float* part = dyn + 26976;
      stage_act(hTl, HT);
      __syncthreads();
      {
        const int c = tid & 31, bq = (tid >> 5) & 7, kh = tid >> 8;
        float4 a = {0.f, 0.f, 0.f, 0.f};
        if (kh == 0) {
          const float* wp = Wxf + c; const float* rp = xT + bq * 4;
          #pragma unroll 4
          for (int k = 0; k < 128; ++k) {
            float w = wp[k * 32]; float4 r = *(const float4*)(rp + k * 36);
            a.x = fmaf(w, r.x, a.x); a.y = fmaf(w, r.y, a.y);
            a.z = fmaf(w, r.z, a.z); a.w = fmaf(w, r.w, a.w);
          }
          wp = Whl + c; rp = hTl + bq * 4;
          #pragma unroll 4
          for (int k = 0; k < 64; ++k) {
            float w = wp[k * 32]; float4 r = *(const float4*)(rp + k * 36);
            a.x = fmaf(w, r.x, a.x); a.y = fmaf(w, r.y, a.y);
            a.z = fmaf(w, r.z, a.z); a.w = fmaf(w, r.w, a.w);
          }
        } else {
          const float* wp = Whl + 64 * 32 + c; const float* rp = hTl + 64 * 36 + bq * 4;
          #pragma unroll 4
          for (int k = 0; k < 192; ++k) {
            float w = wp[k * 32]; float4 r = *(const float4*)(rp + k * 36);
            a.x = fmaf(w, r.x, a.x); a.y = fmaf(w, r.y, a.y);
            a.z = fmaf(w, r.z, a.z); a.w = fmaf(w, r.w, a.w);
          }
        }
        *(float4*)(part + tid * 4) = a;
      }
      __syncthreads();
      if (tid < 256) {
        float4 p0 = *(float4*)(part + tid * 4);
        float4 p1 = *(float4*)(part + (tid + 256) * 4);
        int c = tid & 31, bq = tid >> 5;
        float base = blc[c];
        int b0 = bq * 4;
        st_sc(&ZP0[(size_t)(b0 + 0) * 2048 + c0 + c], p0.x + p1.x + base + Wlab[slab[b0 + 0] * 32 + c]);
        st_sc(&ZP0[(size_t)(b0 + 1) * 2048 + c0 + c], p0.y + p1.y + base + Wlab[slab[b0 + 1] * 32 + c]);
        st_sc(&ZP0[(size_t)(b0 + 2) * 2048 + c0 + c], p0.z + p1.z + base + Wlab[slab[b0 + 2] * 32 + c]);
        st_sc(&ZP0[(size_t)(b0 + 3) * 2048 + c0 + c], p0.w + p1.w + base + Wlab[slab[b0 + 3] * 32 + c]);
      }
    } else if (bid >= 144 && bid < 176) { // BH
      const int c0 = (bid - 144) * 64;
      float* W = dyn; float* hTh = dyn + 16384;
      stage_act(hTh, HT + 8192);
      __syncthreads();
      const int c = tid & 63, bq = tid >> 6;
      const float* wp = W + c; const float* rp = hTh + bq * 4;
      float4 a = {0.f, 0.f, 0.f, 0.f};
      #pragma unroll 4
      for (int k = 0; k < 256; ++k) {
        float w = wp[k * 64]; float4 r = *(const float4*)(rp + k * 36);
        a.x = fmaf(w, r.x, a.x); a.y = fmaf(w, r.y, a.y);
        a.z = fmaf(w, r.z, a.z); a.w = fmaf(w, r.w, a.w);
      }
      st_sc(&ZP1[(size_t)(bq * 4 + 0) * 2048 + c0 + c], a.x);
      st_sc(&ZP1[(size_t)(bq * 4 + 1) * 2048 + c0 + c], a.y);
      st_sc(&ZP1[(size_t)(bq * 4 + 2) * 2048 + c0 + c], a.z);
      st_sc(&ZP1[(size_t)(bq * 4 + 3) * 2048 + c0 + c], a.w);
    } else if (bid >= 176 && bid < 218) { // OL / OHI / PL
      float* W = dyn; float* hT = dyn + 8192; float* part = dyn + 17408;
      const bool isOL = bid < 192, isOHI = (bid >= 192 && bid < 208);
      stage_act(hT, isOHI ? (HT + 8192) : HT);
      __syncthreads();
      gemm32(W, hT, part);
      __syncthreads();
      if (tid < 256) {
        float4 p0 = *(float4*)(part + tid * 4);
        float4 p1 = *(float4*)(part + (tid + 256) * 4);
        int c = tid & 31, bq = tid >> 5;
        float v0 = p0.x + p1.x, v1 = p0.y + p1.y, v2 = p0.z + p1.z, v3 = p0.w + p1.w;
        if (isOL) {
          const int u0 = (bid - 176) * 32;
          st_sc(&OH0[(bq * 4 + 0) * 512 + u0 + c], v0);
          st_sc(&OH0[(bq * 4 + 1) * 512 + u0 + c], v1);
          st_sc(&OH0[(bq * 4 + 2) * 512 + u0 + c], v2);
          st_sc(&OH0[(bq * 4 + 3) * 512 + u0 + c], v3);
        } else if (isOHI) {
          const int u0 = (bid - 192) * 32;
          st_sc(&OH1[(bq * 4 + 0) * 512 + u0 + c], v0);
          st_sc(&OH1[(bq * 4 + 1) * 512 + u0 + c], v1);
          st_sc(&OH1[(bq * 4 + 2) * 512 + u0 + c], v2);
          st_sc(&OH1[(bq * 4 + 3) * 512 + u0 + c], v3);
        } else {
          const int j0 = (bid - 208) * 32;
          st_sc(&HP0[(bq * 4 + 0) * 320 + j0 + c], v0);
          st_sc(&HP0[(bq * 4 + 1) * 320 + j0 + c], v1);
          st_sc(&HP0[(bq * 4 + 2) * 320 + j0 + c], v2);
          st_sc(&HP0[(bq * 4 + 3) * 320 + j0 + c], v3);
        }
      }
    } else if (bid >= 218 && bid < 223) { // PHI
      const int j0 = (bid - 218) * 64;
      float* W = dyn; float* hTh = dyn + 16384;
      stage_act(hTh, HT + 8192);
      __syncthreads();
      const int c = tid & 63, bq = tid >> 6;
      const float* wp = W + c; const float* rp = hTh + bq * 4;
      float4 a = {0.f, 0.f, 0.f, 0.f};
      #pragma unroll 4
      for (int k = 0; k < 256; ++k) {
        float w = wp[k * 64]; float4 r = *(const float4*)(rp + k * 36);
        a.x = fmaf(w, r.x, a.x); a.y = fmaf(w, r.y, a.y);
        a.z = fmaf(w, r.z, a.z); a.w = fmaf(w, r.w, a.w);
      }
      st_sc(&HP1[(bq * 4 + 0) * 320 + j0 + c], a.x);
      st_sc(&HP1[(bq * 4 + 1) * 320 + j0 + c], a.y);
      st_sc(&HP1[(bq * 4 + 2) * 320 + j0 + c], a.z);
      st_sc(&HP1[(bq * 4 + 3) * 320 + j0 + c], a.w);
    }
  };
  // CA output (slot2): softmax(out) for step t-1 from OUTPRE
  auto caOut = [&](int t) {
    float* WfL = dyn + 17000; float* bfL = dyn + 30120;
    float* to  = dyn + 32312; float* lp = dyn + 32824; float* lg = dyn + 33224;
    const int b = bid - 223;
    to[tid] = tanhf(ld_sc(&OUTPRE[b * 512 + tid]));
    __syncthreads();
    if (tid < 400) {
      int l = tid % 25, p = tid / 25;
      float s = 0.f;
      #pragma unroll
      for (int q = 0; q < 32; ++q) { int k = p * 32 + q; s += to[k] * WfL[k * 25 + l]; }
      lp[p * 25 + l] = s;
    }
    __syncthreads();
    if (tid < 25) {
      float s = bfL[tid];
      #pragma unroll
      for (int p = 0; p < 16; ++p) s += lp[p * 25 + tid];
      lg[tid] = s;
    }
    __syncthreads();
    if (tid == 0) {
      float mx = lg[0];
      for (int l = 1; l < 25; ++l) mx = fmaxf(mx, lg[l]);
      float ss = 0.f;
      for (int l = 0; l < 25; ++l) ss += __expf(lg[l] - mx);
      lg[25] = mx; lg[26] = 1.f / ss;
    }
    __syncthreads();
    if (tid < 25)
      out[((size_t)b * 250 + (t - 1)) * 25 + tid] = __expf(lg[tid] - lg[25]) * lg[26];
  };
  // CA attention (slot3): rv_t, ring insert
  auto caAtt = [&](int t) {
    float* ring = dyn;
    float* bpL  = dyn + 29800;
    float* hid  = dyn + 30152;
    float* kn   = dyn + 30472;
    float* att4 = dyn + 30728;
    float* red  = dyn + 31752;
    float* msum = dyn + 31784;
    float* rvp  = dyn + 31800;
    const int b = bid - 223;
    if (tid < 320) {
      float x, y;
      ldpair_sc(&HP0[b * 320 + tid], &HP1[b * 320 + tid], x, y);
      hid[tid] = tanhf(x + y + bpL[tid]);
    }
    __syncthreads();
    if (tid < 256) {
      float v = hid[64 + tid]; float pq = v * v;
      for (int off = 32; off; off >>= 1) pq += __shfl_down(pq, off, 64);
      if ((tid & 63) == 0) red[tid >> 6] = rsqrtf(fmaxf(pq, 1e-12f));
    }
    __syncthreads();
    if (tid < 256) kn[tid] = hid[64 + tid] * red[tid >> 6];
    __syncthreads();
    const int start = (250 - t) % 250;
    if (tid < 500) {
      int m = tid >> 1, dh = tid & 1;
      int p = start + m; if (p >= 250) p -= 250;
      const float* cell = ring + p * 68;
      const float* k0 = kn + dh * 128;
      float n2 = 0.f, d0 = 0.f, d1 = 0.f;
      #pragma unroll
      for (int s = 0; s < 64; s += 4) {
        float4 q = *(const float4*)(cell + s);
        n2 += q.x * q.x + q.y * q.y + q.z * q.z + q.w * q.w;
        d0 += k0[s] * q.x + k0[s + 1] * q.y + k0[s + 2] * q.z + k0[s + 3] * q.w;
        d1 += k0[64 + s] * q.x + k0[64 + s + 1] * q.y + k0[64 + s + 2] * q.z + k0[64 + s + 3] * q.w;
      }
      float rs = rsqrtf(fmaxf(n2, 1e-12f));
      att4[(2 * dh) * 256 + m] = d0 * rs;
      att4[(2 * dh + 1) * 256 + m] = d1 * rs;
    }
    __syncthreads();
    {
      int h4 = tid >> 7, mm = tid & 127;
      float v0 = att4[h4 * 256 + mm];
      bool has2 = (mm + 128) < 250;
      float v1 = has2 ? att4[h4 * 256 + mm + 128] : -3.0e38f;
      float mx = fmaxf(v0, v1);
      for (int off = 32; off; off >>= 1) mx = fmaxf(mx, __shfl_down(mx, off, 64));
      if ((tid & 63) == 0) red[tid >> 6] = mx;
      __syncthreads();
      float MX = fmaxf(red[h4 * 2], red[h4 * 2 + 1]);
      float e0 = __expf(v0 - MX);
      float e1 = has2 ? __expf(v1 - MX) : 0.f;
      att4[h4 * 256 + mm] = e0;
      if (has2) att4[h4 * 256 + mm + 128] = e1;
      float sm_ = e0 + e1;
      for (int off = 32; off; off >>= 1) sm_ += __shfl_down(sm_, off, 64);
      if ((tid & 63) == 0) red[8 + (tid >> 6)] = sm_;
      __syncthreads();
      if (tid < 4) msum[tid] = red[8 + tid * 2] + red[8 + tid * 2 + 1];
      __syncthreads();
    }
    {
      int h4 = tid >> 7, s = tid & 63, mh = (tid >> 6) & 1;
      float a = 0.f;
      for (int m = mh * 125; m < mh * 125 + 125; ++m) {
        int p = start + m; if (p >= 250) p -= 250;
        a += att4[h4 * 256 + m] * ring[p * 68 + s];
      }
      rvp[tid] = a;
    }
    __syncthreads();
    if (tid < 256) {
      int h4 = tid >> 6, s = tid & 63;
      float rv = (rvp[h4 * 128 + s] + rvp[h4 * 128 + 64 + s]) / msum[h4];
      st_sc(&RVT[(h4 * 64 + s) * 32 + b], rv);
    }
    __syncthreads();
    if (tid < 64) {
      int ip = start + 249; if (ip >= 250) ip -= 250;
      ring[ip * 68 + tid] = hid[tid];
    }
  };

  const bool isAZ = bid < 64, isAO = (bid >= 64 && bid < 80),
             isBL = (bid >= 80 && bid < 144), isB = (bid >= 80 && bid < 223),
             isCA = (bid >= 223 && bid < 255);

  // ---------------- main sequence ----------------
  // prologue: zacc_0 (h = 0 via memset HT/RVT)
  if (isBL) blStageX(0);
  if (isB) bGemm();
  gbar();
  if (isAZ) azPre();
  if (isAO) aoPre();
  gbar();
  for (int t = 0; t < 250; ++t) {
    // slot1: gates + outpre_{t-1} + x-staging
    if (isAZ) azGates();
    else if (isAO && t >= 1) aoOut();
    else if (isBL) blStageX(t + 1 <= 249 ? t + 1 : 249);
    gbar();
    // slot2: B gemms + output softmax for t-1
    if (isB) bGemm();
    else if (isCA && t >= 1) caOut(t);
    gbar();
    // slot3: attention + A prefetch
    if (isCA) caAtt(t);
    else if (isAZ) azPre();
    else if (isAO) aoPre();
    gbar();
  }
  // epilogue: outpre_249 -> out[249]
  if (isAO) aoOut();
  gbar();
  if (isCA) caOut(250);
}

extern "C" void kernel_launch(void* const* d_in, const int* in_sizes, int n_in,
                              void* d_out, int out_size, void* d_ws, size_t ws_size,
                              hipStream_t stream) {
  const float* images = (const float*)d_in[0];
  const int* labels = (const int*)d_in[1];
  const float* k1  = (const float*)d_in[2];
  const float* cb1 = (const float*)d_in[3];
  const float* g1  = (const float*)d_in[4];
  const float* be1 = (const float*)d_in[5];
  const float* mm1 = (const float*)d_in[6];
  const float* mv1 = (const float*)d_in[7];
  const float* k2  = (const float*)d_in[8];
  const float* cb2 = (const float*)d_in[9];
  const float* g2  = (const float*)d_in[10];
  const float* be2 = (const float*)d_in[11];
  const float* mm2 = (const float*)d_in[12];
  const float* mv2 = (const float*)d_in[13];
  const float* k3  = (const float*)d_in[14];
  const float* cb3 = (const float*)d_in[15];
  const float* g3  = (const float*)d_in[16];
  const float* be3 = (const float*)d_in[17];
  const float* mm3 = (const float*)d_in[18];
  const float* mv3 = (const float*)d_in[19];
  const float* Wx  = (const float*)d_in[20];
  const float* Wh  = (const float*)d_in[21];
  const float* bl  = (const float*)d_in[22];
  const float* Wp  = (const float*)d_in[23];
  const float* bp  = (const float*)d_in[24];
  const float* Wo  = (const float*)d_in[25];
  const float* bo  = (const float*)d_in[26];
  const float* Wf  = (const float*)d_in[27];
  const float* bf  = (const float*)d_in[28];
  float* ws = (float*)d_ws;

  hipFuncSetAttribute((const void*)lstm_kernel,
                      hipFuncAttributeMaxDynamicSharedMemorySize, DYN_BYTES);

  // zero activation/state/barrier region (ws poisoned 0xAA before each call)
  hipMemsetAsync((char*)d_ws + OFF_ZP0 * sizeof(float), 0,
                 (WS_FLOATS - OFF_ZP0) * sizeof(float), stream);
  prep_kernel<<<1024, 256, 0, stream>>>(Wx, Wh, bl, ws);
  conv_kernel<<<8000, 128, 0, stream>>>(images,
      k1, cb1, g1, be1, mm1, mv1,
      k2, cb2, g2, be2, mm2, mv2,
      k3, cb3, g3, be3, mm3, mv3, ws);
  lstm_kernel<<<256, 512, DYN_BYTES, stream>>>(labels, Wo, bo, Wp, bp, Wf, bf, ws,
                                               (float*)d_out);
}

// Round 5
// 6992.625 us; speedup vs baseline: 4.5727x; 1.2035x over previous
//
#include <hip/hip_runtime.h>

// ---------------- problem constants ----------------
// B=32, T=250, FEAT=128, CLASSES=25, UNITS=512, CELL=64, HEADS=4, IN_LSTM=409

// ---------------- scratch layout (floats) ----------------
constexpr size_t OFF_FEATP  = 0;                              // [8000][128]
constexpr size_t OFF_WXI    = OFF_FEATP + (size_t)8000 * 128; // [409][2048] gate-interleaved
constexpr size_t OFF_WHI    = OFF_WXI + (size_t)409 * 2048;   // [512][2048]
constexpr size_t OFF_BLI    = OFF_WHI + (size_t)512 * 2048;   // [2048]
constexpr size_t OFF_ZP0    = OFF_BLI + 2048;                 // [32][2048]
constexpr size_t OFF_ZP1    = OFF_ZP0 + (size_t)32 * 2048;    // [32][2048]
constexpr size_t OFF_OH0    = OFF_ZP1 + (size_t)32 * 2048;    // [32][512]
constexpr size_t OFF_OH1    = OFF_OH0 + (size_t)32 * 512;     // [32][512]
constexpr size_t OFF_HP0    = OFF_OH1 + (size_t)32 * 512;     // [32][320]
constexpr size_t OFF_HP1    = OFF_HP0 + (size_t)32 * 320;     // [32][320]
constexpr size_t OFF_OUTPRE = OFF_HP1 + (size_t)32 * 320;     // [32][512]
constexpr size_t OFF_HT     = OFF_OUTPRE + (size_t)32 * 512;  // [512][32]
constexpr size_t OFF_RVT    = OFF_HT + (size_t)512 * 32;      // [256][32]
constexpr size_t OFF_BAR    = OFF_RVT + (size_t)256 * 32;     // barrier ints
constexpr size_t WS_FLOATS  = OFF_BAR + 1024;

constexpr int DYN_FLOATS = 34816;                 // 136 KB dynamic LDS
constexpr int DYN_BYTES  = DYN_FLOATS * 4;

__device__ __forceinline__ float sigm(float x) { return 1.f / (1.f + __expf(-x)); }

// ---- LLC-coherent accesses (bypass L1+L2). Loads batched in asm with the
// waitcnt inside so they cannot be serialized into dependent round-trips.
__device__ __forceinline__ void st_sc(float* p, float v) {
  __hip_atomic_store(p, v, __ATOMIC_RELAXED, __HIP_MEMORY_SCOPE_AGENT);
}
__device__ __forceinline__ float ld_sc(const float* p) {
  return __hip_atomic_load(p, __ATOMIC_RELAXED, __HIP_MEMORY_SCOPE_AGENT);
}
__device__ __forceinline__ void ld8x2_sc(const double* b0, double* v) {
  const double *p0 = b0, *p1 = b0 + 512, *p2 = b0 + 1024, *p3 = b0 + 1536,
               *p4 = b0 + 2048, *p5 = b0 + 2560, *p6 = b0 + 3072, *p7 = b0 + 3584;
  asm volatile(
      "global_load_dwordx2 %0, %8, off sc0 sc1\n\t"
      "global_load_dwordx2 %1, %9, off sc0 sc1\n\t"
      "global_load_dwordx2 %2, %10, off sc0 sc1\n\t"
      "global_load_dwordx2 %3, %11, off sc0 sc1\n\t"
      "global_load_dwordx2 %4, %12, off sc0 sc1\n\t"
      "global_load_dwordx2 %5, %13, off sc0 sc1\n\t"
      "global_load_dwordx2 %6, %14, off sc0 sc1\n\t"
      "global_load_dwordx2 %7, %15, off sc0 sc1\n\t"
      "s_waitcnt vmcnt(0)"
      : "=&v"(v[0]), "=&v"(v[1]), "=&v"(v[2]), "=&v"(v[3]),
        "=&v"(v[4]), "=&v"(v[5]), "=&v"(v[6]), "=&v"(v[7])
      : "v"(p0), "v"(p1), "v"(p2), "v"(p3), "v"(p4), "v"(p5), "v"(p6), "v"(p7));
}
__device__ __forceinline__ void ldpair2_sc(const double* a, const double* b,
                                           double& x, double& y) {
  asm volatile(
      "global_load_dwordx2 %0, %2, off sc0 sc1\n\t"
      "global_load_dwordx2 %1, %3, off sc0 sc1\n\t"
      "s_waitcnt vmcnt(0)"
      : "=&v"(x), "=&v"(y) : "v"(a), "v"(b));
}
__device__ __forceinline__ void ldpair_sc(const float* a, const float* b,
                                          float& x, float& y) {
  asm volatile(
      "global_load_dword %0, %2, off sc0 sc1\n\t"
      "global_load_dword %1, %3, off sc0 sc1\n\t"
      "s_waitcnt vmcnt(0)"
      : "=&v"(x), "=&v"(y) : "v"(a), "v"(b));
}

// ---------------- weight re-layout: gate-interleaved Wx/Wh/bl ----------------
__global__ __launch_bounds__(256) void prep_kernel(const float* __restrict__ Wx,
                                                   const float* __restrict__ Wh,
                                                   const float* __restrict__ bl,
                                                   float* __restrict__ ws) {
  float* WXI = ws + OFF_WXI;
  float* WHI = ws + OFF_WHI;
  float* BLI = ws + OFF_BLI;
  const int total = 409 * 2048 + 512 * 2048 + 2048;
  for (int idx = blockIdx.x * blockDim.x + threadIdx.x; idx < total;
       idx += gridDim.x * blockDim.x) {
    if (idx < 409 * 2048) {
      int k = idx >> 11, cc = idx & 2047;
      WXI[idx] = Wx[(size_t)k * 2048 + (cc & 3) * 512 + (cc >> 2)];
    } else if (idx < 409 * 2048 + 512 * 2048) {
      int j = idx - 409 * 2048;
      int k = j >> 11, cc = j & 2047;
      WHI[j] = Wh[(size_t)k * 2048 + (cc & 3) * 512 + (cc >> 2)];
    } else {
      int cc = idx - (409 * 2048 + 512 * 2048);
      BLI[cc] = bl[(cc & 3) * 512 + (cc >> 2)];
    }
  }
}

// ---------------- conv stack (validated) ----------------
__global__ __launch_bounds__(128) void conv_kernel(
    const float* __restrict__ img,
    const float* __restrict__ k1, const float* __restrict__ cb1, const float* __restrict__ g1,
    const float* __restrict__ be1, const float* __restrict__ mm1, const float* __restrict__ mv1,
    const float* __restrict__ k2, const float* __restrict__ cb2, const float* __restrict__ g2,
    const float* __restrict__ be2, const float* __restrict__ mm2, const float* __restrict__ mv2,
    const float* __restrict__ k3, const float* __restrict__ cb3, const float* __restrict__ g3,
    const float* __restrict__ be3, const float* __restrict__ mm3, const float* __restrict__ mv3,
    float* __restrict__ ws) {
  __shared__ float s_in[784];
  __shared__ float s_y1[13 * 13 * 8];
  __shared__ float s_y2[6 * 6 * 16];
  __shared__ float s_k1[72], s_k2[1152], s_k3[4608];
  __shared__ float s_s1[8], s_b1[8], s_s2[16], s_b2[16], s_s3[32], s_b3[32];
  float* FEATP = ws + OFF_FEATP;
  const int n = blockIdx.x, tid = threadIdx.x;
  const float* ip = img + (size_t)n * 784;
  for (int i = tid; i < 784; i += 128) s_in[i] = ip[i];
  for (int i = tid; i < 72; i += 128) s_k1[i] = k1[i];
  for (int i = tid; i < 1152; i += 128) s_k2[i] = k2[i];
  for (int i = tid; i < 4608; i += 128) s_k3[i] = k3[i];
  if (tid < 8) {
    float s = g1[tid] * rsqrtf(mv1[tid] + 1e-3f);
    s_s1[tid] = s; s_b1[tid] = (cb1[tid] - mm1[tid]) * s + be1[tid];
  } else if (tid >= 32 && tid < 48) {
    int c = tid - 32;
    float s = g2[c] * rsqrtf(mv2[c] + 1e-3f);
    s_s2[c] = s; s_b2[c] = (cb2[c] - mm2[c]) * s + be2[c];
  } else if (tid >= 64 && tid < 96) {
    int c = tid - 64;
    float s = g3[c] * rsqrtf(mv3[c] + 1e-3f);
    s_s3[c] = s; s_b3[c] = (cb3[c] - mm3[c]) * s + be3[c];
  }
  __syncthreads();
  for (int idx = tid; idx < 13 * 13 * 8; idx += 128) {
    int co = idx & 7, pos = idx >> 3;
    int j = pos % 13, i = pos / 13;
    float acc = 0.f;
    #pragma unroll
    for (int ky = 0; ky < 3; ++ky)
      #pragma unroll
      for (int kx = 0; kx < 3; ++kx)
        acc += s_in[(2 * i + ky) * 28 + (2 * j + kx)] * s_k1[(ky * 3 + kx) * 8 + co];
    float v = acc * s_s1[co] + s_b1[co];
    s_y1[idx] = v > 0.f ? v : 0.f;
  }
  __syncthreads();
  for (int idx = tid; idx < 6 * 6 * 16; idx += 128) {
    int co = idx & 15, pos = idx >> 4;
    int j = pos % 6, i = pos / 6;
    float acc = 0.f;
    for (int ky = 0; ky < 3; ++ky)
      for (int kx = 0; kx < 3; ++kx) {
        int base = ((2 * i + ky) * 13 + (2 * j + kx)) * 8;
        int kb = (ky * 3 + kx) * 128 + co;
        #pragma unroll
        for (int ci = 0; ci < 8; ++ci) acc += s_y1[base + ci] * s_k2[kb + ci * 16];
      }
    float v = acc * s_s2[co] + s_b2[co];
    s_y2[idx] = v > 0.f ? v : 0.f;
  }
  __syncthreads();
  for (int idx = tid; idx < 128; idx += 128) {
    int co = idx & 31, pos = idx >> 5;
    int j = pos & 1, i = pos >> 1;
    float acc = 0.f;
    for (int ky = 0; ky < 3; ++ky)
      for (int kx = 0; kx < 3; ++kx) {
        int base = ((2 * i + ky) * 6 + (2 * j + kx)) * 16;
        int kb = (ky * 3 + kx) * 512 + co;
        #pragma unroll
        for (int ci = 0; ci < 16; ++ci) acc += s_y2[base + ci] * s_k3[kb + ci * 32];
      }
    float v = acc * s_s3[co] + s_b3[co];
    FEATP[(size_t)n * 128 + idx] = v > 0.f ? v : 0.f;
  }
}

// ---------------- persistent LSTM scan ----------------
__global__ __launch_bounds__(512) void lstm_kernel(
    const int* __restrict__ labels,
    const float* __restrict__ Wo, const float* __restrict__ bo,
    const float* __restrict__ Wp, const float* __restrict__ bp,
    const float* __restrict__ Wf, const float* __restrict__ bf,
    float* __restrict__ ws, float* __restrict__ out) {
  extern __shared__ float dyn[];
  const float* FEATP = ws + OFF_FEATP;
  const float* WXI   = ws + OFF_WXI;
  const float* WHI   = ws + OFF_WHI;
  const float* BLI   = ws + OFF_BLI;
  float* ZP0    = ws + OFF_ZP0;
  float* ZP1    = ws + OFF_ZP1;
  float* OH0    = ws + OFF_OH0;
  float* OH1    = ws + OFF_OH1;
  float* HP0    = ws + OFF_HP0;
  float* HP1    = ws + OFF_HP1;
  float* OUTPRE = ws + OFF_OUTPRE;
  float* HT     = ws + OFF_HT;
  float* RVT    = ws + OFF_RVT;
  int*   BARp   = (int*)(ws + OFF_BAR);

  const int bid = blockIdx.x;
  const int tid = threadIdx.x;
  int barGen = 0;

  auto gbar = [&]() {
    asm volatile("s_waitcnt vmcnt(0) lgkmcnt(0)" ::: "memory");
    __syncthreads();
    ++barGen;
    if (tid == 0) {
      int a = __hip_atomic_fetch_add(&BARp[(bid & 7) << 6], 1, __ATOMIC_RELAXED,
                                     __HIP_MEMORY_SCOPE_AGENT);
      if ((a & 31) == 31) {
        int r = __hip_atomic_fetch_add(&BARp[512], 1, __ATOMIC_RELAXED,
                                       __HIP_MEMORY_SCOPE_AGENT);
        if ((r & 7) == 7) {
          __hip_atomic_fetch_add(&BARp[576], 1, __ATOMIC_RELAXED,
                                 __HIP_MEMORY_SCOPE_AGENT);
        }
      }
      while (__hip_atomic_load(&BARp[576], __ATOMIC_RELAXED,
                               __HIP_MEMORY_SCOPE_AGENT) < barGen) {
        __builtin_amdgcn_s_sleep(1);
      }
    }
    __syncthreads();
  };

  // stage 8192-float [256][32] coherent buffer into [256][36]-padded LDS tile
  auto stage_act = [&](float* dst, const float* src) {
    double v[8];
    ld8x2_sc((const double*)src + tid, v);
    #pragma unroll
    for (int j = 0; j < 8; ++j) {
      int i = (tid + j * 512) << 1;
      *(double*)&dst[(i >> 5) * 36 + (i & 31)] = v[j];
    }
  };

  // ---- E32: Y[32c][32b] = sum_k W[k][32] * A[k][36-padded], K multiple of 8.
  // lane tile 4c x 4b, 8 waves k-split, part[4][32][36], returns 2 outputs:
  // (c = tid&31, b = (tid>>5)*2) and (c, b+1).
  auto E32 = [&](const float* Wm, const float* Am, int K, float* part, float2& r) {
    const int wv = tid >> 6, l = tid & 63, cg = l & 7, bg = l >> 3;
    const int Kp = K >> 3;
    const float* wp = Wm + (size_t)(wv * Kp) * 32 + cg * 4;
    const float* ap = Am + (size_t)(wv * Kp) * 36 + bg * 4;
    float4 a0 = {0,0,0,0}, a1 = a0, a2 = a0, a3 = a0;
    #pragma unroll 8
    for (int kk = 0; kk < Kp; ++kk) {
      float4 w = *(const float4*)(wp + kk * 32);
      float4 a = *(const float4*)(ap + kk * 36);
      a0.x = fmaf(w.x, a.x, a0.x); a0.y = fmaf(w.x, a.y, a0.y);
      a0.z = fmaf(w.x, a.z, a0.z); a0.w = fmaf(w.x, a.w, a0.w);
      a1.x = fmaf(w.y, a.x, a1.x); a1.y = fmaf(w.y, a.y, a1.y);
      a1.z = fmaf(w.y, a.z, a1.z); a1.w = fmaf(w.y, a.w, a1.w);
      a2.x = fmaf(w.z, a.x, a2.x); a2.y = fmaf(w.z, a.y, a2.y);
      a2.z = fmaf(w.z, a.z, a2.z); a2.w = fmaf(w.z, a.w, a2.w);
      a3.x = fmaf(w.w, a.x, a3.x); a3.y = fmaf(w.w, a.y, a3.y);
      a3.z = fmaf(w.w, a.z, a3.z); a3.w = fmaf(w.w, a.w, a3.w);
    }
    const int ob = (cg * 4) * 36 + bg * 4;
    if (wv < 4) {
      float* pb = part + wv * 1152 + ob;
      *(float4*)(pb)       = a0;
      *(float4*)(pb + 36)  = a1;
      *(float4*)(pb + 72)  = a2;
      *(float4*)(pb + 108) = a3;
    }
    __syncthreads();
    if (wv >= 4) {
      float* pb = part + (wv - 4) * 1152 + ob;
      float4 t;
      t = *(float4*)(pb);       t.x+=a0.x; t.y+=a0.y; t.z+=a0.z; t.w+=a0.w; *(float4*)(pb)       = t;
      t = *(float4*)(pb + 36);  t.x+=a1.x; t.y+=a1.y; t.z+=a1.z; t.w+=a1.w; *(float4*)(pb + 36)  = t;
      t = *(float4*)(pb + 72);  t.x+=a2.x; t.y+=a2.y; t.z+=a2.z; t.w+=a2.w; *(float4*)(pb + 72)  = t;
      t = *(float4*)(pb + 108); t.x+=a3.x; t.y+=a3.y; t.z+=a3.z; t.w+=a3.w; *(float4*)(pb + 108) = t;
    }
    __syncthreads();
    const int c = tid & 31, b2 = (tid >> 5) * 2;
    const int o = c * 36 + b2;
    float2 s0 = *(float2*)(part + o);
    float2 s1 = *(float2*)(part + 1152 + o);
    float2 s2 = *(float2*)(part + 2304 + o);
    float2 s3 = *(float2*)(part + 3456 + o);
    r.x = (s0.x + s1.x) + (s2.x + s3.x);
    r.y = (s0.y + s1.y) + (s2.y + s3.y);
  };

  // ---- E64: Y[64c][32b], lane tile 8c x 4b, part[4][64][36], returns 4
  // outputs: (c = tid&63, b = (tid>>6)*4 .. +3)
  auto E64 = [&](const float* Wm, const float* Am, int K, float* part, float4& r) {
    const int wv = tid >> 6, l = tid & 63, cg = l & 7, bg = l >> 3;
    const int Kp = K >> 3;
    const float* wp = Wm + (size_t)(wv * Kp) * 64 + cg * 8;
    const float* ap = Am + (size_t)(wv * Kp) * 36 + bg * 4;
    float4 acc[8];
    #pragma unroll
    for (int i = 0; i < 8; ++i) acc[i] = {0,0,0,0};
    #pragma unroll 4
    for (int kk = 0; kk < Kp; ++kk) {
      float4 w0 = *(const float4*)(wp + kk * 64);
      float4 w1 = *(const float4*)(wp + kk * 64 + 4);
      float4 a  = *(const float4*)(ap + kk * 36);
      float wl[8];
      *(float4*)&wl[0] = w0; *(float4*)&wl[4] = w1;
      #pragma unroll
      for (int i = 0; i < 8; ++i) {
        acc[i].x = fmaf(wl[i], a.x, acc[i].x);
        acc[i].y = fmaf(wl[i], a.y, acc[i].y);
        acc[i].z = fmaf(wl[i], a.z, acc[i].z);
        acc[i].w = fmaf(wl[i], a.w, acc[i].w);
      }
    }
    const int ob = (cg * 8) * 36 + bg * 4;
    if (wv < 4) {
      float* pb = part + wv * 2304 + ob;
      #pragma unroll
      for (int i = 0; i < 8; ++i) *(float4*)(pb + i * 36) = acc[i];
    }
    __syncthreads();
    if (wv >= 4) {
      float* pb = part + (wv - 4) * 2304 + ob;
      #pragma unroll
      for (int i = 0; i < 8; ++i) {
        float4 t = *(float4*)(pb + i * 36);
        t.x += acc[i].x; t.y += acc[i].y; t.z += acc[i].z; t.w += acc[i].w;
        *(float4*)(pb + i * 36) = t;
      }
    }
    __syncthreads();
    const int c = tid & 63, b4 = (tid >> 6) * 4;
    const int o = c * 36 + b4;
    float4 s0 = *(float4*)(part + o);
    float4 s1 = *(float4*)(part + 2304 + o);
    float4 s2 = *(float4*)(part + 4608 + o);
    float4 s3 = *(float4*)(part + 6912 + o);
    r.x = (s0.x + s1.x) + (s2.x + s3.x);
    r.y = (s0.y + s1.y) + (s2.y + s3.y);
    r.z = (s0.z + s1.z) + (s2.z + s3.z);
    r.w = (s0.w + s1.w) + (s2.w + s3.w);
  };

  // ---------------- one-time init: weights -> LDS ----------------
  if (bid < 64) {            // AZ: W [256][32] = WXI rows 153..408
    const int c0 = bid * 32;
    for (int i = tid; i < 8192; i += 512)
      dyn[i] = WXI[(size_t)(153 + (i >> 5)) * 2048 + c0 + (i & 31)];
    if (tid < 256) dyn[8192 + tid] = 0.f;  // Cst
  } else if (bid < 80) {     // AO: W [256][32] = Wo rows 512..767
    const int u0 = (bid - 64) * 32;
    for (int i = tid; i < 8192; i += 512)
      dyn[i] = Wo[(size_t)(512 + (i >> 5)) * 512 + u0 + (i & 31)];
    if (tid < 32) dyn[8192 + tid] = bo[u0 + tid];
  } else if (bid < 144) {    // BL: W [384][32] = WXI rows 0..127 + WHI rows 0..255
    const int c0 = (bid - 80) * 32;
    for (int i = tid; i < 4096; i += 512)
      dyn[i] = WXI[(size_t)(i >> 5) * 2048 + c0 + (i & 31)];
    for (int i = tid; i < 8192; i += 512)
      dyn[4096 + i] = WHI[(size_t)(i >> 5) * 2048 + c0 + (i & 31)];
    if (tid < 32) dyn[12320 + tid] = BLI[c0 + tid];
  } else if (bid < 176) {    // BH: W [256][64] = WHI rows 256..511
    const int c0 = (bid - 144) * 64;
    for (int i = tid; i < 16384; i += 512)
      dyn[i] = WHI[(size_t)(256 + (i >> 6)) * 2048 + c0 + (i & 63)];
  } else if (bid < 192) {    // OL: Wo rows 0..255
    const int u0 = (bid - 176) * 32;
    for (int i = tid; i < 8192; i += 512)
      dyn[i] = Wo[(size_t)(i >> 5) * 512 + u0 + (i & 31)];
  } else if (bid < 208) {    // OHI: Wo rows 256..511
    const int u0 = (bid - 192) * 32;
    for (int i = tid; i < 8192; i += 512)
      dyn[i] = Wo[(size_t)(256 + (i >> 5)) * 512 + u0 + (i & 31)];
  } else if (bid < 218) {    // PL: Wp rows 0..255
    const int j0 = (bid - 208) * 32;
    for (int i = tid; i < 8192; i += 512)
      dyn[i] = Wp[(size_t)(i >> 5) * 320 + j0 + (i & 31)];
  } else if (bid < 223) {    // PHI: Wp rows 256..511, [256][64]
    const int j0 = (bid - 218) * 64;
    for (int i = tid; i < 16384; i += 512)
      dyn[i] = Wp[(size_t)(256 + (i >> 6)) * 320 + j0 + (i & 63)];
  } else if (bid < 255) {    // CA
    for (int i = tid; i < 17000; i += 512) dyn[i] = 0.f;       // ring[250][68]
    for (int i = tid; i < 12800; i += 512) dyn[17000 + i] = Wf[i];
    for (int i = tid; i < 320; i += 512) dyn[29800 + i] = bp[i];
    if (tid < 25) dyn[30120 + tid] = bf[tid];
  }
  __syncthreads();

  // ---------------- slot bodies ----------------
  // AZ prefetch (slot3): zf[b][32c] = ZP0+ZP1
  auto azPre = [&]() {
    const int c0 = bid * 32;
    float* zf = dyn + 17664;
    const int b = tid >> 4, c2 = tid & 15;
    double x, y;
    ldpair2_sc((const double*)(ZP0 + (size_t)b * 2048 + c0) + c2,
               (const double*)(ZP1 + (size_t)b * 2048 + c0) + c2, x, y);
    float2 fx = *(float2*)&x, fy = *(float2*)&y;
    float2 s = {fx.x + fy.x, fx.y + fy.y};
    *(double*)&zf[b * 32 + c2 * 2] = *(double*)&s;
  };
  // AO prefetch (slot3): of[b][32u] = OH0+OH1
  auto aoPre = [&]() {
    const int u0 = (bid - 64) * 32;
    float* of = dyn + 17440;
    const int b = tid >> 4, c2 = tid & 15;
    double x, y;
    ldpair2_sc((const double*)(OH0 + b * 512 + u0) + c2,
               (const double*)(OH1 + b * 512 + u0) + c2, x, y);
    float2 fx = *(float2*)&x, fy = *(float2*)&y;
    float2 s = {fx.x + fy.x, fx.y + fy.y};
    *(double*)&of[b * 32 + c2 * 2] = *(double*)&s;
  };
  // AZ gates (slot1)
  auto azGates = [&]() {
    float* Wz = dyn; float* Cst = dyn + 8192; float* rvT = dyn + 8448;
    float* zf = dyn + 17664; float* part = dyn + 18688;
    stage_act(rvT, RVT);
    __syncthreads();
    float2 r;
    E32(Wz, rvT, 256, part, r);
    const int c = tid & 31, b2 = (tid >> 5) * 2;
    zf[b2 * 32 + c] += r.x;
    zf[(b2 + 1) * 32 + c] += r.y;
    __syncthreads();
    if (tid < 256) {
      int u = tid & 7, b = tid >> 3;
      float4 z = *(float4*)(zf + b * 32 + u * 4);
      float ig = sigm(z.x), fg = sigm(z.y), gg = tanhf(z.z), og = sigm(z.w);
      float cc = fg * Cst[b * 8 + u] + ig * gg;
      Cst[b * 8 + u] = cc;
      st_sc(&HT[(size_t)(bid * 8 + u) * 32 + b], og * tanhf(cc));
    }
  };
  // AO (slot1): outpre_{t-1}
  auto aoOut = [&]() {
    const int u0 = (bid - 64) * 32;
    float* W = dyn; float* bo_l = dyn + 8192; float* rvT = dyn + 8224;
    float* of = dyn + 17440; float* part = dyn + 18464;
    stage_act(rvT, RVT);
    __syncthreads();
    float2 r;
    E32(W, rvT, 256, part, r);
    const int c = tid & 31, b2 = (tid >> 5) * 2;
    float bv = bo_l[c];
    st_sc(&OUTPRE[b2 * 512 + u0 + c], r.x + of[b2 * 32 + c] + bv);
    st_sc(&OUTPRE[(b2 + 1) * 512 + u0 + c], r.y + of[(b2 + 1) * 32 + c] + bv);
  };
  // BL x-staging (slot1)
  auto blStageX = [&](int tt1) {
    float* xA = dyn + 12352; int* slab = (int*)(dyn + 12288);
    for (int i = tid; i < 4096; i += 512) {
      int b = i >> 7, k = i & 127;
      xA[k * 36 + b] = FEATP[((size_t)b * 250 + tt1) * 128 + k];
    }
    if (tid < 32) slab[tid] = labels[tid * 250 + tt1];
  };
  // B gemms (slot2)
  auto bGemm = [&]() {
    if (bid >= 80 && bid < 144) {        // BL: zacc LO, K=384 (x128 + h0..255)
      const int c0 = (bid - 80) * 32;
      float* W = dyn; int* slab = (int*)(dyn + 12288); float* blc = dyn + 12320;
      float* A = dyn + 12352; float* part = dyn + 26176;
      stage_act(A + 128 * 36, HT);
      __syncthreads();
      float2 r;
      E32(W, A, 384, part, r);
      const int c = tid & 31, b2 = (tid >> 5) * 2;
      float base = blc[c];
      int l0 = slab[b2], l1 = slab[b2 + 1];
      float w0 = WXI[(size_t)(128 + l0) * 2048 + c0 + c];
      float w1 = WXI[(size_t)(128 + l1) * 2048 + c0 + c];
      st_sc(&ZP0[(size_t)b2 * 2048 + c0 + c], r.x + base + w0);
      st_sc(&ZP0[(size_t)(b2 + 1) * 2048 + c0 + c], r.y + base + w1);
    } else if (bid >= 144 && bid < 176) { // BH: zacc HI, K=256
      const int c0 = (bid - 144) * 64;
      float* W = dyn; float* A = dyn + 16384; float* part = dyn + 25600;
      stage_act(A, HT + 8192);
      __syncthreads();
      float4 r;
      E64(W, A, 256, part, r);
      const int c = tid & 63, b4 = (tid >> 6) * 4;
      st_sc(&ZP1[(size_t)(b4 + 0) * 2048 + c0 + c], r.x);
      st_sc(&ZP1[(size_t)(b4 + 1) * 2048 + c0 + c], r.y);
      st_sc(&ZP1[(size_t)(b4 + 2) * 2048 + c0 + c], r.z);
      st_sc(&ZP1[(size_t)(b4 + 3) * 2048 + c0 + c], r.w);
    } else if (bid >= 176 && bid < 218) { // OL / OHI / PL
      float* W = dyn; float* A = dyn + 8192; float* part = dyn + 17408;
      const bool isOL = bid < 192, isOHI = (bid >= 192 && bid < 208);
      stage_act(A, isOHI ? (HT + 8192) : HT);
      __syncthreads();
      float2 r;
      E32(W, A, 256, part, r);
      const int c = tid & 31, b2 = (tid >> 5) * 2;
      if (isOL) {
        const int u0 = (bid - 176) * 32;
        st_sc(&OH0[b2 * 512 + u0 + c], r.x);
        st_sc(&OH0[(b2 + 1) * 512 + u0 + c], r.y);
      } else if (isOHI) {
        const int u0 = (bid - 192) * 32;
        st_sc(&OH1[b2 * 512 + u0 + c], r.x);
        st_sc(&OH1[(b2 + 1) * 512 + u0 + c], r.y);
      } else {
        const int j0 = (bid - 208) * 32;
        st_sc(&HP0[b2 * 320 + j0 + c], r.x);
        st_sc(&HP0[(b2 + 1) * 320 + j0 + c], r.y);
      }
    } else if (bid >= 218 && bid < 223) { // PHI
      const int j0 = (bid - 218) * 64;
      float* W = dyn; float* A = dyn + 16384; float* part = dyn + 25600;
      stage_act(A, HT + 8192);
      __syncthreads();
      float4 r;
      E64(W, A, 256, part, r);
      const int c = tid & 63, b4 = (tid >> 6) * 4;
      st_sc(&HP1[(b4 + 0) * 320 + j0 + c], r.x);
      st_sc(&HP1[(b4 + 1) * 320 + j0 + c], r.y);
      st_sc(&HP1[(b4 + 2) * 320 + j0 + c], r.z);
      st_sc(&HP1[(b4 + 3) * 320 + j0 + c], r.w);
    }
  };
  // CA output (slot2): softmax(out) for step t-1
  auto caOut = [&](int t) {
    float* WfL = dyn + 17000; float* bfL = dyn + 30120;
    float* to  = dyn + 32312; float* lp = dyn + 32824; float* lg = dyn + 33224;
    const int b = bid - 223;
    to[tid] = tanhf(ld_sc(&OUTPRE[b * 512 + tid]));
    __syncthreads();
    if (tid < 400) {
      int l = tid % 25, p = tid / 25;
      float s = 0.f;
      #pragma unroll
      for (int q = 0; q < 32; ++q) { int k = p * 32 + q; s += to[k] * WfL[k * 25 + l]; }
      lp[p * 25 + l] = s;
    }
    __syncthreads();
    if (tid < 25) {
      float s = bfL[tid];
      #pragma unroll
      for (int p = 0; p < 16; ++p) s += lp[p * 25 + tid];
      lg[tid] = s;
    }
    __syncthreads();
    if (tid == 0) {
      float mx = lg[0];
      for (int l = 1; l < 25; ++l) mx = fmaxf(mx, lg[l]);
      float ss = 0.f;
      for (int l = 0; l < 25; ++l) ss += __expf(lg[l] - mx);
      lg[25] = mx; lg[26] = 1.f / ss;
    }
    __syncthreads();
    if (tid < 25)
      out[((size_t)b * 250 + (t - 1)) * 25 + tid] = __expf(lg[tid] - lg[25]) * lg[26];
  };
  // CA attention (slot3)
  auto caAtt = [&](int t) {
    float* ring = dyn;
    float* bpL  = dyn + 29800;
    float* hid  = dyn + 30152;
    float* kn   = dyn + 30472;
    float* att4 = dyn + 30728;
    float* red  = dyn + 31752;
    float* msum = dyn + 31784;
    float* rvp  = dyn + 31800;
    const int b = bid - 223;
    if (tid < 320) {
      float x, y;
      ldpair_sc(&HP0[b * 320 + tid], &HP1[b * 320 + tid], x, y);
      hid[tid] = tanhf(x + y + bpL[tid]);
    }
    __syncthreads();
    if (tid < 256) {
      float v = hid[64 + tid]; float pq = v * v;
      for (int off = 32; off; off >>= 1) pq += __shfl_down(pq, off, 64);
      if ((tid & 63) == 0) red[tid >> 6] = rsqrtf(fmaxf(pq, 1e-12f));
    }
    __syncthreads();
    if (tid < 256) kn[tid] = hid[64 + tid] * red[tid >> 6];
    __syncthreads();
    const int start = (250 - t) % 250;
    if (tid < 500) {
      int m = tid >> 1, dh = tid & 1;
      int p = start + m; if (p >= 250) p -= 250;
      const float* cell = ring + p * 68;
      const float* k0 = kn + dh * 128;
      float n2 = 0.f, d0 = 0.f, d1 = 0.f;
      #pragma unroll
      for (int s = 0; s < 64; s += 4) {
        float4 q = *(const float4*)(cell + s);
        n2 += q.x * q.x + q.y * q.y + q.z * q.z + q.w * q.w;
        d0 += k0[s] * q.x + k0[s + 1] * q.y + k0[s + 2] * q.z + k0[s + 3] * q.w;
        d1 += k0[64 + s] * q.x + k0[64 + s + 1] * q.y + k0[64 + s + 2] * q.z + k0[64 + s + 3] * q.w;
      }
      float rs = rsqrtf(fmaxf(n2, 1e-12f));
      att4[(2 * dh) * 256 + m] = d0 * rs;
      att4[(2 * dh + 1) * 256 + m] = d1 * rs;
    }
    __syncthreads();
    {
      int h4 = tid >> 7, mm = tid & 127;
      float v0 = att4[h4 * 256 + mm];
      bool has2 = (mm + 128) < 250;
      float v1 = has2 ? att4[h4 * 256 + mm + 128] : -3.0e38f;
      float mx = fmaxf(v0, v1);
      for (int off = 32; off; off >>= 1) mx = fmaxf(mx, __shfl_down(mx, off, 64));
      if ((tid & 63) == 0) red[tid >> 6] = mx;
      __syncthreads();
      float MX = fmaxf(red[h4 * 2], red[h4 * 2 + 1]);
      float e0 = __expf(v0 - MX);
      float e1 = has2 ? __expf(v1 - MX) : 0.f;
      att4[h4 * 256 + mm] = e0;
      if (has2) att4[h4 * 256 + mm + 128] = e1;
      float sm_ = e0 + e1;
      for (int off = 32; off; off >>= 1) sm_ += __shfl_down(sm_, off, 64);
      if ((tid & 63) == 0) red[8 + (tid >> 6)] = sm_;
      __syncthreads();
      if (tid < 4) msum[tid] = red[8 + tid * 2] + red[8 + tid * 2 + 1];
      __syncthreads();
    }
    {
      int h4 = tid >> 7, s = tid & 63, mh = (tid >> 6) & 1;
      float a = 0.f;
      for (int m = mh * 125; m < mh * 125 + 125; ++m) {
        int p = start + m; if (p >= 250) p -= 250;
        a += att4[h4 * 256 + m] * ring[p * 68 + s];
      }
      rvp[tid] = a;
    }
    __syncthreads();
    if (tid < 256) {
      int h4 = tid >> 6, s = tid & 63;
      float rv = (rvp[h4 * 128 + s] + rvp[h4 * 128 + 64 + s]) / msum[h4];
      st_sc(&RVT[(h4 * 64 + s) * 32 + b], rv);
    }
    __syncthreads();
    if (tid < 64) {
      int ip = start + 249; if (ip >= 250) ip -= 250;
      ring[ip * 68 + tid] = hid[tid];
    }
  };

  const bool isAZ = bid < 64, isAO = (bid >= 64 && bid < 80),
             isBL = (bid >= 80 && bid < 144), isB = (bid >= 80 && bid < 223),
             isCA = (bid >= 223 && bid < 255);

  // ---------------- main sequence ----------------
  if (isBL) blStageX(0);
  if (isB) bGemm();
  gbar();
  if (isAZ) azPre();
  if (isAO) aoPre();
  gbar();
  for (int t = 0; t < 250; ++t) {
    // slot1: gates + outpre_{t-1} + x-staging
    if (isAZ) azGates();
    else if (isAO && t >= 1) aoOut();
    else if (isBL) blStageX(t + 1 <= 249 ? t + 1 : 249);
    gbar();
    // slot2: B gemms + output softmax for t-1
    if (isB) bGemm();
    else if (isCA && t >= 1) caOut(t);
    gbar();
    // slot3: attention + A prefetch
    if (isCA) caAtt(t);
    else if (isAZ) azPre();
    else if (isAO) aoPre();
    gbar();
  }
  // epilogue: outpre_249 -> out[249]
  if (isAO) aoOut();
  gbar();
  if (isCA) caOut(250);
}

extern "C" void kernel_launch(void* const* d_in, const int* in_sizes, int n_in,
                              void* d_out, int out_size, void* d_ws, size_t ws_size,
                              hipStream_t stream) {
  const float* images = (const float*)d_in[0];
  const int* labels = (const int*)d_in[1];
  const float* k1  = (const float*)d_in[2];
  const float* cb1 = (const float*)d_in[3];
  const float* g1  = (const float*)d_in[4];
  const float* be1 = (const float*)d_in[5];
  const float* mm1 = (const float*)d_in[6];
  const float* mv1 = (const float*)d_in[7];
  const float* k2  = (const float*)d_in[8];
  const float* cb2 = (const float*)d_in[9];
  const float* g2  = (const float*)d_in[10];
  const float* be2 = (const float*)d_in[11];
  const float* mm2 = (const float*)d_in[12];
  const float* mv2 = (const float*)d_in[13];
  const float* k3  = (const float*)d_in[14];
  const float* cb3 = (const float*)d_in[15];
  const float* g3  = (const float*)d_in[16];
  const float* be3 = (const float*)d_in[17];
  const float* mm3 = (const float*)d_in[18];
  const float* mv3 = (const float*)d_in[19];
  const float* Wx  = (const float*)d_in[20];
  const float* Wh  = (const float*)d_in[21];
  const float* bl  = (const float*)d_in[22];
  const float* Wp  = (const float*)d_in[23];
  const float* bp  = (const float*)d_in[24];
  const float* Wo  = (const float*)d_in[25];
  const float* bo  = (const float*)d_in[26];
  const float* Wf  = (const float*)d_in[27];
  const float* bf  = (const float*)d_in[28];
  float* ws = (float*)d_ws;

  hipFuncSetAttribute((const void*)lstm_kernel,
                      hipFuncAttributeMaxDynamicSharedMemorySize, DYN_BYTES);

  // zero activation/state/barrier region (ws poisoned 0xAA before each call)
  hipMemsetAsync((char*)d_ws + OFF_ZP0 * sizeof(float), 0,
                 (WS_FLOATS - OFF_ZP0) * sizeof(float), stream);
  prep_kernel<<<1024, 256, 0, stream>>>(Wx, Wh, bl, ws);
  conv_kernel<<<8000, 128, 0, stream>>>(images,
      k1, cb1, g1, be1, mm1, mv1,
      k2, cb2, g2, be2, mm2, mv2,
      k3, cb3, g3, be3, mm3, mv3, ws);
  lstm_kernel<<<256, 512, DYN_BYTES, stream>>>(labels, Wo, bo, Wp, bp, Wf, bf, ws,
                                               (float*)d_out);
}

// Round 6
// 6880.464 us; speedup vs baseline: 4.6472x; 1.0163x over previous
//
#include <hip/hip_runtime.h>

// ---------------- problem constants ----------------
// B=32, T=250, FEAT=128, CLASSES=25, UNITS=512, CELL=64, HEADS=4, IN_LSTM=409

// ---------------- scratch layout (floats) ----------------
constexpr size_t OFF_FEATP  = 0;                              // [8000][128]
constexpr size_t OFF_WXI    = OFF_FEATP + (size_t)8000 * 128; // [409][2048] gate-interleaved
constexpr size_t OFF_WHI    = OFF_WXI + (size_t)409 * 2048;   // [512][2048]
constexpr size_t OFF_BLI    = OFF_WHI + (size_t)512 * 2048;   // [2048]
constexpr size_t OFF_ZP0    = OFF_BLI + 2048;                 // [32][2048] zacc partial (h-lo + bl + label)
constexpr size_t OFF_ZP1    = OFF_ZP0 + (size_t)32 * 2048;    // [32][2048] zacc partial (h-hi)
constexpr size_t OFF_OH0    = OFF_ZP1 + (size_t)32 * 2048;    // [32][512]
constexpr size_t OFF_OH1    = OFF_OH0 + (size_t)32 * 512;     // [32][512]
constexpr size_t OFF_HP0    = OFF_OH1 + (size_t)32 * 512;     // [32][320]
constexpr size_t OFF_HP1    = OFF_HP0 + (size_t)32 * 320;     // [32][320]
constexpr size_t OFF_OUTPRE = OFF_HP1 + (size_t)32 * 320;     // [32][512]
constexpr size_t OFF_HT     = OFF_OUTPRE + (size_t)32 * 512;  // [512][32]
constexpr size_t OFF_RVT    = OFF_HT + (size_t)512 * 32;      // [256][32]
constexpr size_t OFF_BAR    = OFF_RVT + (size_t)256 * 32;     // barrier ints
constexpr size_t WS_FLOATS  = OFF_BAR + 1024;

constexpr int DYN_FLOATS = 34816;                 // 136 KB dynamic LDS
constexpr int DYN_BYTES  = DYN_FLOATS * 4;

__device__ __forceinline__ float sigm(float x) { return 1.f / (1.f + __expf(-x)); }

// ---- LLC-coherent accesses (bypass L1+L2). Loads batched in asm with the
// waitcnt inside so they cannot be serialized into dependent round-trips.
__device__ __forceinline__ void st_sc(float* p, float v) {
  __hip_atomic_store(p, v, __ATOMIC_RELAXED, __HIP_MEMORY_SCOPE_AGENT);
}
__device__ __forceinline__ float ld_sc(const float* p) {
  return __hip_atomic_load(p, __ATOMIC_RELAXED, __HIP_MEMORY_SCOPE_AGENT);
}
__device__ __forceinline__ void ld8x2_sc(const double* b0, double* v) {
  const double *p0 = b0, *p1 = b0 + 512, *p2 = b0 + 1024, *p3 = b0 + 1536,
               *p4 = b0 + 2048, *p5 = b0 + 2560, *p6 = b0 + 3072, *p7 = b0 + 3584;
  asm volatile(
      "global_load_dwordx2 %0, %8, off sc0 sc1\n\t"
      "global_load_dwordx2 %1, %9, off sc0 sc1\n\t"
      "global_load_dwordx2 %2, %10, off sc0 sc1\n\t"
      "global_load_dwordx2 %3, %11, off sc0 sc1\n\t"
      "global_load_dwordx2 %4, %12, off sc0 sc1\n\t"
      "global_load_dwordx2 %5, %13, off sc0 sc1\n\t"
      "global_load_dwordx2 %6, %14, off sc0 sc1\n\t"
      "global_load_dwordx2 %7, %15, off sc0 sc1\n\t"
      "s_waitcnt vmcnt(0)"
      : "=&v"(v[0]), "=&v"(v[1]), "=&v"(v[2]), "=&v"(v[3]),
        "=&v"(v[4]), "=&v"(v[5]), "=&v"(v[6]), "=&v"(v[7])
      : "v"(p0), "v"(p1), "v"(p2), "v"(p3), "v"(p4), "v"(p5), "v"(p6), "v"(p7));
}
// 8 rv loads + 2 partial loads, one waitcnt (slot1 staging)
__device__ __forceinline__ void ld10x2_sc(const double* b0, const double* z0,
                                          const double* z1, double* v) {
  const double *p0 = b0, *p1 = b0 + 512, *p2 = b0 + 1024, *p3 = b0 + 1536,
               *p4 = b0 + 2048, *p5 = b0 + 2560, *p6 = b0 + 3072, *p7 = b0 + 3584;
  asm volatile(
      "global_load_dwordx2 %0, %10, off sc0 sc1\n\t"
      "global_load_dwordx2 %1, %11, off sc0 sc1\n\t"
      "global_load_dwordx2 %2, %12, off sc0 sc1\n\t"
      "global_load_dwordx2 %3, %13, off sc0 sc1\n\t"
      "global_load_dwordx2 %4, %14, off sc0 sc1\n\t"
      "global_load_dwordx2 %5, %15, off sc0 sc1\n\t"
      "global_load_dwordx2 %6, %16, off sc0 sc1\n\t"
      "global_load_dwordx2 %7, %17, off sc0 sc1\n\t"
      "global_load_dwordx2 %8, %18, off sc0 sc1\n\t"
      "global_load_dwordx2 %9, %19, off sc0 sc1\n\t"
      "s_waitcnt vmcnt(0)"
      : "=&v"(v[0]), "=&v"(v[1]), "=&v"(v[2]), "=&v"(v[3]), "=&v"(v[4]),
        "=&v"(v[5]), "=&v"(v[6]), "=&v"(v[7]), "=&v"(v[8]), "=&v"(v[9])
      : "v"(p0), "v"(p1), "v"(p2), "v"(p3), "v"(p4), "v"(p5), "v"(p6), "v"(p7),
        "v"(z0), "v"(z1));
}
__device__ __forceinline__ void ldpair_sc(const float* a, const float* b,
                                          float& x, float& y) {
  asm volatile(
      "global_load_dword %0, %2, off sc0 sc1\n\t"
      "global_load_dword %1, %3, off sc0 sc1\n\t"
      "s_waitcnt vmcnt(0)"
      : "=&v"(x), "=&v"(y) : "v"(a), "v"(b));
}

// ---------------- weight re-layout: gate-interleaved Wx/Wh/bl ----------------
__global__ __launch_bounds__(256) void prep_kernel(const float* __restrict__ Wx,
                                                   const float* __restrict__ Wh,
                                                   const float* __restrict__ bl,
                                                   float* __restrict__ ws) {
  float* WXI = ws + OFF_WXI;
  float* WHI = ws + OFF_WHI;
  float* BLI = ws + OFF_BLI;
  const int total = 409 * 2048 + 512 * 2048 + 2048;
  for (int idx = blockIdx.x * blockDim.x + threadIdx.x; idx < total;
       idx += gridDim.x * blockDim.x) {
    if (idx < 409 * 2048) {
      int k = idx >> 11, cc = idx & 2047;
      WXI[idx] = Wx[(size_t)k * 2048 + (cc & 3) * 512 + (cc >> 2)];
    } else if (idx < 409 * 2048 + 512 * 2048) {
      int j = idx - 409 * 2048;
      int k = j >> 11, cc = j & 2047;
      WHI[j] = Wh[(size_t)k * 2048 + (cc & 3) * 512 + (cc >> 2)];
    } else {
      int cc = idx - (409 * 2048 + 512 * 2048);
      BLI[cc] = bl[(cc & 3) * 512 + (cc >> 2)];
    }
  }
}

// ---------------- conv stack (validated) ----------------
__global__ __launch_bounds__(128) void conv_kernel(
    const float* __restrict__ img,
    const float* __restrict__ k1, const float* __restrict__ cb1, const float* __restrict__ g1,
    const float* __restrict__ be1, const float* __restrict__ mm1, const float* __restrict__ mv1,
    const float* __restrict__ k2, const float* __restrict__ cb2, const float* __restrict__ g2,
    const float* __restrict__ be2, const float* __restrict__ mm2, const float* __restrict__ mv2,
    const float* __restrict__ k3, const float* __restrict__ cb3, const float* __restrict__ g3,
    const float* __restrict__ be3, const float* __restrict__ mm3, const float* __restrict__ mv3,
    float* __restrict__ ws) {
  __shared__ float s_in[784];
  __shared__ float s_y1[13 * 13 * 8];
  __shared__ float s_y2[6 * 6 * 16];
  __shared__ float s_k1[72], s_k2[1152], s_k3[4608];
  __shared__ float s_s1[8], s_b1[8], s_s2[16], s_b2[16], s_s3[32], s_b3[32];
  float* FEATP = ws + OFF_FEATP;
  const int n = blockIdx.x, tid = threadIdx.x;
  const float* ip = img + (size_t)n * 784;
  for (int i = tid; i < 784; i += 128) s_in[i] = ip[i];
  for (int i = tid; i < 72; i += 128) s_k1[i] = k1[i];
  for (int i = tid; i < 1152; i += 128) s_k2[i] = k2[i];
  for (int i = tid; i < 4608; i += 128) s_k3[i] = k3[i];
  if (tid < 8) {
    float s = g1[tid] * rsqrtf(mv1[tid] + 1e-3f);
    s_s1[tid] = s; s_b1[tid] = (cb1[tid] - mm1[tid]) * s + be1[tid];
  } else if (tid >= 32 && tid < 48) {
    int c = tid - 32;
    float s = g2[c] * rsqrtf(mv2[c] + 1e-3f);
    s_s2[c] = s; s_b2[c] = (cb2[c] - mm2[c]) * s + be2[c];
  } else if (tid >= 64 && tid < 96) {
    int c = tid - 64;
    float s = g3[c] * rsqrtf(mv3[c] + 1e-3f);
    s_s3[c] = s; s_b3[c] = (cb3[c] - mm3[c]) * s + be3[c];
  }
  __syncthreads();
  for (int idx = tid; idx < 13 * 13 * 8; idx += 128) {
    int co = idx & 7, pos = idx >> 3;
    int j = pos % 13, i = pos / 13;
    float acc = 0.f;
    #pragma unroll
    for (int ky = 0; ky < 3; ++ky)
      #pragma unroll
      for (int kx = 0; kx < 3; ++kx)
        acc += s_in[(2 * i + ky) * 28 + (2 * j + kx)] * s_k1[(ky * 3 + kx) * 8 + co];
    float v = acc * s_s1[co] + s_b1[co];
    s_y1[idx] = v > 0.f ? v : 0.f;
  }
  __syncthreads();
  for (int idx = tid; idx < 6 * 6 * 16; idx += 128) {
    int co = idx & 15, pos = idx >> 4;
    int j = pos % 6, i = pos / 6;
    float acc = 0.f;
    for (int ky = 0; ky < 3; ++ky)
      for (int kx = 0; kx < 3; ++kx) {
        int base = ((2 * i + ky) * 13 + (2 * j + kx)) * 8;
        int kb = (ky * 3 + kx) * 128 + co;
        #pragma unroll
        for (int ci = 0; ci < 8; ++ci) acc += s_y1[base + ci] * s_k2[kb + ci * 16];
      }
    float v = acc * s_s2[co] + s_b2[co];
    s_y2[idx] = v > 0.f ? v : 0.f;
  }
  __syncthreads();
  for (int idx = tid; idx < 128; idx += 128) {
    int co = idx & 31, pos = idx >> 5;
    int j = pos & 1, i = pos >> 1;
    float acc = 0.f;
    for (int ky = 0; ky < 3; ++ky)
      for (int kx = 0; kx < 3; ++kx) {
        int base = ((2 * i + ky) * 6 + (2 * j + kx)) * 16;
        int kb = (ky * 3 + kx) * 512 + co;
        #pragma unroll
        for (int ci = 0; ci < 16; ++ci) acc += s_y2[base + ci] * s_k3[kb + ci * 32];
      }
    float v = acc * s_s3[co] + s_b3[co];
    FEATP[(size_t)n * 128 + idx] = v > 0.f ? v : 0.f;
  }
}

// ---------------- persistent LSTM scan ----------------
// Roles: AZ 0..63 (gates slot1, x-gemm slot3 local), AO 64..79 (outpre slot1),
// BL 80..143 (zacc h-lo slot3), BH 144..175 (zacc h-hi slot3, E64),
// OL 176..191 / OHI 192..207 (outh slot2), PL 208..217 / PHI 218..222 (Wp slot2),
// CA 223..254 (softmax-out slot2, attention slot3). 255 idle.
__global__ __launch_bounds__(512) void lstm_kernel(
    const int* __restrict__ labels,
    const float* __restrict__ Wo, const float* __restrict__ bo,
    const float* __restrict__ Wp, const float* __restrict__ bp,
    const float* __restrict__ Wf, const float* __restrict__ bf,
    float* __restrict__ ws, float* __restrict__ out) {
  extern __shared__ float dyn[];
  const float* FEATP = ws + OFF_FEATP;
  const float* WXI   = ws + OFF_WXI;
  const float* WHI   = ws + OFF_WHI;
  const float* BLI   = ws + OFF_BLI;
  float* ZP0    = ws + OFF_ZP0;
  float* ZP1    = ws + OFF_ZP1;
  float* OH0    = ws + OFF_OH0;
  float* OH1    = ws + OFF_OH1;
  float* HP0    = ws + OFF_HP0;
  float* HP1    = ws + OFF_HP1;
  float* OUTPRE = ws + OFF_OUTPRE;
  float* HT     = ws + OFF_HT;
  float* RVT    = ws + OFF_RVT;
  int*   BARp   = (int*)(ws + OFF_BAR);

  const int bid = blockIdx.x;
  const int tid = threadIdx.x;
  int barGen = 0;

  // fence-free barrier; release fans out to 8 per-line flags
  auto gbar = [&]() {
    asm volatile("s_waitcnt vmcnt(0) lgkmcnt(0)" ::: "memory");
    __syncthreads();
    ++barGen;
    if (tid == 0) {
      int a = __hip_atomic_fetch_add(&BARp[(bid & 7) << 6], 1, __ATOMIC_RELAXED,
                                     __HIP_MEMORY_SCOPE_AGENT);
      if ((a & 31) == 31) {
        int r = __hip_atomic_fetch_add(&BARp[512], 1, __ATOMIC_RELAXED,
                                       __HIP_MEMORY_SCOPE_AGENT);
        if ((r & 7) == 7) {
          #pragma unroll
          for (int x = 0; x < 8; ++x)
            __hip_atomic_store(&BARp[576 + x * 32], barGen, __ATOMIC_RELAXED,
                               __HIP_MEMORY_SCOPE_AGENT);
        }
      }
      while (__hip_atomic_load(&BARp[576 + (bid & 7) * 32], __ATOMIC_RELAXED,
                               __HIP_MEMORY_SCOPE_AGENT) < barGen) {
        __builtin_amdgcn_s_sleep(1);
      }
    }
    __syncthreads();
  };

  // stage 8192-float [256][32] coherent buffer into [256][36]-padded LDS tile
  auto stage_act = [&](float* dst, const float* src) {
    double v[8];
    ld8x2_sc((const double*)src + tid, v);
    #pragma unroll
    for (int j = 0; j < 8; ++j) {
      int i = (tid + j * 512) << 1;
      *(double*)&dst[(i >> 5) * 36 + (i & 31)] = v[j];
    }
  };

  // ---- E32: Y[32c][32b] = W[K][32c] * A[K][32b pad36]. Lane tile 8c x 4b,
  // 2-way k-split in wave (shfl-combined), 8 waves k-split, part[4][32][36].
  // Output: r.x=(c,b2), r.y=(c,b2+1), c=tid&31, b2=(tid>>5)*2. K mult of 16.
  auto E32 = [&](const float* Wm, const float* Am, int K, float* part, float2& r) {
    const int wv = tid >> 6, l = tid & 63;
    const int ksub = l & 1, cg = (l >> 1) & 3, bg = l >> 3;
    const int Kp = K >> 4;
    const int kb = wv * (K >> 3) + ksub * Kp;
    const float* wp = Wm + (size_t)kb * 32 + cg * 8;
    const float* ap = Am + (size_t)kb * 36 + bg * 4;
    float4 acc[8];
    #pragma unroll
    for (int i = 0; i < 8; ++i) acc[i] = {0.f, 0.f, 0.f, 0.f};
    #pragma unroll 4
    for (int kk = 0; kk < Kp; ++kk) {
      float4 w0 = *(const float4*)(wp + kk * 32);
      float4 w1 = *(const float4*)(wp + kk * 32 + 4);
      float4 a  = *(const float4*)(ap + kk * 36);
      float wl[8];
      *(float4*)&wl[0] = w0; *(float4*)&wl[4] = w1;
      #pragma unroll
      for (int i = 0; i < 8; ++i) {
        acc[i].x = fmaf(wl[i], a.x, acc[i].x);
        acc[i].y = fmaf(wl[i], a.y, acc[i].y);
        acc[i].z = fmaf(wl[i], a.z, acc[i].z);
        acc[i].w = fmaf(wl[i], a.w, acc[i].w);
      }
    }
    #pragma unroll
    for (int i = 0; i < 8; ++i) {
      acc[i].x += __shfl_xor(acc[i].x, 1, 64);
      acc[i].y += __shfl_xor(acc[i].y, 1, 64);
      acc[i].z += __shfl_xor(acc[i].z, 1, 64);
      acc[i].w += __shfl_xor(acc[i].w, 1, 64);
    }
    const int ob = (cg * 8) * 36 + bg * 4;
    if (ksub == 0 && wv < 4) {
      float* pb = part + wv * 1152 + ob;
      #pragma unroll
      for (int i = 0; i < 8; ++i) *(float4*)(pb + i * 36) = acc[i];
    }
    __syncthreads();
    if (ksub == 0 && wv >= 4) {
      float* pb = part + (wv - 4) * 1152 + ob;
      #pragma unroll
      for (int i = 0; i < 8; ++i) {
        float4 t = *(float4*)(pb + i * 36);
        t.x += acc[i].x; t.y += acc[i].y; t.z += acc[i].z; t.w += acc[i].w;
        *(float4*)(pb + i * 36) = t;
      }
    }
    __syncthreads();
    const int c = tid & 31, b2 = (tid >> 5) * 2;
    const int o = c * 36 + b2;
    float2 s0 = *(float2*)(part + o);
    float2 s1 = *(float2*)(part + 1152 + o);
    float2 s2 = *(float2*)(part + 2304 + o);
    float2 s3 = *(float2*)(part + 3456 + o);
    r.x = (s0.x + s1.x) + (s2.x + s3.x);
    r.y = (s0.y + s1.y) + (s2.y + s3.y);
  };

  // ---- E64: Y[64c][32b]. Lane tile 8c x 8b, 2-way in-wave k-split,
  // part[4][64][36]. K MUST be 256 (w-rotation assumes ksub=(k>>4)&1).
  // Weight slab stored with odd-16-k-group rows rotated by 4 floats.
  // Output: r = rows b4..b4+3 at col c; c=tid&63, b4=(tid>>6)*4.
  auto E64 = [&](const float* Wm, const float* Am, float* part, float4& r) {
    const int wv = tid >> 6, l = tid & 63;
    const int ksub = l & 1, cg = (l >> 1) & 7, bg = l >> 4;
    const int kb = wv * 32 + ksub * 16;
    const float* wp0 = Wm + (size_t)kb * 64 + ((cg * 8 + ksub * 4) & 63);
    const float* wp1 = Wm + (size_t)kb * 64 + ((cg * 8 + 4 + ksub * 4) & 63);
    const float* ap = Am + (size_t)kb * 36 + bg * 8;
    float4 acc[8][2];
    #pragma unroll
    for (int i = 0; i < 8; ++i) { acc[i][0] = {0.f,0.f,0.f,0.f}; acc[i][1] = {0.f,0.f,0.f,0.f}; }
    #pragma unroll 2
    for (int kk = 0; kk < 16; ++kk) {
      float4 w0 = *(const float4*)(wp0 + kk * 64);
      float4 w1 = *(const float4*)(wp1 + kk * 64);
      float4 a0 = *(const float4*)(ap + kk * 36);
      float4 a1 = *(const float4*)(ap + kk * 36 + 4);
      float wl[8];
      *(float4*)&wl[0] = w0; *(float4*)&wl[4] = w1;
      #pragma unroll
      for (int i = 0; i < 8; ++i) {
        acc[i][0].x = fmaf(wl[i], a0.x, acc[i][0].x);
        acc[i][0].y = fmaf(wl[i], a0.y, acc[i][0].y);
        acc[i][0].z = fmaf(wl[i], a0.z, acc[i][0].z);
        acc[i][0].w = fmaf(wl[i], a0.w, acc[i][0].w);
        acc[i][1].x = fmaf(wl[i], a1.x, acc[i][1].x);
        acc[i][1].y = fmaf(wl[i], a1.y, acc[i][1].y);
        acc[i][1].z = fmaf(wl[i], a1.z, acc[i][1].z);
        acc[i][1].w = fmaf(wl[i], a1.w, acc[i][1].w);
      }
    }
    #pragma unroll
    for (int i = 0; i < 8; ++i) {
      #pragma unroll
      for (int j = 0; j < 2; ++j) {
        acc[i][j].x += __shfl_xor(acc[i][j].x, 1, 64);
        acc[i][j].y += __shfl_xor(acc[i][j].y, 1, 64);
        acc[i][j].z += __shfl_xor(acc[i][j].z, 1, 64);
        acc[i][j].w += __shfl_xor(acc[i][j].w, 1, 64);
      }
    }
    const int ob = (cg * 8) * 36 + bg * 8;
    if (ksub == 0 && wv < 4) {
      float* pb = part + wv * 2304 + ob;
      #pragma unroll
      for (int i = 0; i < 8; ++i) {
        *(float4*)(pb + i * 36) = acc[i][0];
        *(float4*)(pb + i * 36 + 4) = acc[i][1];
      }
    }
    __syncthreads();
    if (ksub == 0 && wv >= 4) {
      float* pb = part + (wv - 4) * 2304 + ob;
      #pragma unroll
      for (int i = 0; i < 8; ++i) {
        float4 t0 = *(float4*)(pb + i * 36);
        float4 t1 = *(float4*)(pb + i * 36 + 4);
        t0.x += acc[i][0].x; t0.y += acc[i][0].y; t0.z += acc[i][0].z; t0.w += acc[i][0].w;
        t1.x += acc[i][1].x; t1.y += acc[i][1].y; t1.z += acc[i][1].z; t1.w += acc[i][1].w;
        *(float4*)(pb + i * 36) = t0;
        *(float4*)(pb + i * 36 + 4) = t1;
      }
    }
    __syncthreads();
    const int c = tid & 63, b4 = (tid >> 6) * 4;
    const int o = c * 36 + b4;
    float4 s0 = *(float4*)(part + o);
    float4 s1 = *(float4*)(part + 2304 + o);
    float4 s2 = *(float4*)(part + 4608 + o);
    float4 s3 = *(float4*)(part + 6912 + o);
    r.x = (s0.x + s1.x) + (s2.x + s3.x);
    r.y = (s0.y + s1.y) + (s2.y + s3.y);
    r.z = (s0.z + s1.z) + (s2.z + s3.z);
    r.w = (s0.w + s1.w) + (s2.w + s3.w);
  };

  // ---------------- one-time init: weights -> LDS ----------------
  if (bid < 64) {            // AZ: Wz rv rows 153..408; Wxx x rows 0..127
    const int c0 = bid * 32;
    for (int i = tid; i < 8192; i += 512)
      dyn[i] = WXI[(size_t)(153 + (i >> 5)) * 2048 + c0 + (i & 31)];
    for (int i = tid; i < 4096; i += 512)
      dyn[8192 + i] = WXI[(size_t)(i >> 5) * 2048 + c0 + (i & 31)];
    if (tid < 256) dyn[12288 + tid] = 0.f;  // Cst
  } else if (bid < 80) {     // AO: Wo rows 512..767
    const int u0 = (bid - 64) * 32;
    for (int i = tid; i < 8192; i += 512)
      dyn[i] = Wo[(size_t)(512 + (i >> 5)) * 512 + u0 + (i & 31)];
    if (tid < 32) dyn[8192 + tid] = bo[u0 + tid];
  } else if (bid < 144) {    // BL: WHI rows 0..255
    const int c0 = (bid - 80) * 32;
    for (int i = tid; i < 8192; i += 512)
      dyn[i] = WHI[(size_t)(i >> 5) * 2048 + c0 + (i & 31)];
    if (tid < 32) dyn[8192 + tid] = BLI[c0 + tid];
  } else if (bid < 176) {    // BH: WHI rows 256..511, [256][64] rotated
    const int c0 = (bid - 144) * 64;
    for (int i = tid; i < 16384; i += 512) {
      int k = i >> 6, c = i & 63;
      int cr = (c + ((k >> 4) & 1) * 4) & 63;
      dyn[k * 64 + cr] = WHI[(size_t)(256 + k) * 2048 + c0 + c];
    }
  } else if (bid < 192) {    // OL: Wo rows 0..255
    const int u0 = (bid - 176) * 32;
    for (int i = tid; i < 8192; i += 512)
      dyn[i] = Wo[(size_t)(i >> 5) * 512 + u0 + (i & 31)];
  } else if (bid < 208) {    // OHI: Wo rows 256..511
    const int u0 = (bid - 192) * 32;
    for (int i = tid; i < 8192; i += 512)
      dyn[i] = Wo[(size_t)(256 + (i >> 5)) * 512 + u0 + (i & 31)];
  } else if (bid < 218) {    // PL: Wp rows 0..255
    const int j0 = (bid - 208) * 32;
    for (int i = tid; i < 8192; i += 512)
      dyn[i] = Wp[(size_t)(i >> 5) * 320 + j0 + (i & 31)];
  } else if (bid < 223) {    // PHI: Wp rows 256..511, [256][64] rotated
    const int j0 = (bid - 218) * 64;
    for (int i = tid; i < 16384; i += 512) {
      int k = i >> 6, c = i & 63;
      int cr = (c + ((k >> 4) & 1) * 4) & 63;
      dyn[k * 64 + cr] = Wp[(size_t)(256 + k) * 320 + j0 + c];
    }
  } else if (bid < 255) {    // CA
    for (int i = tid; i < 17000; i += 512) dyn[i] = 0.f;       // ring[250][68]
    for (int i = tid; i < 12800; i += 512) dyn[17000 + i] = Wf[i];
    for (int i = tid; i < 320; i += 512) dyn[29800 + i] = bp[i];
    if (tid < 25) dyn[30120 + tid] = bf[tid];
  }
  __syncthreads();

  // ---------------- slot bodies ----------------
  // AZ dyn: Wz[0,8192) Wxx[8192,12288) Cst[12288,12544) rvT[12544,21760)
  //         xT[21760,26368) zx[26368,27392) zf[27392,28416) part[28416,33024)
  auto azGates = [&]() {
    const int c0 = bid * 32;
    float* Wz = dyn; float* Cst = dyn + 12288; float* rvT = dyn + 12544;
    float* zx = dyn + 26368; float* zf = dyn + 27392; float* part = dyn + 28416;
    {
      const int b = tid >> 4, c2 = tid & 15;
      double v[10];
      ld10x2_sc((const double*)RVT + tid,
                (const double*)(ZP0 + (size_t)b * 2048 + c0) + c2,
                (const double*)(ZP1 + (size_t)b * 2048 + c0) + c2, v);
      #pragma unroll
      for (int j = 0; j < 8; ++j) {
        int i = (tid + j * 512) << 1;
        *(double*)&rvT[(i >> 5) * 36 + (i & 31)] = v[j];
      }
      float2 f0 = *(float2*)&v[8], f1 = *(float2*)&v[9];
      float2 s = {f0.x + f1.x, f0.y + f1.y};
      *(double*)&zf[b * 32 + c2 * 2] = *(double*)&s;
    }
    __syncthreads();
    float2 r;
    E32(Wz, rvT, 256, part, r);
    const int c = tid & 31, b2 = (tid >> 5) * 2;
    zf[b2 * 32 + c] += r.x + zx[b2 * 32 + c];
    zf[(b2 + 1) * 32 + c] += r.y + zx[(b2 + 1) * 32 + c];
    __syncthreads();
    if (tid < 256) {
      int u = tid & 7, b = tid >> 3;
      float4 z = *(float4*)(zf + b * 32 + u * 4);
      float ig = sigm(z.x), fg = sigm(z.y), gg = tanhf(z.z), og = sigm(z.w);
      float cc = fg * Cst[b * 8 + u] + ig * gg;
      Cst[b * 8 + u] = cc;
      st_sc(&HT[(size_t)(bid * 8 + u) * 32 + b], og * tanhf(cc));
    }
  };
  // AZ slot3: zx = x_{tt}@Wx (kept local, never leaves LDS)
  auto azX = [&](int tt) {
    float* Wxx = dyn + 8192; float* xT = dyn + 21760;
    float* zx = dyn + 26368; float* part = dyn + 28416;
    for (int i = tid; i < 4096; i += 512) {
      int b = i >> 7, k = i & 127;
      xT[k * 36 + b] = FEATP[((size_t)b * 250 + tt) * 128 + k];
    }
    __syncthreads();
    float2 r;
    E32(Wxx, xT, 128, part, r);
    const int c = tid & 31, b2 = (tid >> 5) * 2;
    zx[b2 * 32 + c] = r.x;
    zx[(b2 + 1) * 32 + c] = r.y;
  };
  // AO dyn: W[0,8192) bo[8192,8224) rvT[8224,17440) of[17440,18464) part[18464,23072)
  auto aoOut = [&]() {
    const int u0 = (bid - 64) * 32;
    float* W = dyn; float* bo_l = dyn + 8192; float* rvT = dyn + 8224;
    float* of = dyn + 17440; float* part = dyn + 18464;
    {
      const int b = tid >> 4, c2 = tid & 15;
      double v[10];
      ld10x2_sc((const double*)RVT + tid,
                (const double*)(OH0 + b * 512 + u0) + c2,
                (const double*)(OH1 + b * 512 + u0) + c2, v);
      #pragma unroll
      for (int j = 0; j < 8; ++j) {
        int i = (tid + j * 512) << 1;
        *(double*)&rvT[(i >> 5) * 36 + (i & 31)] = v[j];
      }
      float2 f0 = *(float2*)&v[8], f1 = *(float2*)&v[9];
      float2 s = {f0.x + f1.x, f0.y + f1.y};
      *(double*)&of[b * 32 + c2 * 2] = *(double*)&s;
    }
    __syncthreads();
    float2 r;
    E32(W, rvT, 256, part, r);
    const int c = tid & 31, b2 = (tid >> 5) * 2;
    float bv = bo_l[c];
    st_sc(&OUTPRE[b2 * 512 + u0 + c], r.x + of[b2 * 32 + c] + bv);
    st_sc(&OUTPRE[(b2 + 1) * 512 + u0 + c], r.y + of[(b2 + 1) * 32 + c] + bv);
  };
  // BL dyn: W[0,8192) blc[8192,8224) slab[8224,8256) hT[8256,17472) part[17472,22080)
  auto blLoadLab = [&](int tt1) {
    int* slab = (int*)(dyn + 8224);
    if (tid < 32) slab[tid] = labels[tid * 250 + tt1];
  };
  auto blGemm = [&]() {
    const int c0 = (bid - 80) * 32;
    float* W = dyn; float* blc = dyn + 8192; int* slab = (int*)(dyn + 8224);
    float* A = dyn + 8256; float* part = dyn + 17472;
    stage_act(A, HT);
    __syncthreads();
    float2 r;
    E32(W, A, 256, part, r);
    const int c = tid & 31, b2 = (tid >> 5) * 2;
    float base = blc[c];
    int l0 = slab[b2], l1 = slab[b2 + 1];
    st_sc(&ZP0[(size_t)b2 * 2048 + c0 + c],
          r.x + base + WXI[(size_t)(128 + l0) * 2048 + c0 + c]);
    st_sc(&ZP0[(size_t)(b2 + 1) * 2048 + c0 + c],
          r.y + base + WXI[(size_t)(128 + l1) * 2048 + c0 + c]);
  };
  // BH dyn: W[0,16384) hT[16384,25600) part[25600,34816)
  auto bhGemm = [&]() {
    const int c0 = (bid - 144) * 64;
    float* W = dyn; float* A = dyn + 16384; float* part = dyn + 25600;
    stage_act(A, HT + 8192);
    __syncthreads();
    float4 r;
    E64(W, A, part, r);
    const int c = tid & 63, b4 = (tid >> 6) * 4;
    st_sc(&ZP1[(size_t)(b4 + 0) * 2048 + c0 + c], r.x);
    st_sc(&ZP1[(size_t)(b4 + 1) * 2048 + c0 + c], r.y);
    st_sc(&ZP1[(size_t)(b4 + 2) * 2048 + c0 + c], r.z);
    st_sc(&ZP1[(size_t)(b4 + 3) * 2048 + c0 + c], r.w);
  };
  // OL/OHI/PL/PHI (slot2)
  auto bGemmP = [&]() {
    if (bid < 218) {  // OL / OHI / PL : E32
      float* W = dyn; float* A = dyn + 8192; float* part = dyn + 17408;
      const bool isOLr = bid < 192, isOHIr = (bid >= 192 && bid < 208);
      stage_act(A, isOHIr ? (HT + 8192) : HT);
      __syncthreads();
      float2 r;
      E32(W, A, 256, part, r);
      const int c = tid & 31, b2 = (tid >> 5) * 2;
      if (isOLr) {
        const int u0 = (bid - 176) * 32;
        st_sc(&OH0[b2 * 512 + u0 + c], r.x);
        st_sc(&OH0[(b2 + 1) * 512 + u0 + c], r.y);
      } else if (isOHIr) {
        const int u0 = (bid - 192) * 32;
        st_sc(&OH1[b2 * 512 + u0 + c], r.x);
        st_sc(&OH1[(b2 + 1) * 512 + u0 + c], r.y);
      } else {
        const int j0 = (bid - 208) * 32;
        st_sc(&HP0[b2 * 320 + j0 + c], r.x);
        st_sc(&HP0[(b2 + 1) * 320 + j0 + c], r.y);
      }
    } else {          // PHI : E64
      const int j0 = (bid - 218) * 64;
      float* W = dyn; float* A = dyn + 16384; float* part = dyn + 25600;
      stage_act(A, HT + 8192);
      __syncthreads();
      float4 r;
      E64(W, A, part, r);
      const int c = tid & 63, b4 = (tid >> 6) * 4;
      st_sc(&HP1[(b4 + 0) * 320 + j0 + c], r.x);
      st_sc(&HP1[(b4 + 1) * 320 + j0 + c], r.y);
      st_sc(&HP1[(b4 + 2) * 320 + j0 + c], r.z);
      st_sc(&HP1[(b4 + 3) * 320 + j0 + c], r.w);
    }
  };
  // CA dyn: ring[0,17000) Wf[17000,29800) bp[29800,30120) bf[30120,30152)
  //         hid[30152,30472) kn[30472,30728) att4[30728,31752) red[31752,31784)
  //         msum[31784,31800) rvp[31800,33848)  (to/lp/lg alias rvp in slot2)
  auto caOut = [&](int t) {
    float* WfL = dyn + 17000; float* bfL = dyn + 30120;
    float* to  = dyn + 31800; float* lp = dyn + 32312; float* lg = dyn + 32712;
    const int b = bid - 223;
    to[tid] = tanhf(ld_sc(&OUTPRE[b * 512 + tid]));
    __syncthreads();
    if (tid < 400) {
      int l = tid % 25, p = tid / 25;
      float s = 0.f;
      #pragma unroll
      for (int q = 0; q < 32; ++q) { int k = p * 32 + q; s += to[k] * WfL[k * 25 + l]; }
      lp[p * 25 + l] = s;
    }
    __syncthreads();
    if (tid < 25) {
      float s = bfL[tid];
      #pragma unroll
      for (int p = 0; p < 16; ++p) s += lp[p * 25 + tid];
      lg[tid] = s;
    }
    __syncthreads();
    if (tid == 0) {
      float mx = lg[0];
      for (int l = 1; l < 25; ++l) mx = fmaxf(mx, lg[l]);
      float ss = 0.f;
      for (int l = 0; l < 25; ++l) ss += __expf(lg[l] - mx);
      lg[25] = mx; lg[26] = 1.f / ss;
    }
    __syncthreads();
    if (tid < 25)
      out[((size_t)b * 250 + (t - 1)) * 25 + tid] = __expf(lg[tid] - lg[25]) * lg[26];
  };
  auto caAtt = [&](int t) {
    float* ring = dyn;
    float* bpL  = dyn + 29800;
    float* hid  = dyn + 30152;
    float* kn   = dyn + 30472;
    float* att4 = dyn + 30728;
    float* red  = dyn + 31752;
    float* msum = dyn + 31784;
    float* rvp  = dyn + 31800;
    const int b = bid - 223;
    if (tid < 320) {
      float x, y;
      ldpair_sc(&HP0[b * 320 + tid], &HP1[b * 320 + tid], x, y);
      hid[tid] = tanhf(x + y + bpL[tid]);
    }
    __syncthreads();
    if (tid < 256) {
      float v = hid[64 + tid]; float pq = v * v;
      for (int off = 32; off; off >>= 1) pq += __shfl_down(pq, off, 64);
      if ((tid & 63) == 0) red[tid >> 6] = rsqrtf(fmaxf(pq, 1e-12f));
    }
    __syncthreads();
    if (tid < 256) kn[tid] = hid[64 + tid] * red[tid >> 6];
    __syncthreads();
    const int start = (250 - t) % 250;
    if (tid < 500) {
      int m = tid >> 1, dh = tid & 1;
      int p = start + m; if (p >= 250) p -= 250;
      const float* cell = ring + p * 68;
      const float* k0 = kn + dh * 128;
      float n2 = 0.f, d0 = 0.f, d1 = 0.f;
      #pragma unroll
      for (int s = 0; s < 64; s += 4) {
        float4 q = *(const float4*)(cell + s);
        n2 += q.x * q.x + q.y * q.y + q.z * q.z + q.w * q.w;
        d0 += k0[s] * q.x + k0[s + 1] * q.y + k0[s + 2] * q.z + k0[s + 3] * q.w;
        d1 += k0[64 + s] * q.x + k0[64 + s + 1] * q.y + k0[64 + s + 2] * q.z + k0[64 + s + 3] * q.w;
      }
      float rs = rsqrtf(fmaxf(n2, 1e-12f));
      att4[(2 * dh) * 256 + m] = d0 * rs;
      att4[(2 * dh + 1) * 256 + m] = d1 * rs;
    }
    __syncthreads();
    {
      int h4 = tid >> 7, mm = tid & 127;
      float v0 = att4[h4 * 256 + mm];
      bool has2 = (mm + 128) < 250;
      float v1 = has2 ? att4[h4 * 256 + mm + 128] : -3.0e38f;
      float mx = fmaxf(v0, v1);
      for (int off = 32; off; off >>= 1) mx = fmaxf(mx, __shfl_down(mx, off, 64));
      if ((tid & 63) == 0) red[tid >> 6] = mx;
      __syncthreads();
      float MX = fmaxf(red[h4 * 2], red[h4 * 2 + 1]);
      float e0 = __expf(v0 - MX);
      float e1 = has2 ? __expf(v1 - MX) : 0.f;
      att4[h4 * 256 + mm] = e0;
      if (has2) att4[h4 * 256 + mm + 128] = e1;
      float sm_ = e0 + e1;
      for (int off = 32; off; off >>= 1) sm_ += __shfl_down(sm_, off, 64);
      if ((tid & 63) == 0) red[8 + (tid >> 6)] = sm_;
      __syncthreads();
      if (tid < 4) msum[tid] = red[8 + tid * 2] + red[8 + tid * 2 + 1];
      __syncthreads();
    }
    {
      int h4 = tid >> 7, mh = (tid >> 4) & 7, s4 = tid & 15;
      float4 a = {0.f, 0.f, 0.f, 0.f};
      for (int m = mh; m < 250; m += 8) {
        int p = start + m; if (p >= 250) p -= 250;
        float w = att4[h4 * 256 + m];
        float4 q = *(const float4*)(ring + p * 68 + s4 * 4);
        a.x = fmaf(w, q.x, a.x); a.y = fmaf(w, q.y, a.y);
        a.z = fmaf(w, q.z, a.z); a.w = fmaf(w, q.w, a.w);
      }
      *(float4*)(rvp + tid * 4) = a;
    }
    __syncthreads();
    if (tid < 256) {
      int h = tid >> 6, s = tid & 63;
      float sum = 0.f;
      #pragma unroll
      for (int j = 0; j < 8; ++j)
        sum += rvp[(h * 128 + j * 16 + (s >> 2)) * 4 + (s & 3)];
      st_sc(&RVT[(h * 64 + s) * 32 + b], sum / msum[h]);
    }
    __syncthreads();
    if (tid < 64) {
      int ip = start + 249; if (ip >= 250) ip -= 250;
      ring[ip * 68 + tid] = hid[tid];
    }
  };

  const bool isAZ = bid < 64, isAO = (bid >= 64 && bid < 80),
             isBL = (bid >= 80 && bid < 144), isBH = (bid >= 144 && bid < 176),
             isP2 = (bid >= 176 && bid < 223), isCA = (bid >= 223 && bid < 255);

  // ---------------- main sequence ----------------
  // prologue: zacc_0 partials (h=0 via memset HT, rv=0 via memset RVT)
  if (isAZ) azX(0);
  else if (isBL) { blLoadLab(0); blGemm(); }
  else if (isBH) bhGemm();
  gbar();
  for (int t = 0; t < 250; ++t) {
    const int tn = (t + 1 <= 249) ? t + 1 : 249;
    // slot1: gates_t + outpre_{t-1} + label staging
    if (isAZ) azGates();
    else if (isAO) { if (t >= 1) aoOut(); }
    else if (isBL) blLoadLab(tn);
    gbar();
    // slot2: outh/Wp gemms (h_t) + softmax out_{t-1}
    if (isP2) bGemmP();
    else if (isCA && t >= 1) caOut(t);
    gbar();
    // slot3: attention_t (rv_t)  ||  zacc_{t+1} partials  ||  x_{t+1} gemm
    if (isCA) caAtt(t);
    else if (isAZ) azX(tn);
    else if (isBL) blGemm();
    else if (isBH) bhGemm();
    gbar();
  }
  // epilogue: outpre_249 -> out[249]
  if (isAO) aoOut();
  gbar();
  if (isCA) caOut(250);
}

extern "C" void kernel_launch(void* const* d_in, const int* in_sizes, int n_in,
                              void* d_out, int out_size, void* d_ws, size_t ws_size,
                              hipStream_t stream) {
  const float* images = (const float*)d_in[0];
  const int* labels = (const int*)d_in[1];
  const float* k1  = (const float*)d_in[2];
  const float* cb1 = (const float*)d_in[3];
  const float* g1  = (const float*)d_in[4];
  const float* be1 = (const float*)d_in[5];
  const float* mm1 = (const float*)d_in[6];
  const float* mv1 = (const float*)d_in[7];
  const float* k2  = (const float*)d_in[8];
  const float* cb2 = (const float*)d_in[9];
  const float* g2  = (const float*)d_in[10];
  const float* be2 = (const float*)d_in[11];
  const float* mm2 = (const float*)d_in[12];
  const float* mv2 = (const float*)d_in[13];
  const float* k3  = (const float*)d_in[14];
  const float* cb3 = (const float*)d_in[15];
  const float* g3  = (const float*)d_in[16];
  const float* be3 = (const float*)d_in[17];
  const float* mm3 = (const float*)d_in[18];
  const float* mv3 = (const float*)d_in[19];
  const float* Wx  = (const float*)d_in[20];
  const float* Wh  = (const float*)d_in[21];
  const float* bl  = (const float*)d_in[22];
  const float* Wp  = (const float*)d_in[23];
  const float* bp  = (const float*)d_in[24];
  const float* Wo  = (const float*)d_in[25];
  const float* bo  = (const float*)d_in[26];
  const float* Wf  = (const float*)d_in[27];
  const float* bf  = (const float*)d_in[28];
  float* ws = (float*)d_ws;

  hipFuncSetAttribute((const void*)lstm_kernel,
                      hipFuncAttributeMaxDynamicSharedMemorySize, DYN_BYTES);

  // zero activation/state/barrier region (ws poisoned 0xAA before each call)
  hipMemsetAsync((char*)d_ws + OFF_ZP0 * sizeof(float), 0,
                 (WS_FLOATS - OFF_ZP0) * sizeof(float), stream);
  prep_kernel<<<1024, 256, 0, stream>>>(Wx, Wh, bl, ws);
  conv_kernel<<<8000, 128, 0, stream>>>(images,
      k1, cb1, g1, be1, mm1, mv1,
      k2, cb2, g2, be2, mm2, mv2,
      k3, cb3, g3, be3, mm3, mv3, ws);
  lstm_kernel<<<256, 512, DYN_BYTES, stream>>>(labels, Wo, bo, Wp, bp, Wf, bf, ws,
                                               (float*)d_out);
}